// Round 2
// baseline (897.970 us; speedup 1.0000x reference)
//
#include <hip/hip_runtime.h>
#include <hip/hip_bf16.h>

#define CIN 128
#define NHEAD 8
#define CHD 16
#define KVOL 27

constexpr float EPS_BN = 1e-5f;
constexpr float EPS_NORM = 1e-12f;

// ---------------- Kernel 1: BN1 statistics (sum, sumsq of points@w1, 3 cols) ----
__global__ void k_bn1_stats(const float* __restrict__ points,
                            const float* __restrict__ w1,
                            float* __restrict__ stats1, int N) {
  float w[9];
#pragma unroll
  for (int i = 0; i < 9; ++i) w[i] = w1[i];
  float s[3] = {0.f, 0.f, 0.f}, ss[3] = {0.f, 0.f, 0.f};
  for (int n = blockIdx.x * blockDim.x + threadIdx.x; n < N;
       n += gridDim.x * blockDim.x) {
    float p0 = points[3 * n], p1 = points[3 * n + 1], p2 = points[3 * n + 2];
#pragma unroll
    for (int j = 0; j < 3; ++j) {
      float y = p0 * w[j] + p1 * w[3 + j] + p2 * w[6 + j];
      s[j] += y;
      ss[j] += y * y;
    }
  }
#pragma unroll
  for (int j = 0; j < 3; ++j) {
    for (int off = 32; off > 0; off >>= 1) {
      s[j] += __shfl_down(s[j], off);
      ss[j] += __shfl_down(ss[j], off);
    }
  }
  if ((threadIdx.x & 63) == 0) {
#pragma unroll
    for (int j = 0; j < 3; ++j) {
      atomicAdd(&stats1[j], s[j]);
      atomicAdd(&stats1[3 + j], ss[j]);
    }
  }
}

// ---------------- Kernel 2: BN2 statistics (sum, sumsq of h0@w2, 128 cols) -----
__global__ void k_bn2_stats(const float* __restrict__ points,
                            const float* __restrict__ w1,
                            const float* __restrict__ g1,
                            const float* __restrict__ b1,
                            const float* __restrict__ w2,
                            const float* __restrict__ stats1,
                            float* __restrict__ stats2, int N) {
  int c = threadIdx.x;
  float w[9];
#pragma unroll
  for (int i = 0; i < 9; ++i) w[i] = w1[i];
  float sc1[3], sh1[3];
#pragma unroll
  for (int j = 0; j < 3; ++j) {
    float m = stats1[j] / (float)N;
    float var = stats1[3 + j] / (float)N - m * m;
    float sc = rsqrtf(var + EPS_BN) * g1[j];
    sc1[j] = sc;
    sh1[j] = b1[j] - m * sc;
  }
  float wc0 = w2[c], wc1 = w2[CIN + c], wc2 = w2[2 * CIN + c];
  float s = 0.f, ss = 0.f;
  for (int n = blockIdx.x; n < N; n += gridDim.x) {
    float p0 = points[3 * n], p1 = points[3 * n + 1], p2 = points[3 * n + 2];
    float y0 = p0 * w[0] + p1 * w[3] + p2 * w[6];
    float y1 = p0 * w[1] + p1 * w[4] + p2 * w[7];
    float y2 = p0 * w[2] + p1 * w[5] + p2 * w[8];
    float a0 = fmaxf(y0 * sc1[0] + sh1[0], 0.f);
    float a1 = fmaxf(y1 * sc1[1] + sh1[1], 0.f);
    float a2 = fmaxf(y2 * sc1[2] + sh1[2], 0.f);
    float y = a0 * wc0 + a1 * wc1 + a2 * wc2;
    s += y;
    ss += y * y;
  }
  atomicAdd(&stats2[c], s);
  atomicAdd(&stats2[CIN + c], ss);
}

// ---------------- Kernel 3: normalized positional encodings ---------------------
__global__ void k_pn(const float* __restrict__ pos_enc, float* __restrict__ pn) {
  int t = blockIdx.x * blockDim.x + threadIdx.x;
  if (t >= KVOL * NHEAD) return;
  const float* src = pos_enc + t * CHD;
  float vals[CHD];
  float sum = 0.f;
#pragma unroll
  for (int i = 0; i < CHD; ++i) {
    vals[i] = src[i];
    sum += vals[i] * vals[i];
  }
  float inv = 1.f / fmaxf(sqrtf(sum), EPS_NORM);
#pragma unroll
  for (int i = 0; i < CHD; ++i) pn[t * CHD + i] = vals[i] * inv;
}

// ---------------- Kernel 4: per-point chain -> qn, v ---------------------------
__global__ __launch_bounds__(256) void k_qv(
    const float* __restrict__ points, const float* __restrict__ feats,
    const float* __restrict__ w1, const float* __restrict__ g1,
    const float* __restrict__ b1, const float* __restrict__ w2,
    const float* __restrict__ g2, const float* __restrict__ b2,
    const float* __restrict__ w3, const float* __restrict__ b3,
    const float* __restrict__ wq, const float* __restrict__ bq,
    const float* __restrict__ wv, const float* __restrict__ bv,
    const float* __restrict__ stats1, const float* __restrict__ stats2,
    float* __restrict__ qn, float* __restrict__ vout, int N) {
  __shared__ float h0s[16][4];
  __shared__ float h1s[16][CIN];
  __shared__ float xs[16][CIN];

  int t = threadIdx.x;
  int c = t & 127;
  int half = t >> 7;
  int base = blockIdx.x * 16;

  if (t < 16) {
    int n = base + t;
    float a0 = 0.f, a1 = 0.f, a2 = 0.f;
    if (n < N) {
      float p0 = points[3 * n], p1 = points[3 * n + 1], p2 = points[3 * n + 2];
#pragma unroll
      for (int j = 0; j < 3; ++j) {
        float m = stats1[j] / (float)N;
        float var = stats1[3 + j] / (float)N - m * m;
        float sc = rsqrtf(var + EPS_BN) * g1[j];
        float sh = b1[j] - m * sc;
        float y = p0 * w1[j] + p1 * w1[3 + j] + p2 * w1[6 + j];
        float a = fmaxf(y * sc + sh, 0.f);
        if (j == 0) a0 = a;
        if (j == 1) a1 = a;
        if (j == 2) a2 = a;
      }
    }
    h0s[t][0] = a0;
    h0s[t][1] = a1;
    h0s[t][2] = a2;
  }
  __syncthreads();

  float m2 = stats2[c] / (float)N;
  float v2 = stats2[CIN + c] / (float)N - m2 * m2;
  float sc2 = rsqrtf(v2 + EPS_BN) * g2[c];
  float sh2 = b2[c] - m2 * sc2;
  float w2c0 = w2[c], w2c1 = w2[CIN + c], w2c2 = w2[2 * CIN + c];

#pragma unroll
  for (int i = 0; i < 8; ++i) {
    int p = i * 2 + half;
    float y = h0s[p][0] * w2c0 + h0s[p][1] * w2c1 + h0s[p][2] * w2c2;
    h1s[p][c] = fmaxf(y * sc2 + sh2, 0.f);
  }
  __syncthreads();

  float acc[8];
  float b3c = b3[c];
#pragma unroll
  for (int i = 0; i < 8; ++i) acc[i] = b3c;
  for (int k = 0; k < CIN; ++k) {
    float w = w3[k * CIN + c];
#pragma unroll
    for (int i = 0; i < 8; ++i) acc[i] += h1s[i * 2 + half][k] * w;
  }
#pragma unroll
  for (int i = 0; i < 8; ++i) {
    int p = i * 2 + half;
    int n = base + p;
    float f = (n < N) ? feats[(size_t)n * CIN + c] : 0.f;
    xs[p][c] = acc[i] + f;
  }
  __syncthreads();

  float qa[8], va[8];
  float bqc = bq[c], bvc = bv[c];
#pragma unroll
  for (int i = 0; i < 8; ++i) {
    qa[i] = bqc;
    va[i] = bvc;
  }
  for (int k = 0; k < CIN; ++k) {
    float wqv = wq[k * CIN + c];
    float wvv = wv[k * CIN + c];
#pragma unroll
    for (int i = 0; i < 8; ++i) {
      float xv = xs[i * 2 + half][k];
      qa[i] += xv * wqv;
      va[i] += xv * wvv;
    }
  }

#pragma unroll
  for (int i = 0; i < 8; ++i) {
    float q = qa[i];
    float sum = q * q;
    sum += __shfl_xor(sum, 1);
    sum += __shfl_xor(sum, 2);
    sum += __shfl_xor(sum, 4);
    sum += __shfl_xor(sum, 8);
    float inv = 1.f / fmaxf(sqrtf(sum), EPS_NORM);
    int n = base + i * 2 + half;
    if (n < N) {
      qn[(size_t)n * CIN + c] = q * inv;
      vout[(size_t)n * CIN + c] = va[i];
    }
  }
}

// ---------------- Sort phase: histogram / scan / scatter records ---------------
__global__ void k_hist(const int* __restrict__ q_idx, int* __restrict__ cnt,
                       int M) {
  for (int i = blockIdx.x * blockDim.x + threadIdx.x; i < M;
       i += gridDim.x * blockDim.x)
    atomicAdd(&cnt[q_idx[i]], 1);
}

// single block, 1024 threads: exclusive scan of cnt[0..N) -> offs[0..N], cursor
__global__ __launch_bounds__(1024) void k_scan(const int* __restrict__ cnt,
                                               int* __restrict__ offs,
                                               int* __restrict__ cursor, int N) {
  __shared__ int ls[1024];
  int t = threadIdx.x;
  int chunk = (N + 1023) / 1024;
  int start = t * chunk;
  int end = min(start + chunk, N);
  int s = 0;
  for (int i = start; i < end; ++i) s += cnt[i];
  ls[t] = s;
  __syncthreads();
  for (int off = 1; off < 1024; off <<= 1) {
    int v = 0;
    if (t >= off) v = ls[t - off];
    __syncthreads();
    ls[t] += v;
    __syncthreads();
  }
  int run = (t == 0) ? 0 : ls[t - 1];
  for (int i = start; i < end; ++i) {
    int c = cnt[i];
    offs[i] = run;
    cursor[i] = run;
    run += c;
  }
  if (t == 1023) offs[N] = ls[1023];
}

__global__ void k_scatter_rec(const int* __restrict__ q_idx,
                              const int* __restrict__ k_idx,
                              const int* __restrict__ kernel_idx,
                              int* __restrict__ cursor,
                              unsigned* __restrict__ recs, int M) {
  for (int i = blockIdx.x * blockDim.x + threadIdx.x; i < M;
       i += gridDim.x * blockDim.x) {
    int qi = q_idx[i];
    int pos = atomicAdd(&cursor[qi], 1);
    recs[pos] = (unsigned)k_idx[i] | ((unsigned)kernel_idx[i] << 17);
  }
}

// ---------------- Fused attention gather-reduce + output projection ------------
// 256 threads = 4 waves = 4 points. Wave w owns point blockIdx*4+w; lane l owns
// channels {2l, 2l+1}. Then block applies @wo + bo from LDS.
__global__ __launch_bounds__(256) void k_attn_out(
    const unsigned* __restrict__ recs, const int* __restrict__ offs,
    const float* __restrict__ qn, const float* __restrict__ v,
    const float* __restrict__ pn, const float* __restrict__ wo,
    const float* __restrict__ bo, float* __restrict__ out, int N) {
  __shared__ float accs[4][CIN];
  int t = threadIdx.x;
  int w = t >> 6;
  int l = t & 63;
  int n = blockIdx.x * 4 + w;

  const float2* qn2 = (const float2*)qn;
  const float2* v2p = (const float2*)v;
  const float2* pn2 = (const float2*)pn;

  float ax = 0.f, ay = 0.f;
  if (n < N) {
    float2 q2 = qn2[(size_t)n * 64 + l];
    int beg = offs[n], end = offs[n + 1];
    for (int idx = beg; idx < end; ++idx) {
      unsigned rec = recs[idx];
      int ki = rec & 0x1FFFF;
      int kk = rec >> 17;
      float2 p2 = pn2[kk * 64 + l];
      float d = q2.x * p2.x + q2.y * p2.y;
      d += __shfl_xor(d, 1);
      d += __shfl_xor(d, 2);
      d += __shfl_xor(d, 4);
      float2 vv = v2p[(size_t)ki * 64 + l];
      ax += d * vv.x;
      ay += d * vv.y;
    }
  }
  accs[w][2 * l] = ax;
  accs[w][2 * l + 1] = ay;
  __syncthreads();

  int c = t & 127;
  int pr = t >> 7;  // 0..1 -> handles points pr and pr+2
  float o0 = bo[c], o1 = o0;
  for (int k = 0; k < CIN; ++k) {
    float wv = wo[k * CIN + c];
    o0 += accs[pr][k] * wv;
    o1 += accs[pr + 2][k] * wv;
  }
  int n0 = blockIdx.x * 4 + pr;
  int n1 = n0 + 2;
  if (n0 < N) out[(size_t)n0 * CIN + c] = o0;
  if (n1 < N) out[(size_t)n1 * CIN + c] = o1;
}

// ---------------- launch -------------------------------------------------------
extern "C" void kernel_launch(void* const* d_in, const int* in_sizes, int n_in,
                              void* d_out, int out_size, void* d_ws,
                              size_t ws_size, hipStream_t stream) {
  const float* points = (const float*)d_in[0];
  const float* feats = (const float*)d_in[1];
  const int* k_idx = (const int*)d_in[2];
  const int* q_idx = (const int*)d_in[3];
  const int* kernel_idx = (const int*)d_in[4];
  const float* w1 = (const float*)d_in[5];
  const float* g1 = (const float*)d_in[6];
  const float* b1 = (const float*)d_in[7];
  const float* w2 = (const float*)d_in[8];
  const float* g2 = (const float*)d_in[9];
  const float* b2 = (const float*)d_in[10];
  const float* w3 = (const float*)d_in[11];
  const float* b3 = (const float*)d_in[12];
  const float* wq = (const float*)d_in[13];
  const float* bq = (const float*)d_in[14];
  const float* wv = (const float*)d_in[15];
  const float* bv = (const float*)d_in[16];
  const float* wo = (const float*)d_in[17];
  const float* bo = (const float*)d_in[18];
  const float* pos_enc = (const float*)d_in[19];

  int N = in_sizes[0] / 3;
  int M = in_sizes[2];

  float* ws = (float*)d_ws;
  float* stats1 = ws;        // 8 floats
  float* stats2 = ws + 8;    // 256 floats
  float* pn = ws + 8 + 256;  // 3456 floats
  int* cnt = (int*)(ws + 4096);      // N ints
  int* offs = cnt + N;               // N+1 ints
  int* cursor = offs + N + 1;        // N ints
  unsigned* recs = (unsigned*)(cursor + N);  // M u32
  float* qn = (float*)(recs + M);            // N*128 floats
  float* vbuf = qn + (size_t)N * CIN;        // N*128 floats
  float* outf = (float*)d_out;

  hipMemsetAsync(ws, 0, 4096 * sizeof(float), stream);
  hipMemsetAsync(cnt, 0, (size_t)N * sizeof(int), stream);

  k_bn1_stats<<<256, 256, 0, stream>>>(points, w1, stats1, N);
  k_bn2_stats<<<512, 128, 0, stream>>>(points, w1, g1, b1, w2, stats1, stats2, N);
  k_pn<<<1, 256, 0, stream>>>(pos_enc, pn);
  k_hist<<<2048, 256, 0, stream>>>(q_idx, cnt, M);
  k_scan<<<1, 1024, 0, stream>>>(cnt, offs, cursor, N);
  k_scatter_rec<<<2048, 256, 0, stream>>>(q_idx, k_idx, kernel_idx, cursor, recs, M);
  k_qv<<<(N + 15) / 16, 256, 0, stream>>>(points, feats, w1, g1, b1, w2, g2, b2,
                                          w3, b3, wq, bq, wv, bv, stats1, stats2,
                                          qn, vbuf, N);
  k_attn_out<<<(N + 3) / 4, 256, 0, stream>>>(recs, offs, qn, vbuf, pn, wo, bo,
                                              outf, N);
}

// Round 5
// 781.720 us; speedup vs baseline: 1.1487x; 1.1487x over previous
//
#include <hip/hip_runtime.h>
#include <hip/hip_bf16.h>

#define CIN 128
#define NHEAD 8
#define CHD 16
#define KVOL 27

constexpr float EPS_BN = 1e-5f;
constexpr float EPS_NORM = 1e-12f;

typedef __attribute__((ext_vector_type(8))) short short8;
typedef __attribute__((ext_vector_type(4))) float f32x4;

__device__ __forceinline__ float bflo(unsigned u) {
  return __uint_as_float(u << 16);
}
__device__ __forceinline__ float bfhi(unsigned u) {
  return __uint_as_float(u & 0xffff0000u);
}

// ---------------- BN1 statistics ----------------------------------------------
__global__ void k_bn1_stats(const float* __restrict__ points,
                            const float* __restrict__ w1,
                            float* __restrict__ stats1, int N) {
  float w[9];
#pragma unroll
  for (int i = 0; i < 9; ++i) w[i] = w1[i];
  float s[3] = {0.f, 0.f, 0.f}, ss[3] = {0.f, 0.f, 0.f};
  for (int n = blockIdx.x * blockDim.x + threadIdx.x; n < N;
       n += gridDim.x * blockDim.x) {
    float p0 = points[3 * n], p1 = points[3 * n + 1], p2 = points[3 * n + 2];
#pragma unroll
    for (int j = 0; j < 3; ++j) {
      float y = p0 * w[j] + p1 * w[3 + j] + p2 * w[6 + j];
      s[j] += y;
      ss[j] += y * y;
    }
  }
#pragma unroll
  for (int j = 0; j < 3; ++j) {
    for (int off = 32; off > 0; off >>= 1) {
      s[j] += __shfl_down(s[j], off);
      ss[j] += __shfl_down(ss[j], off);
    }
  }
  if ((threadIdx.x & 63) == 0) {
#pragma unroll
    for (int j = 0; j < 3; ++j) {
      atomicAdd(&stats1[j], s[j]);
      atomicAdd(&stats1[3 + j], ss[j]);
    }
  }
}

// ---------------- BN2 statistics ----------------------------------------------
__global__ void k_bn2_stats(const float* __restrict__ points,
                            const float* __restrict__ w1,
                            const float* __restrict__ g1,
                            const float* __restrict__ b1,
                            const float* __restrict__ w2,
                            const float* __restrict__ stats1,
                            float* __restrict__ stats2, int N) {
  int c = threadIdx.x;
  float w[9];
#pragma unroll
  for (int i = 0; i < 9; ++i) w[i] = w1[i];
  float sc1[3], sh1[3];
#pragma unroll
  for (int j = 0; j < 3; ++j) {
    float m = stats1[j] / (float)N;
    float var = stats1[3 + j] / (float)N - m * m;
    float sc = rsqrtf(var + EPS_BN) * g1[j];
    sc1[j] = sc;
    sh1[j] = b1[j] - m * sc;
  }
  float wc0 = w2[c], wc1 = w2[CIN + c], wc2 = w2[2 * CIN + c];
  float s = 0.f, ss = 0.f;
  for (int n = blockIdx.x; n < N; n += gridDim.x) {
    float p0 = points[3 * n], p1 = points[3 * n + 1], p2 = points[3 * n + 2];
    float y0 = p0 * w[0] + p1 * w[3] + p2 * w[6];
    float y1 = p0 * w[1] + p1 * w[4] + p2 * w[7];
    float y2 = p0 * w[2] + p1 * w[5] + p2 * w[8];
    float a0 = fmaxf(y0 * sc1[0] + sh1[0], 0.f);
    float a1 = fmaxf(y1 * sc1[1] + sh1[1], 0.f);
    float a2 = fmaxf(y2 * sc1[2] + sh1[2], 0.f);
    float y = a0 * wc0 + a1 * wc1 + a2 * wc2;
    s += y;
    ss += y * y;
  }
  atomicAdd(&stats2[c], s);
  atomicAdd(&stats2[CIN + c], ss);
}

// ---------------- prep: pn normalize + bf16 transposed weights -----------------
__global__ void k_prep(const float* __restrict__ pos_enc,
                       const float* __restrict__ wq,
                       const float* __restrict__ wv,
                       const float* __restrict__ w3,
                       const float* __restrict__ wo, float* __restrict__ pn,
                       __hip_bfloat16* __restrict__ wqT,
                       __hip_bfloat16* __restrict__ wvT,
                       __hip_bfloat16* __restrict__ w3T,
                       __hip_bfloat16* __restrict__ woT) {
  int g = blockIdx.x * 256 + threadIdx.x;
  if (g < KVOL * NHEAD) {
    const float* src = pos_enc + g * CHD;
    float vals[CHD];
    float s = 0.f;
#pragma unroll
    for (int i = 0; i < CHD; ++i) {
      vals[i] = src[i];
      s += vals[i] * vals[i];
    }
    float inv = 1.f / fmaxf(sqrtf(s), EPS_NORM);
#pragma unroll
    for (int i = 0; i < CHD; ++i) pn[g * CHD + i] = vals[i] * inv;
  }
  if (g < CIN * CIN) {
    int k = g >> 7, c = g & 127;
    int gt = c * CIN + k;
    wqT[gt] = __float2bfloat16(wq[g]);
    wvT[gt] = __float2bfloat16(wv[g]);
    w3T[gt] = __float2bfloat16(w3[g]);
    woT[gt] = __float2bfloat16(wo[g]);
  }
}

// ---------------- sort: histogram / scan / scatter -----------------------------
__global__ void k_hist(const int* __restrict__ q_idx, int* __restrict__ cnt,
                       int M) {
  for (int i = blockIdx.x * blockDim.x + threadIdx.x; i < M;
       i += gridDim.x * blockDim.x)
    atomicAdd(&cnt[q_idx[i]], 1);
}

__global__ __launch_bounds__(1024) void k_scan(const int* __restrict__ cnt,
                                               int* __restrict__ offs,
                                               int* __restrict__ cursor, int N) {
  __shared__ int ls[1024];
  int t = threadIdx.x;
  int chunk = (N + 1023) / 1024;
  int start = t * chunk;
  int end = min(start + chunk, N);
  int s = 0;
  for (int i = start; i < end; ++i) s += cnt[i];
  ls[t] = s;
  __syncthreads();
  for (int off = 1; off < 1024; off <<= 1) {
    int v = 0;
    if (t >= off) v = ls[t - off];
    __syncthreads();
    ls[t] += v;
    __syncthreads();
  }
  int run = (t == 0) ? 0 : ls[t - 1];
  for (int i = start; i < end; ++i) {
    int c = cnt[i];
    offs[i] = run;
    cursor[i] = run;
    run += c;
  }
  if (t == 1023) offs[N] = ls[1023];
}

__global__ void k_scatter_rec(const int* __restrict__ q_idx,
                              const int* __restrict__ k_idx,
                              const int* __restrict__ kernel_idx,
                              int* __restrict__ cursor,
                              unsigned* __restrict__ recs, int M) {
  for (int i = blockIdx.x * blockDim.x + threadIdx.x; i < M;
       i += gridDim.x * blockDim.x) {
    int qi = q_idx[i];
    int pos = atomicAdd(&cursor[qi], 1);
    recs[pos] = (unsigned)k_idx[i] | ((unsigned)kernel_idx[i] << 17);
  }
}

// ---------------- qv: full per-point chain via MFMA ----------------------------
// 256 threads = 4 waves, 32 points/block. Wave w owns output cols [32w,32w+32).
__global__ __launch_bounds__(256) void k_qv(
    const float* __restrict__ points, const float* __restrict__ feats,
    const float* __restrict__ w1, const float* __restrict__ g1,
    const float* __restrict__ b1, const float* __restrict__ w2,
    const float* __restrict__ g2, const float* __restrict__ b2,
    const float* __restrict__ b3, const float* __restrict__ bq,
    const float* __restrict__ bv, const __hip_bfloat16* __restrict__ w3T,
    const __hip_bfloat16* __restrict__ wqT,
    const __hip_bfloat16* __restrict__ wvT, const float* __restrict__ stats1,
    const float* __restrict__ stats2, __hip_bfloat16* __restrict__ qn,
    __hip_bfloat16* __restrict__ vout, int N) {
  __shared__ float h0s[32][3];
  __shared__ __hip_bfloat16 h1s[32][136];  // +16B row pad
  __shared__ __hip_bfloat16 xs[32][136];

  int t = threadIdx.x;
  int n0 = blockIdx.x * 32;

  // phase 0: h0 (bn1+relu of points@w1) for 32 points
  if (t < 32) {
    int n = n0 + t;
    float p0 = 0.f, p1 = 0.f, p2 = 0.f;
    if (n < N) {
      p0 = points[3 * n];
      p1 = points[3 * n + 1];
      p2 = points[3 * n + 2];
    }
#pragma unroll
    for (int j = 0; j < 3; ++j) {
      float m = stats1[j] / (float)N;
      float var = stats1[3 + j] / (float)N - m * m;
      float sc = rsqrtf(var + EPS_BN) * g1[j];
      float sh = b1[j] - m * sc;
      float y = p0 * w1[j] + p1 * w1[3 + j] + p2 * w1[6 + j];
      h0s[t][j] = fmaxf(y * sc + sh, 0.f);
    }
  }
  __syncthreads();

  // phase 1: h1 = relu(bn2(h0@w2)) -> LDS bf16
  {
    int c = t & 127, half = t >> 7;
    float m2 = stats2[c] / (float)N;
    float v2 = stats2[CIN + c] / (float)N - m2 * m2;
    float sc2 = rsqrtf(v2 + EPS_BN) * g2[c];
    float sh2 = b2[c] - m2 * sc2;
    float wc0 = w2[c], wc1 = w2[CIN + c], wc2 = w2[2 * CIN + c];
#pragma unroll
    for (int i = 0; i < 16; ++i) {
      int p = i * 2 + half;
      float y = h0s[p][0] * wc0 + h0s[p][1] * wc1 + h0s[p][2] * wc2;
      h1s[p][c] = __float2bfloat16(fmaxf(y * sc2 + sh2, 0.f));
    }
  }
  __syncthreads();

  int w = t >> 6, l = t & 63;
  int lr = l & 15, lg = l >> 4;
  int colbase = w * 32;

  // phase 2: x = feats + h1@w3 + b3 -> LDS bf16
  {
    f32x4 acc[2][2];
#pragma unroll
    for (int nt = 0; nt < 2; ++nt) {
      float bc = b3[colbase + nt * 16 + lr];
#pragma unroll
      for (int mt = 0; mt < 2; ++mt) acc[mt][nt] = {bc, bc, bc, bc};
    }
#pragma unroll
    for (int kk = 0; kk < 4; ++kk) {
      short8 aA[2], bB[2];
#pragma unroll
      for (int mt = 0; mt < 2; ++mt)
        aA[mt] = *(const short8*)((const char*)h1s + (mt * 16 + lr) * 272 +
                                  (kk * 32 + lg * 8) * 2);
#pragma unroll
      for (int nt = 0; nt < 2; ++nt)
        bB[nt] = *(const short8*)((const char*)w3T +
                                  ((size_t)(colbase + nt * 16 + lr) * CIN +
                                   kk * 32 + lg * 8) *
                                      2);
#pragma unroll
      for (int mt = 0; mt < 2; ++mt)
#pragma unroll
        for (int nt = 0; nt < 2; ++nt)
          acc[mt][nt] = __builtin_amdgcn_mfma_f32_16x16x32_bf16(
              aA[mt], bB[nt], acc[mt][nt], 0, 0, 0);
    }
#pragma unroll
    for (int mt = 0; mt < 2; ++mt)
#pragma unroll
      for (int nt = 0; nt < 2; ++nt)
#pragma unroll
        for (int r = 0; r < 4; ++r) {
          int row = mt * 16 + lg * 4 + r;
          int col = colbase + nt * 16 + lr;
          int n = n0 + row;
          float f = (n < N) ? feats[(size_t)n * CIN + col] : 0.f;
          xs[row][col] = __float2bfloat16(acc[mt][nt][r] + f);
        }
  }
  __syncthreads();

  // phase 3: q = x@wq + bq, v = x@wv + bv
  f32x4 aq[2][2], av[2][2];
#pragma unroll
  for (int nt = 0; nt < 2; ++nt) {
    float bqc = bq[colbase + nt * 16 + lr];
    float bvc = bv[colbase + nt * 16 + lr];
#pragma unroll
    for (int mt = 0; mt < 2; ++mt) {
      aq[mt][nt] = {bqc, bqc, bqc, bqc};
      av[mt][nt] = {bvc, bvc, bvc, bvc};
    }
  }
#pragma unroll
  for (int kk = 0; kk < 4; ++kk) {
    short8 aA[2], bQ[2], bV[2];
#pragma unroll
    for (int mt = 0; mt < 2; ++mt)
      aA[mt] = *(const short8*)((const char*)xs + (mt * 16 + lr) * 272 +
                                (kk * 32 + lg * 8) * 2);
#pragma unroll
    for (int nt = 0; nt < 2; ++nt) {
      size_t off =
          ((size_t)(colbase + nt * 16 + lr) * CIN + kk * 32 + lg * 8) * 2;
      bQ[nt] = *(const short8*)((const char*)wqT + off);
      bV[nt] = *(const short8*)((const char*)wvT + off);
    }
#pragma unroll
    for (int mt = 0; mt < 2; ++mt)
#pragma unroll
      for (int nt = 0; nt < 2; ++nt) {
        aq[mt][nt] = __builtin_amdgcn_mfma_f32_16x16x32_bf16(aA[mt], bQ[nt],
                                                             aq[mt][nt], 0, 0, 0);
        av[mt][nt] = __builtin_amdgcn_mfma_f32_16x16x32_bf16(aA[mt], bV[nt],
                                                             av[mt][nt], 0, 0, 0);
      }
  }

  // phase 4: per-head L2 norm of q (each 16-col N-tile == one head), store bf16
#pragma unroll
  for (int mt = 0; mt < 2; ++mt)
#pragma unroll
    for (int nt = 0; nt < 2; ++nt)
#pragma unroll
      for (int r = 0; r < 4; ++r) {
        float q = aq[mt][nt][r];
        float s = q * q;
        s += __shfl_xor(s, 1);
        s += __shfl_xor(s, 2);
        s += __shfl_xor(s, 4);
        s += __shfl_xor(s, 8);
        float inv = 1.f / fmaxf(sqrtf(s), EPS_NORM);
        int row = mt * 16 + lg * 4 + r;
        int col = colbase + nt * 16 + lr;
        int n = n0 + row;
        if (n < N) {
          qn[(size_t)n * CIN + col] = __float2bfloat16(q * inv);
          vout[(size_t)n * CIN + col] = __float2bfloat16(av[mt][nt][r]);
        }
      }
}

// ---------------- attn: per-point dot table + pipelined gather + MFMA out ------
// 512 threads = 8 waves = 8 points/block; lane l owns channels {2l, 2l+1}.
__global__ __launch_bounds__(512) void k_attn_out(
    const unsigned* __restrict__ recs, const int* __restrict__ offs,
    const __hip_bfloat16* __restrict__ qn, const __hip_bfloat16* __restrict__ v,
    const float* __restrict__ pn, const __hip_bfloat16* __restrict__ woT,
    const float* __restrict__ bo, float* __restrict__ out, int N) {
  __shared__ float dots[8][KVOL * NHEAD];   // 6.9 KB
  __shared__ __hip_bfloat16 a_lds[16][136]; // 4.35 KB (+16B row pad)
  int t = threadIdx.x;
  int w = t >> 6, l = t & 63;
  int n = blockIdx.x * 8 + w;
  int h = l >> 3;

  // precompute all 27 head-dots for this wave's point
  float qx = 0.f, qy = 0.f;
  if (n < N) {
    unsigned qw = *(const unsigned*)((const char*)qn + ((size_t)n * CIN + 2 * l) * 2);
    qx = bflo(qw);
    qy = bfhi(qw);
    const float2* pn2 = (const float2*)pn;
#pragma unroll
    for (int kk = 0; kk < KVOL; ++kk) {
      float2 p2 = pn2[kk * 64 + l];
      float d = qx * p2.x + qy * p2.y;
      d += __shfl_xor(d, 1);
      d += __shfl_xor(d, 2);
      d += __shfl_xor(d, 4);
      if ((l & 7) == 0) dots[w][kk * NHEAD + h] = d;
    }
  }
  // zero the pad rows 8..15 of a_lds
  for (int i = t; i < 544; i += 512) ((unsigned*)((char*)a_lds + 8 * 272))[i] = 0u;
  __syncthreads();

  // gather-reduce: ax,ay accumulate attn * v over this point's records
  float ax = 0.f, ay = 0.f;
  if (n < N) {
    int beg = offs[n], end = offs[n + 1];
    const char* vbase = (const char*)v + 4 * l;
    int idx = beg;
    for (; idx + 4 <= end; idx += 4) {
      unsigned r0 = recs[idx], r1 = recs[idx + 1], r2 = recs[idx + 2],
               r3 = recs[idx + 3];
      unsigned v0 = *(const unsigned*)(vbase + (size_t)(r0 & 0x1FFFF) * 256);
      unsigned v1 = *(const unsigned*)(vbase + (size_t)(r1 & 0x1FFFF) * 256);
      unsigned v2 = *(const unsigned*)(vbase + (size_t)(r2 & 0x1FFFF) * 256);
      unsigned v3 = *(const unsigned*)(vbase + (size_t)(r3 & 0x1FFFF) * 256);
      float a0 = dots[w][(r0 >> 17) * NHEAD + h];
      float a1 = dots[w][(r1 >> 17) * NHEAD + h];
      float a2 = dots[w][(r2 >> 17) * NHEAD + h];
      float a3 = dots[w][(r3 >> 17) * NHEAD + h];
      ax += a0 * bflo(v0);
      ay += a0 * bfhi(v0);
      ax += a1 * bflo(v1);
      ay += a1 * bfhi(v1);
      ax += a2 * bflo(v2);
      ay += a2 * bfhi(v2);
      ax += a3 * bflo(v3);
      ay += a3 * bfhi(v3);
    }
    for (; idx < end; ++idx) {
      unsigned r0 = recs[idx];
      unsigned v0 = *(const unsigned*)(vbase + (size_t)(r0 & 0x1FFFF) * 256);
      float a0 = dots[w][(r0 >> 17) * NHEAD + h];
      ax += a0 * bflo(v0);
      ay += a0 * bfhi(v0);
    }
  }
  a_lds[w][2 * l] = __float2bfloat16(ax);
  a_lds[w][2 * l + 1] = __float2bfloat16(ay);
  __syncthreads();

  // MFMA epilogue: out[8][128] = a_lds(16x128, rows 8..15 zero) @ wo + bo
  int lr = l & 15, lg = l >> 4;
  float bc = bo[16 * w + lr];
  f32x4 acc = {bc, bc, bc, bc};
#pragma unroll
  for (int kk = 0; kk < 4; ++kk) {
    short8 aA = *(const short8*)((const char*)a_lds + lr * 272 +
                                 (kk * 32 + lg * 8) * 2);
    short8 bB = *(const short8*)((const char*)woT +
                                 ((size_t)(16 * w + lr) * CIN + kk * 32 + lg * 8) * 2);
    acc = __builtin_amdgcn_mfma_f32_16x16x32_bf16(aA, bB, acc, 0, 0, 0);
  }
#pragma unroll
  for (int r = 0; r < 4; ++r) {
    int row = lg * 4 + r;
    if (row < 8) {
      int nn = blockIdx.x * 8 + row;
      if (nn < N) out[(size_t)nn * CIN + 16 * w + lr] = acc[r];
    }
  }
}

// ---------------- launch -------------------------------------------------------
extern "C" void kernel_launch(void* const* d_in, const int* in_sizes, int n_in,
                              void* d_out, int out_size, void* d_ws,
                              size_t ws_size, hipStream_t stream) {
  const float* points = (const float*)d_in[0];
  const float* feats = (const float*)d_in[1];
  const int* k_idx = (const int*)d_in[2];
  const int* q_idx = (const int*)d_in[3];
  const int* kernel_idx = (const int*)d_in[4];
  const float* w1 = (const float*)d_in[5];
  const float* g1 = (const float*)d_in[6];
  const float* b1 = (const float*)d_in[7];
  const float* w2 = (const float*)d_in[8];
  const float* g2 = (const float*)d_in[9];
  const float* b2 = (const float*)d_in[10];
  const float* w3 = (const float*)d_in[11];
  const float* b3 = (const float*)d_in[12];
  const float* wq = (const float*)d_in[13];
  const float* bq = (const float*)d_in[14];
  const float* wv = (const float*)d_in[15];
  const float* bv = (const float*)d_in[16];
  const float* wo = (const float*)d_in[17];
  const float* bo = (const float*)d_in[18];
  const float* pos_enc = (const float*)d_in[19];

  int N = in_sizes[0] / 3;
  int M = in_sizes[2];

  float* ws = (float*)d_ws;
  float* stats1 = ws;        // 8
  float* stats2 = ws + 8;    // 256
  float* pn = ws + 264;      // 3456 (ends at 3720 < 4096)
  int* cnt = (int*)(ws + 4096);
  int* offs = cnt + N;
  int* cursor = offs + N + 1;
  unsigned* recs = (unsigned*)(cursor + N);
  __hip_bfloat16* qn = (__hip_bfloat16*)(recs + M);
  __hip_bfloat16* vb = qn + (size_t)N * CIN;
  __hip_bfloat16* wqT = vb + (size_t)N * CIN;
  __hip_bfloat16* wvT = wqT + CIN * CIN;
  __hip_bfloat16* w3T = wvT + CIN * CIN;
  __hip_bfloat16* woT = w3T + CIN * CIN;
  float* outf = (float*)d_out;

  hipMemsetAsync(ws, 0, 4096 * sizeof(float), stream);
  hipMemsetAsync(cnt, 0, (size_t)N * sizeof(int), stream);

  k_bn1_stats<<<256, 256, 0, stream>>>(points, w1, stats1, N);
  k_bn2_stats<<<512, 128, 0, stream>>>(points, w1, g1, b1, w2, stats1, stats2, N);
  k_prep<<<64, 256, 0, stream>>>(pos_enc, wq, wv, w3, wo, pn, wqT, wvT, w3T, woT);
  k_hist<<<2048, 256, 0, stream>>>(q_idx, cnt, M);
  k_scan<<<1, 1024, 0, stream>>>(cnt, offs, cursor, N);
  k_scatter_rec<<<2048, 256, 0, stream>>>(q_idx, k_idx, kernel_idx, cursor, recs, M);
  k_qv<<<(N + 31) / 32, 256, 0, stream>>>(points, feats, w1, g1, b1, w2, g2, b2,
                                          b3, bq, bv, w3T, wqT, wvT, stats1,
                                          stats2, qn, vb, N);
  k_attn_out<<<(N + 7) / 8, 512, 0, stream>>>(recs, offs, qn, vb, pn, woT, bo,
                                              outf, N);
}

// Round 6
// 739.649 us; speedup vs baseline: 1.2140x; 1.0569x over previous
//
#include <hip/hip_runtime.h>
#include <hip/hip_bf16.h>

#define CIN 128
#define NHEAD 8
#define CHD 16
#define KVOL 27

constexpr float EPS_BN = 1e-5f;
constexpr float EPS_NORM = 1e-12f;

typedef __attribute__((ext_vector_type(8))) short short8;
typedef __attribute__((ext_vector_type(4))) float f32x4;

__device__ __forceinline__ float bflo(unsigned u) {
  return __uint_as_float(u << 16);
}
__device__ __forceinline__ float bfhi(unsigned u) {
  return __uint_as_float(u & 0xffff0000u);
}

// ---------------- BN1 statistics ----------------------------------------------
__global__ void k_bn1_stats(const float* __restrict__ points,
                            const float* __restrict__ w1,
                            float* __restrict__ stats1, int N) {
  float w[9];
#pragma unroll
  for (int i = 0; i < 9; ++i) w[i] = w1[i];
  float s[3] = {0.f, 0.f, 0.f}, ss[3] = {0.f, 0.f, 0.f};
  for (int n = blockIdx.x * blockDim.x + threadIdx.x; n < N;
       n += gridDim.x * blockDim.x) {
    float p0 = points[3 * n], p1 = points[3 * n + 1], p2 = points[3 * n + 2];
#pragma unroll
    for (int j = 0; j < 3; ++j) {
      float y = p0 * w[j] + p1 * w[3 + j] + p2 * w[6 + j];
      s[j] += y;
      ss[j] += y * y;
    }
  }
#pragma unroll
  for (int j = 0; j < 3; ++j) {
    for (int off = 32; off > 0; off >>= 1) {
      s[j] += __shfl_down(s[j], off);
      ss[j] += __shfl_down(ss[j], off);
    }
  }
  if ((threadIdx.x & 63) == 0) {
#pragma unroll
    for (int j = 0; j < 3; ++j) {
      atomicAdd(&stats1[j], s[j]);
      atomicAdd(&stats1[3 + j], ss[j]);
    }
  }
}

// ---------------- BN2 statistics ----------------------------------------------
__global__ void k_bn2_stats(const float* __restrict__ points,
                            const float* __restrict__ w1,
                            const float* __restrict__ g1,
                            const float* __restrict__ b1,
                            const float* __restrict__ w2,
                            const float* __restrict__ stats1,
                            float* __restrict__ stats2, int N) {
  int c = threadIdx.x;
  float w[9];
#pragma unroll
  for (int i = 0; i < 9; ++i) w[i] = w1[i];
  float sc1[3], sh1[3];
#pragma unroll
  for (int j = 0; j < 3; ++j) {
    float m = stats1[j] / (float)N;
    float var = stats1[3 + j] / (float)N - m * m;
    float sc = rsqrtf(var + EPS_BN) * g1[j];
    sc1[j] = sc;
    sh1[j] = b1[j] - m * sc;
  }
  float wc0 = w2[c], wc1 = w2[CIN + c], wc2 = w2[2 * CIN + c];
  float s = 0.f, ss = 0.f;
  for (int n = blockIdx.x; n < N; n += gridDim.x) {
    float p0 = points[3 * n], p1 = points[3 * n + 1], p2 = points[3 * n + 2];
    float y0 = p0 * w[0] + p1 * w[3] + p2 * w[6];
    float y1 = p0 * w[1] + p1 * w[4] + p2 * w[7];
    float y2 = p0 * w[2] + p1 * w[5] + p2 * w[8];
    float a0 = fmaxf(y0 * sc1[0] + sh1[0], 0.f);
    float a1 = fmaxf(y1 * sc1[1] + sh1[1], 0.f);
    float a2 = fmaxf(y2 * sc1[2] + sh1[2], 0.f);
    float y = a0 * wc0 + a1 * wc1 + a2 * wc2;
    s += y;
    ss += y * y;
  }
  atomicAdd(&stats2[c], s);
  atomicAdd(&stats2[CIN + c], ss);
}

// ---------------- prep: pn normalize + bf16 transposed weights -----------------
__global__ void k_prep(const float* __restrict__ pos_enc,
                       const float* __restrict__ wq,
                       const float* __restrict__ wv,
                       const float* __restrict__ w3,
                       const float* __restrict__ wo, float* __restrict__ pn,
                       __hip_bfloat16* __restrict__ wqT,
                       __hip_bfloat16* __restrict__ wvT,
                       __hip_bfloat16* __restrict__ w3T,
                       __hip_bfloat16* __restrict__ woT) {
  int g = blockIdx.x * 256 + threadIdx.x;
  if (g < KVOL * NHEAD) {
    const float* src = pos_enc + g * CHD;
    float vals[CHD];
    float s = 0.f;
#pragma unroll
    for (int i = 0; i < CHD; ++i) {
      vals[i] = src[i];
      s += vals[i] * vals[i];
    }
    float inv = 1.f / fmaxf(sqrtf(s), EPS_NORM);
#pragma unroll
    for (int i = 0; i < CHD; ++i) pn[g * CHD + i] = vals[i] * inv;
  }
  if (g < CIN * CIN) {
    int k = g >> 7, c = g & 127;
    int gt = c * CIN + k;
    wqT[gt] = __float2bfloat16(wq[g]);
    wvT[gt] = __float2bfloat16(wv[g]);
    w3T[gt] = __float2bfloat16(w3[g]);
    woT[gt] = __float2bfloat16(wo[g]);
  }
}

// ---------------- sort: histogram / padded scan / scatter / pad ----------------
__global__ void k_hist(const int* __restrict__ q_idx, int* __restrict__ cnt,
                       int M) {
  for (int i = blockIdx.x * blockDim.x + threadIdx.x; i < M;
       i += gridDim.x * blockDim.x)
    atomicAdd(&cnt[q_idx[i]], 1);
}

// single block: exclusive scan of PADDED counts (ceil(cnt/8)*8) -> poffs, cursor
__global__ __launch_bounds__(1024) void k_scan(const int* __restrict__ cnt,
                                               int* __restrict__ poffs,
                                               int* __restrict__ cursor, int N) {
  __shared__ int ls[1024];
  int t = threadIdx.x;
  int chunk = (N + 1023) / 1024;
  int start = t * chunk;
  int end = min(start + chunk, N);
  int s = 0;
  for (int i = start; i < end; ++i) s += (cnt[i] + 7) & ~7;
  ls[t] = s;
  __syncthreads();
  for (int off = 1; off < 1024; off <<= 1) {
    int v = 0;
    if (t >= off) v = ls[t - off];
    __syncthreads();
    ls[t] += v;
    __syncthreads();
  }
  int run = (t == 0) ? 0 : ls[t - 1];
  for (int i = start; i < end; ++i) {
    int pc = (cnt[i] + 7) & ~7;
    poffs[i] = run;
    cursor[i] = run;
    run += pc;
  }
  if (t == 1023) poffs[N] = ls[1023];
}

// fill pad slots with dummy record (kk=27 -> dot 0, ki=0)
__global__ void k_pad(const int* __restrict__ cnt, const int* __restrict__ poffs,
                      unsigned* __restrict__ recs, int N) {
  int n = blockIdx.x * 256 + threadIdx.x;
  if (n >= N) return;
  int b = poffs[n] + cnt[n];
  int e = poffs[n + 1];
  for (int i = b; i < e; ++i) recs[i] = 27u << 17;
}

__global__ void k_scatter_rec(const int* __restrict__ q_idx,
                              const int* __restrict__ k_idx,
                              const int* __restrict__ kernel_idx,
                              int* __restrict__ cursor,
                              unsigned* __restrict__ recs, int M) {
  for (int i = blockIdx.x * blockDim.x + threadIdx.x; i < M;
       i += gridDim.x * blockDim.x) {
    int qi = q_idx[i];
    int pos = atomicAdd(&cursor[qi], 1);
    recs[pos] = (unsigned)k_idx[i] | ((unsigned)kernel_idx[i] << 17);
  }
}

// ---------------- qv: full per-point chain via MFMA ----------------------------
__global__ __launch_bounds__(256) void k_qv(
    const float* __restrict__ points, const float* __restrict__ feats,
    const float* __restrict__ w1, const float* __restrict__ g1,
    const float* __restrict__ b1, const float* __restrict__ w2,
    const float* __restrict__ g2, const float* __restrict__ b2,
    const float* __restrict__ b3, const float* __restrict__ bq,
    const float* __restrict__ bv, const __hip_bfloat16* __restrict__ w3T,
    const __hip_bfloat16* __restrict__ wqT,
    const __hip_bfloat16* __restrict__ wvT, const float* __restrict__ stats1,
    const float* __restrict__ stats2, __hip_bfloat16* __restrict__ qn,
    __hip_bfloat16* __restrict__ vout, int N) {
  __shared__ float h0s[32][3];
  __shared__ __hip_bfloat16 h1s[32][136];
  __shared__ __hip_bfloat16 xs[32][136];

  int t = threadIdx.x;
  int n0 = blockIdx.x * 32;

  if (t < 32) {
    int n = n0 + t;
    float p0 = 0.f, p1 = 0.f, p2 = 0.f;
    if (n < N) {
      p0 = points[3 * n];
      p1 = points[3 * n + 1];
      p2 = points[3 * n + 2];
    }
#pragma unroll
    for (int j = 0; j < 3; ++j) {
      float m = stats1[j] / (float)N;
      float var = stats1[3 + j] / (float)N - m * m;
      float sc = rsqrtf(var + EPS_BN) * g1[j];
      float sh = b1[j] - m * sc;
      float y = p0 * w1[j] + p1 * w1[3 + j] + p2 * w1[6 + j];
      h0s[t][j] = fmaxf(y * sc + sh, 0.f);
    }
  }
  __syncthreads();

  {
    int c = t & 127, half = t >> 7;
    float m2 = stats2[c] / (float)N;
    float v2 = stats2[CIN + c] / (float)N - m2 * m2;
    float sc2 = rsqrtf(v2 + EPS_BN) * g2[c];
    float sh2 = b2[c] - m2 * sc2;
    float wc0 = w2[c], wc1 = w2[CIN + c], wc2 = w2[2 * CIN + c];
#pragma unroll
    for (int i = 0; i < 16; ++i) {
      int p = i * 2 + half;
      float y = h0s[p][0] * wc0 + h0s[p][1] * wc1 + h0s[p][2] * wc2;
      h1s[p][c] = __float2bfloat16(fmaxf(y * sc2 + sh2, 0.f));
    }
  }
  __syncthreads();

  int w = t >> 6, l = t & 63;
  int lr = l & 15, lg = l >> 4;
  int colbase = w * 32;

  {
    f32x4 acc[2][2];
#pragma unroll
    for (int nt = 0; nt < 2; ++nt) {
      float bc = b3[colbase + nt * 16 + lr];
#pragma unroll
      for (int mt = 0; mt < 2; ++mt) acc[mt][nt] = {bc, bc, bc, bc};
    }
#pragma unroll
    for (int kk = 0; kk < 4; ++kk) {
      short8 aA[2], bB[2];
#pragma unroll
      for (int mt = 0; mt < 2; ++mt)
        aA[mt] = *(const short8*)((const char*)h1s + (mt * 16 + lr) * 272 +
                                  (kk * 32 + lg * 8) * 2);
#pragma unroll
      for (int nt = 0; nt < 2; ++nt)
        bB[nt] = *(const short8*)((const char*)w3T +
                                  ((size_t)(colbase + nt * 16 + lr) * CIN +
                                   kk * 32 + lg * 8) *
                                      2);
#pragma unroll
      for (int mt = 0; mt < 2; ++mt)
#pragma unroll
        for (int nt = 0; nt < 2; ++nt)
          acc[mt][nt] = __builtin_amdgcn_mfma_f32_16x16x32_bf16(
              aA[mt], bB[nt], acc[mt][nt], 0, 0, 0);
    }
#pragma unroll
    for (int mt = 0; mt < 2; ++mt)
#pragma unroll
      for (int nt = 0; nt < 2; ++nt)
#pragma unroll
        for (int r = 0; r < 4; ++r) {
          int row = mt * 16 + lg * 4 + r;
          int col = colbase + nt * 16 + lr;
          int n = n0 + row;
          float f = (n < N) ? feats[(size_t)n * CIN + col] : 0.f;
          xs[row][col] = __float2bfloat16(acc[mt][nt][r] + f);
        }
  }
  __syncthreads();

  f32x4 aq[2][2], av[2][2];
#pragma unroll
  for (int nt = 0; nt < 2; ++nt) {
    float bqc = bq[colbase + nt * 16 + lr];
    float bvc = bv[colbase + nt * 16 + lr];
#pragma unroll
    for (int mt = 0; mt < 2; ++mt) {
      aq[mt][nt] = {bqc, bqc, bqc, bqc};
      av[mt][nt] = {bvc, bvc, bvc, bvc};
    }
  }
#pragma unroll
  for (int kk = 0; kk < 4; ++kk) {
    short8 aA[2], bQ[2], bV[2];
#pragma unroll
    for (int mt = 0; mt < 2; ++mt)
      aA[mt] = *(const short8*)((const char*)xs + (mt * 16 + lr) * 272 +
                                (kk * 32 + lg * 8) * 2);
#pragma unroll
    for (int nt = 0; nt < 2; ++nt) {
      size_t off =
          ((size_t)(colbase + nt * 16 + lr) * CIN + kk * 32 + lg * 8) * 2;
      bQ[nt] = *(const short8*)((const char*)wqT + off);
      bV[nt] = *(const short8*)((const char*)wvT + off);
    }
#pragma unroll
    for (int mt = 0; mt < 2; ++mt)
#pragma unroll
      for (int nt = 0; nt < 2; ++nt) {
        aq[mt][nt] = __builtin_amdgcn_mfma_f32_16x16x32_bf16(aA[mt], bQ[nt],
                                                             aq[mt][nt], 0, 0, 0);
        av[mt][nt] = __builtin_amdgcn_mfma_f32_16x16x32_bf16(aA[mt], bV[nt],
                                                             av[mt][nt], 0, 0, 0);
      }
  }

#pragma unroll
  for (int mt = 0; mt < 2; ++mt)
#pragma unroll
    for (int nt = 0; nt < 2; ++nt)
#pragma unroll
      for (int r = 0; r < 4; ++r) {
        float q = aq[mt][nt][r];
        float s = q * q;
        s += __shfl_xor(s, 1);
        s += __shfl_xor(s, 2);
        s += __shfl_xor(s, 4);
        s += __shfl_xor(s, 8);
        float inv = 1.f / fmaxf(sqrtf(s), EPS_NORM);
        int row = mt * 16 + lg * 4 + r;
        int col = colbase + nt * 16 + lr;
        int n = n0 + row;
        if (n < N) {
          qn[(size_t)n * CIN + col] = __float2bfloat16(q * inv);
          vout[(size_t)n * CIN + col] = __float2bfloat16(av[mt][nt][r]);
        }
      }
}

// ---------------- gather: one wave per point, no barriers, 8-deep --------------
__global__ __launch_bounds__(256) void k_gather(
    const unsigned* __restrict__ recs, const int* __restrict__ poffs,
    const unsigned* __restrict__ qn32, const __hip_bfloat16* __restrict__ v,
    const float* __restrict__ pn, unsigned* __restrict__ accb, int N) {
  __shared__ float dots[4][(KVOL + 1) * NHEAD];  // 4 x 224 floats
  int t = threadIdx.x;
  int w = t >> 6, l = t & 63;
  int h = l >> 3;
  const float2* pn2 = (const float2*)pn;
  const char* vbase = (const char*)v + 4 * l;

  for (int n = blockIdx.x * 4 + w; n < N; n += gridDim.x * 4) {
    // per-point dot table (27 kernels x 8 heads), slot 27 = 0 for pad records
    unsigned qw = qn32[(size_t)n * 64 + l];
    float qx = bflo(qw), qy = bfhi(qw);
#pragma unroll
    for (int kk = 0; kk < KVOL; ++kk) {
      float2 p2 = pn2[kk * 64 + l];
      float d = qx * p2.x + qy * p2.y;
      d += __shfl_xor(d, 1);
      d += __shfl_xor(d, 2);
      d += __shfl_xor(d, 4);
      if ((l & 7) == 0) dots[w][kk * NHEAD + h] = d;
    }
    if ((l & 7) == 0) dots[w][KVOL * NHEAD + h] = 0.f;

    float ax = 0.f, ay = 0.f;
    int beg = poffs[n], end = poffs[n + 1];
    for (int idx = beg; idx < end; idx += 8) {
      unsigned r0 = recs[idx + 0], r1 = recs[idx + 1], r2 = recs[idx + 2],
               r3 = recs[idx + 3], r4 = recs[idx + 4], r5 = recs[idx + 5],
               r6 = recs[idx + 6], r7 = recs[idx + 7];
      unsigned v0 = *(const unsigned*)(vbase + (size_t)(r0 & 0x1FFFF) * 256);
      unsigned v1 = *(const unsigned*)(vbase + (size_t)(r1 & 0x1FFFF) * 256);
      unsigned v2 = *(const unsigned*)(vbase + (size_t)(r2 & 0x1FFFF) * 256);
      unsigned v3 = *(const unsigned*)(vbase + (size_t)(r3 & 0x1FFFF) * 256);
      unsigned v4 = *(const unsigned*)(vbase + (size_t)(r4 & 0x1FFFF) * 256);
      unsigned v5 = *(const unsigned*)(vbase + (size_t)(r5 & 0x1FFFF) * 256);
      unsigned v6 = *(const unsigned*)(vbase + (size_t)(r6 & 0x1FFFF) * 256);
      unsigned v7 = *(const unsigned*)(vbase + (size_t)(r7 & 0x1FFFF) * 256);
      float a0 = dots[w][(r0 >> 17) * NHEAD + h];
      float a1 = dots[w][(r1 >> 17) * NHEAD + h];
      float a2 = dots[w][(r2 >> 17) * NHEAD + h];
      float a3 = dots[w][(r3 >> 17) * NHEAD + h];
      float a4 = dots[w][(r4 >> 17) * NHEAD + h];
      float a5 = dots[w][(r5 >> 17) * NHEAD + h];
      float a6 = dots[w][(r6 >> 17) * NHEAD + h];
      float a7 = dots[w][(r7 >> 17) * NHEAD + h];
      ax += a0 * bflo(v0);
      ay += a0 * bfhi(v0);
      ax += a1 * bflo(v1);
      ay += a1 * bfhi(v1);
      ax += a2 * bflo(v2);
      ay += a2 * bfhi(v2);
      ax += a3 * bflo(v3);
      ay += a3 * bfhi(v3);
      ax += a4 * bflo(v4);
      ay += a4 * bfhi(v4);
      ax += a5 * bflo(v5);
      ay += a5 * bfhi(v5);
      ax += a6 * bflo(v6);
      ay += a6 * bfhi(v6);
      ax += a7 * bflo(v7);
      ay += a7 * bfhi(v7);
    }
    __hip_bfloat16 bx = __float2bfloat16(ax), by = __float2bfloat16(ay);
    unsigned pk = (unsigned)*(unsigned short*)&bx |
                  ((unsigned)*(unsigned short*)&by << 16);
    accb[(size_t)n * 64 + l] = pk;
  }
}

// ---------------- out2: out = accb @ wo + bo (MFMA, 32 rows/block) -------------
__global__ __launch_bounds__(256) void k_out2(
    const __hip_bfloat16* __restrict__ accb,
    const __hip_bfloat16* __restrict__ woT, const float* __restrict__ bo,
    float* __restrict__ out, int N) {
  int t = threadIdx.x;
  int w = t >> 6, l = t & 63;
  int lr = l & 15, lg = l >> 4;
  int colbase = w * 32;
  int n0 = blockIdx.x * 32;

  f32x4 acc[2][2];
#pragma unroll
  for (int nt = 0; nt < 2; ++nt) {
    float bc = bo[colbase + nt * 16 + lr];
#pragma unroll
    for (int mt = 0; mt < 2; ++mt) acc[mt][nt] = {bc, bc, bc, bc};
  }
#pragma unroll
  for (int kk = 0; kk < 4; ++kk) {
    short8 aA[2], bB[2];
#pragma unroll
    for (int mt = 0; mt < 2; ++mt)
      aA[mt] = *(const short8*)((const char*)accb +
                                ((size_t)(n0 + mt * 16 + lr) * CIN + kk * 32 +
                                 lg * 8) *
                                    2);
#pragma unroll
    for (int nt = 0; nt < 2; ++nt)
      bB[nt] = *(const short8*)((const char*)woT +
                                ((size_t)(colbase + nt * 16 + lr) * CIN +
                                 kk * 32 + lg * 8) *
                                    2);
#pragma unroll
    for (int mt = 0; mt < 2; ++mt)
#pragma unroll
      for (int nt = 0; nt < 2; ++nt)
        acc[mt][nt] = __builtin_amdgcn_mfma_f32_16x16x32_bf16(aA[mt], bB[nt],
                                                              acc[mt][nt], 0, 0, 0);
  }
#pragma unroll
  for (int mt = 0; mt < 2; ++mt)
#pragma unroll
    for (int nt = 0; nt < 2; ++nt)
#pragma unroll
      for (int r = 0; r < 4; ++r) {
        int n = n0 + mt * 16 + lg * 4 + r;
        if (n < N) out[(size_t)n * CIN + colbase + nt * 16 + lr] = acc[mt][nt][r];
      }
}

// ---------------- launch -------------------------------------------------------
extern "C" void kernel_launch(void* const* d_in, const int* in_sizes, int n_in,
                              void* d_out, int out_size, void* d_ws,
                              size_t ws_size, hipStream_t stream) {
  const float* points = (const float*)d_in[0];
  const float* feats = (const float*)d_in[1];
  const int* k_idx = (const int*)d_in[2];
  const int* q_idx = (const int*)d_in[3];
  const int* kernel_idx = (const int*)d_in[4];
  const float* w1 = (const float*)d_in[5];
  const float* g1 = (const float*)d_in[6];
  const float* b1 = (const float*)d_in[7];
  const float* w2 = (const float*)d_in[8];
  const float* g2 = (const float*)d_in[9];
  const float* b2 = (const float*)d_in[10];
  const float* w3 = (const float*)d_in[11];
  const float* b3 = (const float*)d_in[12];
  const float* wq = (const float*)d_in[13];
  const float* bq = (const float*)d_in[14];
  const float* wv = (const float*)d_in[15];
  const float* bv = (const float*)d_in[16];
  const float* wo = (const float*)d_in[17];
  const float* bo = (const float*)d_in[18];
  const float* pos_enc = (const float*)d_in[19];

  int N = in_sizes[0] / 3;
  int M = in_sizes[2];

  float* ws = (float*)d_ws;
  float* stats1 = ws;        // 8
  float* stats2 = ws + 8;    // 256
  float* pn = ws + 264;      // 3456 (ends < 4096)
  int* cnt = (int*)(ws + 4096);              // N
  int* poffs = cnt + N;                      // N+1
  int* cursor = poffs + N + 1;               // N
  unsigned* recs = (unsigned*)(cursor + N);  // M + 8N (padded)
  __hip_bfloat16* qn = (__hip_bfloat16*)(recs + M + 8 * (size_t)N);
  __hip_bfloat16* vb = qn + (size_t)N * CIN;
  __hip_bfloat16* accb = vb + (size_t)N * CIN;     // N*CIN bf16
  __hip_bfloat16* wqT = accb + (size_t)N * CIN;    // also OOB-read slack for out2
  __hip_bfloat16* wvT = wqT + CIN * CIN;
  __hip_bfloat16* w3T = wvT + CIN * CIN;
  __hip_bfloat16* woT = w3T + CIN * CIN;
  float* outf = (float*)d_out;

  hipMemsetAsync(ws, 0, 4096 * sizeof(float), stream);
  hipMemsetAsync(cnt, 0, (size_t)N * sizeof(int), stream);

  k_bn1_stats<<<256, 256, 0, stream>>>(points, w1, stats1, N);
  k_bn2_stats<<<512, 128, 0, stream>>>(points, w1, g1, b1, w2, stats1, stats2, N);
  k_prep<<<64, 256, 0, stream>>>(pos_enc, wq, wv, w3, wo, pn, wqT, wvT, w3T, woT);
  k_hist<<<2048, 256, 0, stream>>>(q_idx, cnt, M);
  k_scan<<<1, 1024, 0, stream>>>(cnt, poffs, cursor, N);
  k_pad<<<(N + 255) / 256, 256, 0, stream>>>(cnt, poffs, recs, N);
  k_scatter_rec<<<2048, 256, 0, stream>>>(q_idx, k_idx, kernel_idx, cursor, recs, M);
  k_qv<<<(N + 31) / 32, 256, 0, stream>>>(points, feats, w1, g1, b1, w2, g2, b2,
                                          b3, bq, bv, w3T, wqT, wvT, stats1,
                                          stats2, qn, vb, N);
  k_gather<<<2048, 256, 0, stream>>>(recs, poffs, (const unsigned*)qn, vb, pn,
                                     (unsigned*)accb, N);
  k_out2<<<(N + 31) / 32, 256, 0, stream>>>(accb, woT, bo, outf, N);
}

// Round 7
// 521.431 us; speedup vs baseline: 1.7221x; 1.4185x over previous
//
#include <hip/hip_runtime.h>
#include <hip/hip_bf16.h>

#define CIN 128
#define NHEAD 8
#define CHD 16
#define KVOL 27

constexpr float EPS_BN = 1e-5f;
constexpr float EPS_NORM = 1e-12f;

typedef __attribute__((ext_vector_type(8))) short short8;
typedef __attribute__((ext_vector_type(4))) float f32x4;

__device__ __forceinline__ float bflo(unsigned u) {
  return __uint_as_float(u << 16);
}
__device__ __forceinline__ float bfhi(unsigned u) {
  return __uint_as_float(u & 0xffff0000u);
}

// ---------------- BN1 statistics ----------------------------------------------
__global__ void k_bn1_stats(const float* __restrict__ points,
                            const float* __restrict__ w1,
                            float* __restrict__ stats1, int N) {
  float w[9];
#pragma unroll
  for (int i = 0; i < 9; ++i) w[i] = w1[i];
  float s[3] = {0.f, 0.f, 0.f}, ss[3] = {0.f, 0.f, 0.f};
  for (int n = blockIdx.x * blockDim.x + threadIdx.x; n < N;
       n += gridDim.x * blockDim.x) {
    float p0 = points[3 * n], p1 = points[3 * n + 1], p2 = points[3 * n + 2];
#pragma unroll
    for (int j = 0; j < 3; ++j) {
      float y = p0 * w[j] + p1 * w[3 + j] + p2 * w[6 + j];
      s[j] += y;
      ss[j] += y * y;
    }
  }
#pragma unroll
  for (int j = 0; j < 3; ++j) {
    for (int off = 32; off > 0; off >>= 1) {
      s[j] += __shfl_down(s[j], off);
      ss[j] += __shfl_down(ss[j], off);
    }
  }
  if ((threadIdx.x & 63) == 0) {
#pragma unroll
    for (int j = 0; j < 3; ++j) {
      atomicAdd(&stats1[j], s[j]);
      atomicAdd(&stats1[3 + j], ss[j]);
    }
  }
}

// ---------------- BN2 statistics ----------------------------------------------
__global__ void k_bn2_stats(const float* __restrict__ points,
                            const float* __restrict__ w1,
                            const float* __restrict__ g1,
                            const float* __restrict__ b1,
                            const float* __restrict__ w2,
                            const float* __restrict__ stats1,
                            float* __restrict__ stats2, int N) {
  int c = threadIdx.x;
  float w[9];
#pragma unroll
  for (int i = 0; i < 9; ++i) w[i] = w1[i];
  float sc1[3], sh1[3];
#pragma unroll
  for (int j = 0; j < 3; ++j) {
    float m = stats1[j] / (float)N;
    float var = stats1[3 + j] / (float)N - m * m;
    float sc = rsqrtf(var + EPS_BN) * g1[j];
    sc1[j] = sc;
    sh1[j] = b1[j] - m * sc;
  }
  float wc0 = w2[c], wc1 = w2[CIN + c], wc2 = w2[2 * CIN + c];
  float s = 0.f, ss = 0.f;
  for (int n = blockIdx.x; n < N; n += gridDim.x) {
    float p0 = points[3 * n], p1 = points[3 * n + 1], p2 = points[3 * n + 2];
    float y0 = p0 * w[0] + p1 * w[3] + p2 * w[6];
    float y1 = p0 * w[1] + p1 * w[4] + p2 * w[7];
    float y2 = p0 * w[2] + p1 * w[5] + p2 * w[8];
    float a0 = fmaxf(y0 * sc1[0] + sh1[0], 0.f);
    float a1 = fmaxf(y1 * sc1[1] + sh1[1], 0.f);
    float a2 = fmaxf(y2 * sc1[2] + sh1[2], 0.f);
    float y = a0 * wc0 + a1 * wc1 + a2 * wc2;
    s += y;
    ss += y * y;
  }
  atomicAdd(&stats2[c], s);
  atomicAdd(&stats2[CIN + c], ss);
}

// ---------------- prep: pn normalize + bf16 transposed weights -----------------
__global__ void k_prep(const float* __restrict__ pos_enc,
                       const float* __restrict__ wq,
                       const float* __restrict__ wv,
                       const float* __restrict__ w3,
                       const float* __restrict__ wo, float* __restrict__ pn,
                       __hip_bfloat16* __restrict__ wqT,
                       __hip_bfloat16* __restrict__ wvT,
                       __hip_bfloat16* __restrict__ w3T,
                       __hip_bfloat16* __restrict__ woT) {
  int g = blockIdx.x * 256 + threadIdx.x;
  if (g < KVOL * NHEAD) {
    const float* src = pos_enc + g * CHD;
    float vals[CHD];
    float s = 0.f;
#pragma unroll
    for (int i = 0; i < CHD; ++i) {
      vals[i] = src[i];
      s += vals[i] * vals[i];
    }
    float inv = 1.f / fmaxf(sqrtf(s), EPS_NORM);
#pragma unroll
    for (int i = 0; i < CHD; ++i) pn[g * CHD + i] = vals[i] * inv;
  }
  if (g < CIN * CIN) {
    int k = g >> 7, c = g & 127;
    int gt = c * CIN + k;
    wqT[gt] = __float2bfloat16(wq[g]);
    wvT[gt] = __float2bfloat16(wv[g]);
    w3T[gt] = __float2bfloat16(w3[g]);
    woT[gt] = __float2bfloat16(wo[g]);
  }
}

// ---------------- sort: histogram / hierarchical padded scan / scatter ---------
__global__ void k_hist(const int* __restrict__ q_idx, int* __restrict__ cnt,
                       int M) {
  for (int i = blockIdx.x * blockDim.x + threadIdx.x; i < M;
       i += gridDim.x * blockDim.x)
    atomicAdd(&cnt[q_idx[i]], 1);
}

// scan1: 256 thr x 4 elems = 1024 elems/block. Block-local exclusive scan of
// padded counts -> poffs (block-relative); block total -> bsum[blk].
__global__ __launch_bounds__(256) void k_scan1(const int* __restrict__ cnt,
                                               int* __restrict__ poffs,
                                               int* __restrict__ bsum, int N) {
  __shared__ int ws_[4];
  int t = threadIdx.x;
  int l = t & 63, w = t >> 6;
  int base = blockIdx.x * 1024 + t * 4;
  int pc[4];
  int s = 0;
#pragma unroll
  for (int j = 0; j < 4; ++j) {
    int c = (base + j < N) ? cnt[base + j] : 0;
    pc[j] = (c + 7) & ~7;
    s += pc[j];
  }
  int own = s;
  // wave inclusive scan
  for (int off = 1; off < 64; off <<= 1) {
    int v = __shfl_up(s, off);
    if (l >= off) s += v;
  }
  if (l == 63) ws_[w] = s;
  __syncthreads();
  int wbase = 0;
#pragma unroll
  for (int i = 0; i < 4; ++i)
    if (i < w) wbase += ws_[i];
  int ex = wbase + s - own;  // exclusive prefix for this thread
#pragma unroll
  for (int j = 0; j < 4; ++j) {
    if (base + j < N) poffs[base + j] = ex;
    ex += pc[j];
  }
  if (t == 255) bsum[blockIdx.x] = wbase + s;
  // (thread 255's wbase+s == block total since it's last)
}

// scan2: single block, exclusive scan of NB (<=256) block sums -> bbase;
// total -> poffs[N].
__global__ __launch_bounds__(256) void k_scan2(int* __restrict__ bsum,
                                               int* __restrict__ bbase, int NB,
                                               int* __restrict__ poffsN) {
  __shared__ int ws_[4];
  int t = threadIdx.x;
  int l = t & 63, w = t >> 6;
  int s = (t < NB) ? bsum[t] : 0;
  int own = s;
  for (int off = 1; off < 64; off <<= 1) {
    int v = __shfl_up(s, off);
    if (l >= off) s += v;
  }
  if (l == 63) ws_[w] = s;
  __syncthreads();
  int wbase = 0;
#pragma unroll
  for (int i = 0; i < 4; ++i)
    if (i < w) wbase += ws_[i];
  if (t < NB) bbase[t] = wbase + s - own;
  if (t == 255) *poffsN = wbase + s;
}

// scan3: add block base, write cursor, fill pad records in-place.
__global__ __launch_bounds__(256) void k_scan3(const int* __restrict__ cnt,
                                               int* __restrict__ poffs,
                                               const int* __restrict__ bbase,
                                               int* __restrict__ cursor,
                                               unsigned* __restrict__ recs,
                                               int N) {
  int t = threadIdx.x;
  int base = blockIdx.x * 1024 + t * 4;
  int bb = bbase[blockIdx.x];
#pragma unroll
  for (int j = 0; j < 4; ++j) {
    int i = base + j;
    if (i >= N) break;
    int o = poffs[i] + bb;
    poffs[i] = o;
    cursor[i] = o;
    int c = cnt[i];
    int pcend = o + ((c + 7) & ~7);
    for (int p = o + c; p < pcend; ++p) recs[p] = 27u << 17;
  }
}

__global__ void k_scatter_rec(const int* __restrict__ q_idx,
                              const int* __restrict__ k_idx,
                              const int* __restrict__ kernel_idx,
                              int* __restrict__ cursor,
                              unsigned* __restrict__ recs, int M) {
  for (int i = blockIdx.x * blockDim.x + threadIdx.x; i < M;
       i += gridDim.x * blockDim.x) {
    int qi = q_idx[i];
    int pos = atomicAdd(&cursor[qi], 1);
    recs[pos] = (unsigned)k_idx[i] | ((unsigned)kernel_idx[i] << 17);
  }
}

// ---------------- qv: full per-point chain via MFMA ----------------------------
__global__ __launch_bounds__(256) void k_qv(
    const float* __restrict__ points, const float* __restrict__ feats,
    const float* __restrict__ w1, const float* __restrict__ g1,
    const float* __restrict__ b1, const float* __restrict__ w2,
    const float* __restrict__ g2, const float* __restrict__ b2,
    const float* __restrict__ b3, const float* __restrict__ bq,
    const float* __restrict__ bv, const __hip_bfloat16* __restrict__ w3T,
    const __hip_bfloat16* __restrict__ wqT,
    const __hip_bfloat16* __restrict__ wvT, const float* __restrict__ stats1,
    const float* __restrict__ stats2, __hip_bfloat16* __restrict__ qn,
    __hip_bfloat16* __restrict__ vout, int N) {
  __shared__ float h0s[32][3];
  __shared__ __hip_bfloat16 h1s[32][136];
  __shared__ __hip_bfloat16 xs[32][136];

  int t = threadIdx.x;
  int n0 = blockIdx.x * 32;

  if (t < 32) {
    int n = n0 + t;
    float p0 = 0.f, p1 = 0.f, p2 = 0.f;
    if (n < N) {
      p0 = points[3 * n];
      p1 = points[3 * n + 1];
      p2 = points[3 * n + 2];
    }
#pragma unroll
    for (int j = 0; j < 3; ++j) {
      float m = stats1[j] / (float)N;
      float var = stats1[3 + j] / (float)N - m * m;
      float sc = rsqrtf(var + EPS_BN) * g1[j];
      float sh = b1[j] - m * sc;
      float y = p0 * w1[j] + p1 * w1[3 + j] + p2 * w1[6 + j];
      h0s[t][j] = fmaxf(y * sc + sh, 0.f);
    }
  }
  __syncthreads();

  {
    int c = t & 127, half = t >> 7;
    float m2 = stats2[c] / (float)N;
    float v2 = stats2[CIN + c] / (float)N - m2 * m2;
    float sc2 = rsqrtf(v2 + EPS_BN) * g2[c];
    float sh2 = b2[c] - m2 * sc2;
    float wc0 = w2[c], wc1 = w2[CIN + c], wc2 = w2[2 * CIN + c];
#pragma unroll
    for (int i = 0; i < 16; ++i) {
      int p = i * 2 + half;
      float y = h0s[p][0] * wc0 + h0s[p][1] * wc1 + h0s[p][2] * wc2;
      h1s[p][c] = __float2bfloat16(fmaxf(y * sc2 + sh2, 0.f));
    }
  }
  __syncthreads();

  int w = t >> 6, l = t & 63;
  int lr = l & 15, lg = l >> 4;
  int colbase = w * 32;

  {
    f32x4 acc[2][2];
#pragma unroll
    for (int nt = 0; nt < 2; ++nt) {
      float bc = b3[colbase + nt * 16 + lr];
#pragma unroll
      for (int mt = 0; mt < 2; ++mt) acc[mt][nt] = {bc, bc, bc, bc};
    }
#pragma unroll
    for (int kk = 0; kk < 4; ++kk) {
      short8 aA[2], bB[2];
#pragma unroll
      for (int mt = 0; mt < 2; ++mt)
        aA[mt] = *(const short8*)((const char*)h1s + (mt * 16 + lr) * 272 +
                                  (kk * 32 + lg * 8) * 2);
#pragma unroll
      for (int nt = 0; nt < 2; ++nt)
        bB[nt] = *(const short8*)((const char*)w3T +
                                  ((size_t)(colbase + nt * 16 + lr) * CIN +
                                   kk * 32 + lg * 8) *
                                      2);
#pragma unroll
      for (int mt = 0; mt < 2; ++mt)
#pragma unroll
        for (int nt = 0; nt < 2; ++nt)
          acc[mt][nt] = __builtin_amdgcn_mfma_f32_16x16x32_bf16(
              aA[mt], bB[nt], acc[mt][nt], 0, 0, 0);
    }
#pragma unroll
    for (int mt = 0; mt < 2; ++mt)
#pragma unroll
      for (int nt = 0; nt < 2; ++nt)
#pragma unroll
        for (int r = 0; r < 4; ++r) {
          int row = mt * 16 + lg * 4 + r;
          int col = colbase + nt * 16 + lr;
          int n = n0 + row;
          float f = (n < N) ? feats[(size_t)n * CIN + col] : 0.f;
          xs[row][col] = __float2bfloat16(acc[mt][nt][r] + f);
        }
  }
  __syncthreads();

  f32x4 aq[2][2], av[2][2];
#pragma unroll
  for (int nt = 0; nt < 2; ++nt) {
    float bqc = bq[colbase + nt * 16 + lr];
    float bvc = bv[colbase + nt * 16 + lr];
#pragma unroll
    for (int mt = 0; mt < 2; ++mt) {
      aq[mt][nt] = {bqc, bqc, bqc, bqc};
      av[mt][nt] = {bvc, bvc, bvc, bvc};
    }
  }
#pragma unroll
  for (int kk = 0; kk < 4; ++kk) {
    short8 aA[2], bQ[2], bV[2];
#pragma unroll
    for (int mt = 0; mt < 2; ++mt)
      aA[mt] = *(const short8*)((const char*)xs + (mt * 16 + lr) * 272 +
                                (kk * 32 + lg * 8) * 2);
#pragma unroll
    for (int nt = 0; nt < 2; ++nt) {
      size_t off =
          ((size_t)(colbase + nt * 16 + lr) * CIN + kk * 32 + lg * 8) * 2;
      bQ[nt] = *(const short8*)((const char*)wqT + off);
      bV[nt] = *(const short8*)((const char*)wvT + off);
    }
#pragma unroll
    for (int mt = 0; mt < 2; ++mt)
#pragma unroll
      for (int nt = 0; nt < 2; ++nt) {
        aq[mt][nt] = __builtin_amdgcn_mfma_f32_16x16x32_bf16(aA[mt], bQ[nt],
                                                             aq[mt][nt], 0, 0, 0);
        av[mt][nt] = __builtin_amdgcn_mfma_f32_16x16x32_bf16(aA[mt], bV[nt],
                                                             av[mt][nt], 0, 0, 0);
      }
  }

#pragma unroll
  for (int mt = 0; mt < 2; ++mt)
#pragma unroll
    for (int nt = 0; nt < 2; ++nt)
#pragma unroll
      for (int r = 0; r < 4; ++r) {
        float q = aq[mt][nt][r];
        float s = q * q;
        s += __shfl_xor(s, 1);
        s += __shfl_xor(s, 2);
        s += __shfl_xor(s, 4);
        s += __shfl_xor(s, 8);
        float inv = 1.f / fmaxf(sqrtf(s), EPS_NORM);
        int row = mt * 16 + lg * 4 + r;
        int col = colbase + nt * 16 + lr;
        int n = n0 + row;
        if (n < N) {
          qn[(size_t)n * CIN + col] = __float2bfloat16(q * inv);
          vout[(size_t)n * CIN + col] = __float2bfloat16(av[mt][nt][r]);
        }
      }
}

// ---------------- gather: one wave per point, no barriers, 8-deep --------------
__global__ __launch_bounds__(256) void k_gather(
    const unsigned* __restrict__ recs, const int* __restrict__ poffs,
    const unsigned* __restrict__ qn32, const __hip_bfloat16* __restrict__ v,
    const float* __restrict__ pn, unsigned* __restrict__ accb, int N) {
  __shared__ float dots[4][(KVOL + 1) * NHEAD];  // 4 x 224 floats
  int t = threadIdx.x;
  int w = t >> 6, l = t & 63;
  int h = l >> 3;
  const float2* pn2 = (const float2*)pn;
  const char* vbase = (const char*)v + 4 * l;

  for (int n = blockIdx.x * 4 + w; n < N; n += gridDim.x * 4) {
    unsigned qw = qn32[(size_t)n * 64 + l];
    float qx = bflo(qw), qy = bfhi(qw);
#pragma unroll
    for (int kk = 0; kk < KVOL; ++kk) {
      float2 p2 = pn2[kk * 64 + l];
      float d = qx * p2.x + qy * p2.y;
      d += __shfl_xor(d, 1);
      d += __shfl_xor(d, 2);
      d += __shfl_xor(d, 4);
      if ((l & 7) == 0) dots[w][kk * NHEAD + h] = d;
    }
    if ((l & 7) == 0) dots[w][KVOL * NHEAD + h] = 0.f;

    float ax = 0.f, ay = 0.f;
    int beg = poffs[n], end = poffs[n + 1];
    for (int idx = beg; idx < end; idx += 8) {
      unsigned r0 = recs[idx + 0], r1 = recs[idx + 1], r2 = recs[idx + 2],
               r3 = recs[idx + 3], r4 = recs[idx + 4], r5 = recs[idx + 5],
               r6 = recs[idx + 6], r7 = recs[idx + 7];
      unsigned v0 = *(const unsigned*)(vbase + (size_t)(r0 & 0x1FFFF) * 256);
      unsigned v1 = *(const unsigned*)(vbase + (size_t)(r1 & 0x1FFFF) * 256);
      unsigned v2 = *(const unsigned*)(vbase + (size_t)(r2 & 0x1FFFF) * 256);
      unsigned v3 = *(const unsigned*)(vbase + (size_t)(r3 & 0x1FFFF) * 256);
      unsigned v4 = *(const unsigned*)(vbase + (size_t)(r4 & 0x1FFFF) * 256);
      unsigned v5 = *(const unsigned*)(vbase + (size_t)(r5 & 0x1FFFF) * 256);
      unsigned v6 = *(const unsigned*)(vbase + (size_t)(r6 & 0x1FFFF) * 256);
      unsigned v7 = *(const unsigned*)(vbase + (size_t)(r7 & 0x1FFFF) * 256);
      float a0 = dots[w][(r0 >> 17) * NHEAD + h];
      float a1 = dots[w][(r1 >> 17) * NHEAD + h];
      float a2 = dots[w][(r2 >> 17) * NHEAD + h];
      float a3 = dots[w][(r3 >> 17) * NHEAD + h];
      float a4 = dots[w][(r4 >> 17) * NHEAD + h];
      float a5 = dots[w][(r5 >> 17) * NHEAD + h];
      float a6 = dots[w][(r6 >> 17) * NHEAD + h];
      float a7 = dots[w][(r7 >> 17) * NHEAD + h];
      ax += a0 * bflo(v0);
      ay += a0 * bfhi(v0);
      ax += a1 * bflo(v1);
      ay += a1 * bfhi(v1);
      ax += a2 * bflo(v2);
      ay += a2 * bfhi(v2);
      ax += a3 * bflo(v3);
      ay += a3 * bfhi(v3);
      ax += a4 * bflo(v4);
      ay += a4 * bfhi(v4);
      ax += a5 * bflo(v5);
      ay += a5 * bfhi(v5);
      ax += a6 * bflo(v6);
      ay += a6 * bfhi(v6);
      ax += a7 * bflo(v7);
      ay += a7 * bfhi(v7);
    }
    __hip_bfloat16 bx = __float2bfloat16(ax), by = __float2bfloat16(ay);
    unsigned pk = (unsigned)*(unsigned short*)&bx |
                  ((unsigned)*(unsigned short*)&by << 16);
    accb[(size_t)n * 64 + l] = pk;
  }
}

// ---------------- out2: out = accb @ wo + bo (MFMA, 32 rows/block) -------------
__global__ __launch_bounds__(256) void k_out2(
    const __hip_bfloat16* __restrict__ accb,
    const __hip_bfloat16* __restrict__ woT, const float* __restrict__ bo,
    float* __restrict__ out, int N) {
  int t = threadIdx.x;
  int w = t >> 6, l = t & 63;
  int lr = l & 15, lg = l >> 4;
  int colbase = w * 32;
  int n0 = blockIdx.x * 32;

  f32x4 acc[2][2];
#pragma unroll
  for (int nt = 0; nt < 2; ++nt) {
    float bc = bo[colbase + nt * 16 + lr];
#pragma unroll
    for (int mt = 0; mt < 2; ++mt) acc[mt][nt] = {bc, bc, bc, bc};
  }
#pragma unroll
  for (int kk = 0; kk < 4; ++kk) {
    short8 aA[2], bB[2];
#pragma unroll
    for (int mt = 0; mt < 2; ++mt)
      aA[mt] = *(const short8*)((const char*)accb +
                                ((size_t)(n0 + mt * 16 + lr) * CIN + kk * 32 +
                                 lg * 8) *
                                    2);
#pragma unroll
    for (int nt = 0; nt < 2; ++nt)
      bB[nt] = *(const short8*)((const char*)woT +
                                ((size_t)(colbase + nt * 16 + lr) * CIN +
                                 kk * 32 + lg * 8) *
                                    2);
#pragma unroll
    for (int mt = 0; mt < 2; ++mt)
#pragma unroll
      for (int nt = 0; nt < 2; ++nt)
        acc[mt][nt] = __builtin_amdgcn_mfma_f32_16x16x32_bf16(aA[mt], bB[nt],
                                                              acc[mt][nt], 0, 0, 0);
  }
#pragma unroll
  for (int mt = 0; mt < 2; ++mt)
#pragma unroll
    for (int nt = 0; nt < 2; ++nt)
#pragma unroll
      for (int r = 0; r < 4; ++r) {
        int n = n0 + mt * 16 + lg * 4 + r;
        if (n < N) out[(size_t)n * CIN + colbase + nt * 16 + lr] = acc[mt][nt][r];
      }
}

// ---------------- launch -------------------------------------------------------
extern "C" void kernel_launch(void* const* d_in, const int* in_sizes, int n_in,
                              void* d_out, int out_size, void* d_ws,
                              size_t ws_size, hipStream_t stream) {
  const float* points = (const float*)d_in[0];
  const float* feats = (const float*)d_in[1];
  const int* k_idx = (const int*)d_in[2];
  const int* q_idx = (const int*)d_in[3];
  const int* kernel_idx = (const int*)d_in[4];
  const float* w1 = (const float*)d_in[5];
  const float* g1 = (const float*)d_in[6];
  const float* b1 = (const float*)d_in[7];
  const float* w2 = (const float*)d_in[8];
  const float* g2 = (const float*)d_in[9];
  const float* b2 = (const float*)d_in[10];
  const float* w3 = (const float*)d_in[11];
  const float* b3 = (const float*)d_in[12];
  const float* wq = (const float*)d_in[13];
  const float* bq = (const float*)d_in[14];
  const float* wv = (const float*)d_in[15];
  const float* bv = (const float*)d_in[16];
  const float* wo = (const float*)d_in[17];
  const float* bo = (const float*)d_in[18];
  const float* pos_enc = (const float*)d_in[19];

  int N = in_sizes[0] / 3;
  int M = in_sizes[2];
  int NB = (N + 1023) / 1024;  // <= 256 assumed (N <= 262144)

  float* ws = (float*)d_ws;
  float* stats1 = ws;        // 8
  float* stats2 = ws + 8;    // 256
  float* pn = ws + 264;      // 3456 (ends < 4096)
  int* cnt = (int*)(ws + 4096);              // N
  int* poffs = cnt + N;                      // N+1
  int* cursor = poffs + N + 1;               // N
  int* bsum = cursor + N;                    // 512
  int* bbase = bsum + 512;                   // 512
  unsigned* recs = (unsigned*)(bbase + 512); // M + 8N (padded)
  __hip_bfloat16* qn = (__hip_bfloat16*)(recs + M + 8 * (size_t)N);
  __hip_bfloat16* vb = qn + (size_t)N * CIN;
  __hip_bfloat16* accb = vb + (size_t)N * CIN;
  __hip_bfloat16* wqT = accb + (size_t)N * CIN;
  __hip_bfloat16* wvT = wqT + CIN * CIN;
  __hip_bfloat16* w3T = wvT + CIN * CIN;
  __hip_bfloat16* woT = w3T + CIN * CIN;
  float* outf = (float*)d_out;

  hipMemsetAsync(ws, 0, 4096 * sizeof(float), stream);
  hipMemsetAsync(cnt, 0, (size_t)N * sizeof(int), stream);

  k_bn1_stats<<<256, 256, 0, stream>>>(points, w1, stats1, N);
  k_bn2_stats<<<512, 128, 0, stream>>>(points, w1, g1, b1, w2, stats1, stats2, N);
  k_prep<<<64, 256, 0, stream>>>(pos_enc, wq, wv, w3, wo, pn, wqT, wvT, w3T, woT);
  k_hist<<<2048, 256, 0, stream>>>(q_idx, cnt, M);
  k_scan1<<<NB, 256, 0, stream>>>(cnt, poffs, bsum, N);
  k_scan2<<<1, 256, 0, stream>>>(bsum, bbase, NB, poffs + N);
  k_scan3<<<NB, 256, 0, stream>>>(cnt, poffs, bbase, cursor, recs, N);
  k_scatter_rec<<<2048, 256, 0, stream>>>(q_idx, k_idx, kernel_idx, cursor, recs, M);
  k_qv<<<(N + 31) / 32, 256, 0, stream>>>(points, feats, w1, g1, b1, w2, g2, b2,
                                          b3, bq, bv, w3T, wqT, wvT, stats1,
                                          stats2, qn, vb, N);
  k_gather<<<2048, 256, 0, stream>>>(recs, poffs, (const unsigned*)qn, vb, pn,
                                     (unsigned*)accb, N);
  k_out2<<<(N + 31) / 32, 256, 0, stream>>>(accb, woT, bo, outf, N);
}

// Round 8
// 449.116 us; speedup vs baseline: 1.9994x; 1.1610x over previous
//
#include <hip/hip_runtime.h>
#include <hip/hip_bf16.h>

#define CIN 128
#define NHEAD 8
#define CHD 16
#define KVOL 27

constexpr float EPS_BN = 1e-5f;
constexpr float EPS_NORM = 1e-12f;

typedef __attribute__((ext_vector_type(8))) short short8;
typedef __attribute__((ext_vector_type(4))) float f32x4;

__device__ __forceinline__ float bflo(unsigned u) {
  return __uint_as_float(u << 16);
}
__device__ __forceinline__ float bfhi(unsigned u) {
  return __uint_as_float(u & 0xffff0000u);
}

// ---------------- BN1 statistics ----------------------------------------------
__global__ void k_bn1_stats(const float* __restrict__ points,
                            const float* __restrict__ w1,
                            float* __restrict__ stats1, int N) {
  float w[9];
#pragma unroll
  for (int i = 0; i < 9; ++i) w[i] = w1[i];
  float s[3] = {0.f, 0.f, 0.f}, ss[3] = {0.f, 0.f, 0.f};
  for (int n = blockIdx.x * blockDim.x + threadIdx.x; n < N;
       n += gridDim.x * blockDim.x) {
    float p0 = points[3 * n], p1 = points[3 * n + 1], p2 = points[3 * n + 2];
#pragma unroll
    for (int j = 0; j < 3; ++j) {
      float y = p0 * w[j] + p1 * w[3 + j] + p2 * w[6 + j];
      s[j] += y;
      ss[j] += y * y;
    }
  }
#pragma unroll
  for (int j = 0; j < 3; ++j) {
    for (int off = 32; off > 0; off >>= 1) {
      s[j] += __shfl_down(s[j], off);
      ss[j] += __shfl_down(ss[j], off);
    }
  }
  if ((threadIdx.x & 63) == 0) {
#pragma unroll
    for (int j = 0; j < 3; ++j) {
      atomicAdd(&stats1[j], s[j]);
      atomicAdd(&stats1[3 + j], ss[j]);
    }
  }
}

// ---------------- BN2 statistics ----------------------------------------------
__global__ void k_bn2_stats(const float* __restrict__ points,
                            const float* __restrict__ w1,
                            const float* __restrict__ g1,
                            const float* __restrict__ b1,
                            const float* __restrict__ w2,
                            const float* __restrict__ stats1,
                            float* __restrict__ stats2, int N) {
  int c = threadIdx.x;
  float w[9];
#pragma unroll
  for (int i = 0; i < 9; ++i) w[i] = w1[i];
  float sc1[3], sh1[3];
#pragma unroll
  for (int j = 0; j < 3; ++j) {
    float m = stats1[j] / (float)N;
    float var = stats1[3 + j] / (float)N - m * m;
    float sc = rsqrtf(var + EPS_BN) * g1[j];
    sc1[j] = sc;
    sh1[j] = b1[j] - m * sc;
  }
  float wc0 = w2[c], wc1 = w2[CIN + c], wc2 = w2[2 * CIN + c];
  float s = 0.f, ss = 0.f;
  for (int n = blockIdx.x; n < N; n += gridDim.x) {
    float p0 = points[3 * n], p1 = points[3 * n + 1], p2 = points[3 * n + 2];
    float y0 = p0 * w[0] + p1 * w[3] + p2 * w[6];
    float y1 = p0 * w[1] + p1 * w[4] + p2 * w[7];
    float y2 = p0 * w[2] + p1 * w[5] + p2 * w[8];
    float a0 = fmaxf(y0 * sc1[0] + sh1[0], 0.f);
    float a1 = fmaxf(y1 * sc1[1] + sh1[1], 0.f);
    float a2 = fmaxf(y2 * sc1[2] + sh1[2], 0.f);
    float y = a0 * wc0 + a1 * wc1 + a2 * wc2;
    s += y;
    ss += y * y;
  }
  atomicAdd(&stats2[c], s);
  atomicAdd(&stats2[CIN + c], ss);
}

// ---------------- prep: pnb (normalized bf16, 32 rows) + bf16 weights^T --------
__global__ void k_prep(const float* __restrict__ pos_enc,
                       const float* __restrict__ wq,
                       const float* __restrict__ wv,
                       const float* __restrict__ w3,
                       const float* __restrict__ wo,
                       __hip_bfloat16* __restrict__ pnb,
                       __hip_bfloat16* __restrict__ wqT,
                       __hip_bfloat16* __restrict__ wvT,
                       __hip_bfloat16* __restrict__ w3T,
                       __hip_bfloat16* __restrict__ woT) {
  int g = blockIdx.x * 256 + threadIdx.x;
  if (g < 256) {  // (kk,h) pair; rows 27..31 zeroed
    int kk = g >> 3, h = g & 7;
    if (kk < KVOL) {
      const float* src = pos_enc + (kk * NHEAD + h) * CHD;
      float vals[CHD];
      float s = 0.f;
#pragma unroll
      for (int i = 0; i < CHD; ++i) {
        vals[i] = src[i];
        s += vals[i] * vals[i];
      }
      float inv = 1.f / fmaxf(sqrtf(s), EPS_NORM);
#pragma unroll
      for (int i = 0; i < CHD; ++i)
        pnb[kk * CIN + h * CHD + i] = __float2bfloat16(vals[i] * inv);
    } else {
#pragma unroll
      for (int i = 0; i < CHD; ++i)
        pnb[kk * CIN + h * CHD + i] = __float2bfloat16(0.f);
    }
  }
  if (g < CIN * CIN) {
    int k = g >> 7, c = g & 127;
    int gt = c * CIN + k;
    wqT[gt] = __float2bfloat16(wq[g]);
    wvT[gt] = __float2bfloat16(wv[g]);
    w3T[gt] = __float2bfloat16(w3[g]);
    woT[gt] = __float2bfloat16(wo[g]);
  }
}

// ---------------- sort: histogram / hierarchical padded scan / scatter ---------
__global__ void k_hist(const int* __restrict__ q_idx, int* __restrict__ cnt,
                       int M) {
  for (int i = blockIdx.x * blockDim.x + threadIdx.x; i < M;
       i += gridDim.x * blockDim.x)
    atomicAdd(&cnt[q_idx[i]], 1);
}

__global__ __launch_bounds__(256) void k_scan1(const int* __restrict__ cnt,
                                               int* __restrict__ poffs,
                                               int* __restrict__ bsum, int N) {
  __shared__ int ws_[4];
  int t = threadIdx.x;
  int l = t & 63, w = t >> 6;
  int base = blockIdx.x * 1024 + t * 4;
  int pc[4];
  int s = 0;
#pragma unroll
  for (int j = 0; j < 4; ++j) {
    int c = (base + j < N) ? cnt[base + j] : 0;
    pc[j] = (c + 7) & ~7;
    s += pc[j];
  }
  int own = s;
  for (int off = 1; off < 64; off <<= 1) {
    int v = __shfl_up(s, off);
    if (l >= off) s += v;
  }
  if (l == 63) ws_[w] = s;
  __syncthreads();
  int wbase = 0;
#pragma unroll
  for (int i = 0; i < 4; ++i)
    if (i < w) wbase += ws_[i];
  int ex = wbase + s - own;
#pragma unroll
  for (int j = 0; j < 4; ++j) {
    if (base + j < N) poffs[base + j] = ex;
    ex += pc[j];
  }
  if (t == 255) bsum[blockIdx.x] = wbase + s;
}

__global__ __launch_bounds__(256) void k_scan2(int* __restrict__ bsum,
                                               int* __restrict__ bbase, int NB,
                                               int* __restrict__ poffsN) {
  __shared__ int ws_[4];
  int t = threadIdx.x;
  int l = t & 63, w = t >> 6;
  int s = (t < NB) ? bsum[t] : 0;
  int own = s;
  for (int off = 1; off < 64; off <<= 1) {
    int v = __shfl_up(s, off);
    if (l >= off) s += v;
  }
  if (l == 63) ws_[w] = s;
  __syncthreads();
  int wbase = 0;
#pragma unroll
  for (int i = 0; i < 4; ++i)
    if (i < w) wbase += ws_[i];
  if (t < NB) bbase[t] = wbase + s - own;
  if (t == 255) *poffsN = wbase + s;
}

__global__ __launch_bounds__(256) void k_scan3(const int* __restrict__ cnt,
                                               int* __restrict__ poffs,
                                               const int* __restrict__ bbase,
                                               int* __restrict__ cursor,
                                               unsigned* __restrict__ recs,
                                               int N) {
  int t = threadIdx.x;
  int base = blockIdx.x * 1024 + t * 4;
  int bb = bbase[blockIdx.x];
#pragma unroll
  for (int j = 0; j < 4; ++j) {
    int i = base + j;
    if (i >= N) break;
    int o = poffs[i] + bb;
    poffs[i] = o;
    cursor[i] = o;
    int c = cnt[i];
    int pcend = o + ((c + 7) & ~7);
    for (int p = o + c; p < pcend; ++p) recs[p] = 27u << 17;
  }
}

__global__ void k_scatter_rec(const int* __restrict__ q_idx,
                              const int* __restrict__ k_idx,
                              const int* __restrict__ kernel_idx,
                              int* __restrict__ cursor,
                              unsigned* __restrict__ recs, int M) {
  for (int i = blockIdx.x * blockDim.x + threadIdx.x; i < M;
       i += gridDim.x * blockDim.x) {
    int qi = q_idx[i];
    int pos = atomicAdd(&cursor[qi], 1);
    recs[pos] = (unsigned)k_idx[i] | ((unsigned)kernel_idx[i] << 17);
  }
}

// ---------------- qv: full per-point chain via MFMA ----------------------------
__global__ __launch_bounds__(256) void k_qv(
    const float* __restrict__ points, const float* __restrict__ feats,
    const float* __restrict__ w1, const float* __restrict__ g1,
    const float* __restrict__ b1, const float* __restrict__ w2,
    const float* __restrict__ g2, const float* __restrict__ b2,
    const float* __restrict__ b3, const float* __restrict__ bq,
    const float* __restrict__ bv, const __hip_bfloat16* __restrict__ w3T,
    const __hip_bfloat16* __restrict__ wqT,
    const __hip_bfloat16* __restrict__ wvT, const float* __restrict__ stats1,
    const float* __restrict__ stats2, __hip_bfloat16* __restrict__ qn,
    __hip_bfloat16* __restrict__ vout, int N) {
  __shared__ float h0s[32][3];
  __shared__ __hip_bfloat16 h1s[32][136];
  __shared__ __hip_bfloat16 xs[32][136];

  int t = threadIdx.x;
  int n0 = blockIdx.x * 32;

  if (t < 32) {
    int n = n0 + t;
    float p0 = 0.f, p1 = 0.f, p2 = 0.f;
    if (n < N) {
      p0 = points[3 * n];
      p1 = points[3 * n + 1];
      p2 = points[3 * n + 2];
    }
#pragma unroll
    for (int j = 0; j < 3; ++j) {
      float m = stats1[j] / (float)N;
      float var = stats1[3 + j] / (float)N - m * m;
      float sc = rsqrtf(var + EPS_BN) * g1[j];
      float sh = b1[j] - m * sc;
      float y = p0 * w1[j] + p1 * w1[3 + j] + p2 * w1[6 + j];
      h0s[t][j] = fmaxf(y * sc + sh, 0.f);
    }
  }
  __syncthreads();

  {
    int c = t & 127, half = t >> 7;
    float m2 = stats2[c] / (float)N;
    float v2 = stats2[CIN + c] / (float)N - m2 * m2;
    float sc2 = rsqrtf(v2 + EPS_BN) * g2[c];
    float sh2 = b2[c] - m2 * sc2;
    float wc0 = w2[c], wc1 = w2[CIN + c], wc2 = w2[2 * CIN + c];
#pragma unroll
    for (int i = 0; i < 16; ++i) {
      int p = i * 2 + half;
      float y = h0s[p][0] * wc0 + h0s[p][1] * wc1 + h0s[p][2] * wc2;
      h1s[p][c] = __float2bfloat16(fmaxf(y * sc2 + sh2, 0.f));
    }
  }
  __syncthreads();

  int w = t >> 6, l = t & 63;
  int lr = l & 15, lg = l >> 4;
  int colbase = w * 32;

  {
    f32x4 acc[2][2];
#pragma unroll
    for (int nt = 0; nt < 2; ++nt) {
      float bc = b3[colbase + nt * 16 + lr];
#pragma unroll
      for (int mt = 0; mt < 2; ++mt) acc[mt][nt] = {bc, bc, bc, bc};
    }
#pragma unroll
    for (int kk = 0; kk < 4; ++kk) {
      short8 aA[2], bB[2];
#pragma unroll
      for (int mt = 0; mt < 2; ++mt)
        aA[mt] = *(const short8*)((const char*)h1s + (mt * 16 + lr) * 272 +
                                  (kk * 32 + lg * 8) * 2);
#pragma unroll
      for (int nt = 0; nt < 2; ++nt)
        bB[nt] = *(const short8*)((const char*)w3T +
                                  ((size_t)(colbase + nt * 16 + lr) * CIN +
                                   kk * 32 + lg * 8) *
                                      2);
#pragma unroll
      for (int mt = 0; mt < 2; ++mt)
#pragma unroll
        for (int nt = 0; nt < 2; ++nt)
          acc[mt][nt] = __builtin_amdgcn_mfma_f32_16x16x32_bf16(
              aA[mt], bB[nt], acc[mt][nt], 0, 0, 0);
    }
#pragma unroll
    for (int mt = 0; mt < 2; ++mt)
#pragma unroll
      for (int nt = 0; nt < 2; ++nt)
#pragma unroll
        for (int r = 0; r < 4; ++r) {
          int row = mt * 16 + lg * 4 + r;
          int col = colbase + nt * 16 + lr;
          int n = n0 + row;
          float f = (n < N) ? feats[(size_t)n * CIN + col] : 0.f;
          xs[row][col] = __float2bfloat16(acc[mt][nt][r] + f);
        }
  }
  __syncthreads();

  f32x4 aq[2][2], av[2][2];
#pragma unroll
  for (int nt = 0; nt < 2; ++nt) {
    float bqc = bq[colbase + nt * 16 + lr];
    float bvc = bv[colbase + nt * 16 + lr];
#pragma unroll
    for (int mt = 0; mt < 2; ++mt) {
      aq[mt][nt] = {bqc, bqc, bqc, bqc};
      av[mt][nt] = {bvc, bvc, bvc, bvc};
    }
  }
#pragma unroll
  for (int kk = 0; kk < 4; ++kk) {
    short8 aA[2], bQ[2], bV[2];
#pragma unroll
    for (int mt = 0; mt < 2; ++mt)
      aA[mt] = *(const short8*)((const char*)xs + (mt * 16 + lr) * 272 +
                                (kk * 32 + lg * 8) * 2);
#pragma unroll
    for (int nt = 0; nt < 2; ++nt) {
      size_t off =
          ((size_t)(colbase + nt * 16 + lr) * CIN + kk * 32 + lg * 8) * 2;
      bQ[nt] = *(const short8*)((const char*)wqT + off);
      bV[nt] = *(const short8*)((const char*)wvT + off);
    }
#pragma unroll
    for (int mt = 0; mt < 2; ++mt)
#pragma unroll
      for (int nt = 0; nt < 2; ++nt) {
        aq[mt][nt] = __builtin_amdgcn_mfma_f32_16x16x32_bf16(aA[mt], bQ[nt],
                                                             aq[mt][nt], 0, 0, 0);
        av[mt][nt] = __builtin_amdgcn_mfma_f32_16x16x32_bf16(aA[mt], bV[nt],
                                                             av[mt][nt], 0, 0, 0);
      }
  }

#pragma unroll
  for (int mt = 0; mt < 2; ++mt)
#pragma unroll
    for (int nt = 0; nt < 2; ++nt)
#pragma unroll
      for (int r = 0; r < 4; ++r) {
        float q = aq[mt][nt][r];
        float s = q * q;
        s += __shfl_xor(s, 1);
        s += __shfl_xor(s, 2);
        s += __shfl_xor(s, 4);
        s += __shfl_xor(s, 8);
        float inv = 1.f / fmaxf(sqrtf(s), EPS_NORM);
        int row = mt * 16 + lg * 4 + r;
        int col = colbase + nt * 16 + lr;
        int n = n0 + row;
        if (n < N) {
          qn[(size_t)n * CIN + col] = __float2bfloat16(q * inv);
          vout[(size_t)n * CIN + col] = __float2bfloat16(av[mt][nt][r]);
        }
      }
}

// ---------------- dots: dots[n][kk*8+h] = <qn[n,h], pnb[kk,h]> via MFMA --------
// 256 thr = 4 waves, 16 points/wave. K padded 16->32 with zeros.
__global__ __launch_bounds__(256) void k_dots(
    const __hip_bfloat16* __restrict__ qn,
    const __hip_bfloat16* __restrict__ pnb, __hip_bfloat16* __restrict__ dotsb,
    int N) {
  __shared__ unsigned short lds[4][16][224];
  int t = threadIdx.x, w = t >> 6, l = t & 63;
  int lr = l & 15, lg = l >> 4;
  int n0 = blockIdx.x * 64 + w * 16;
  const short8 zero8 = {0, 0, 0, 0, 0, 0, 0, 0};
#pragma unroll
  for (int h = 0; h < NHEAD; ++h) {
    short8 aA = zero8, bB0 = zero8, bB1 = zero8;
    if (lg < 2) {
      aA = *(const short8*)(qn + (size_t)(n0 + lr) * CIN + h * CHD + lg * 8);
      bB0 = *(const short8*)(pnb + lr * CIN + h * CHD + lg * 8);
      bB1 = *(const short8*)(pnb + (16 + lr) * CIN + h * CHD + lg * 8);
    }
    f32x4 c0 = {0.f, 0.f, 0.f, 0.f}, c1 = {0.f, 0.f, 0.f, 0.f};
    c0 = __builtin_amdgcn_mfma_f32_16x16x32_bf16(aA, bB0, c0, 0, 0, 0);
    c1 = __builtin_amdgcn_mfma_f32_16x16x32_bf16(aA, bB1, c1, 0, 0, 0);
#pragma unroll
    for (int r = 0; r < 4; ++r) {
      int row = lg * 4 + r;
      __hip_bfloat16 b0 = __float2bfloat16(c0[r]);
      lds[w][row][lr * 8 + h] = *(unsigned short*)&b0;
      if (lr < KVOL - 16) {
        __hip_bfloat16 b1 = __float2bfloat16(c1[r]);
        lds[w][row][(16 + lr) * 8 + h] = *(unsigned short*)&b1;
      }
    }
  }
  // wave-local LDS dependency (no barrier needed), coalesced write-out
  const unsigned* ldw = (const unsigned*)&lds[w][0][0];  // 16*112 dwords
#pragma unroll 4
  for (int row = 0; row < 16; ++row) {
    int n = n0 + row;
    if (n >= N) break;
    unsigned* dst = (unsigned*)(dotsb + (size_t)n * 224);
    dst[l] = ldw[row * 112 + l];
    if (l < 48) dst[64 + l] = ldw[row * 112 + 64 + l];
  }
}

// ---------------- gather + out projection fused --------------------------------
// 512 thr = 8 waves; block owns 32 points (4/wave); epilogue MFMA from LDS.
__global__ __launch_bounds__(512) void k_gather_out(
    const unsigned* __restrict__ recs, const int* __restrict__ poffs,
    const unsigned* __restrict__ dotsdw, const __hip_bfloat16* __restrict__ v,
    const __hip_bfloat16* __restrict__ woT, const float* __restrict__ bo,
    float* __restrict__ out, int N) {
  __shared__ __hip_bfloat16 accs[32][136];
  __shared__ float lds_dots[8][224];
  int t = threadIdx.x;
  int w = t >> 6, l = t & 63;
  int h = l >> 3;
  int n0 = blockIdx.x * 32;
  const char* vbase = (const char*)v + 4 * l;

#pragma unroll 1
  for (int j = 0; j < 4; ++j) {
    int n = n0 + w * 4 + j;
    float ax = 0.f, ay = 0.f;
    if (n < N) {
      // stage this point's dots row: 112 dwords -> f32 expand
      const unsigned* dr = dotsdw + (size_t)n * 112;
      unsigned u0 = dr[l];
      unsigned u1 = (l < 48) ? dr[64 + l] : 0u;
      lds_dots[w][2 * l] = bflo(u0);
      lds_dots[w][2 * l + 1] = bfhi(u0);
      if (l < 48) {
        lds_dots[w][128 + 2 * l] = bflo(u1);
        lds_dots[w][129 + 2 * l] = bfhi(u1);
      }
      if (l < 8) lds_dots[w][216 + l] = 0.f;  // pad-record slot (kk=27)

      int beg = poffs[n], end = poffs[n + 1];
      for (int idx = beg; idx < end; idx += 8) {
        unsigned r0 = recs[idx + 0], r1 = recs[idx + 1], r2 = recs[idx + 2],
                 r3 = recs[idx + 3], r4 = recs[idx + 4], r5 = recs[idx + 5],
                 r6 = recs[idx + 6], r7 = recs[idx + 7];
        unsigned v0 = *(const unsigned*)(vbase + (size_t)(r0 & 0x1FFFF) * 256);
        unsigned v1 = *(const unsigned*)(vbase + (size_t)(r1 & 0x1FFFF) * 256);
        unsigned v2 = *(const unsigned*)(vbase + (size_t)(r2 & 0x1FFFF) * 256);
        unsigned v3 = *(const unsigned*)(vbase + (size_t)(r3 & 0x1FFFF) * 256);
        unsigned v4 = *(const unsigned*)(vbase + (size_t)(r4 & 0x1FFFF) * 256);
        unsigned v5 = *(const unsigned*)(vbase + (size_t)(r5 & 0x1FFFF) * 256);
        unsigned v6 = *(const unsigned*)(vbase + (size_t)(r6 & 0x1FFFF) * 256);
        unsigned v7 = *(const unsigned*)(vbase + (size_t)(r7 & 0x1FFFF) * 256);
        float a0 = lds_dots[w][(r0 >> 17) * 8 + h];
        float a1 = lds_dots[w][(r1 >> 17) * 8 + h];
        float a2 = lds_dots[w][(r2 >> 17) * 8 + h];
        float a3 = lds_dots[w][(r3 >> 17) * 8 + h];
        float a4 = lds_dots[w][(r4 >> 17) * 8 + h];
        float a5 = lds_dots[w][(r5 >> 17) * 8 + h];
        float a6 = lds_dots[w][(r6 >> 17) * 8 + h];
        float a7 = lds_dots[w][(r7 >> 17) * 8 + h];
        ax += a0 * bflo(v0);
        ay += a0 * bfhi(v0);
        ax += a1 * bflo(v1);
        ay += a1 * bfhi(v1);
        ax += a2 * bflo(v2);
        ay += a2 * bfhi(v2);
        ax += a3 * bflo(v3);
        ay += a3 * bfhi(v3);
        ax += a4 * bflo(v4);
        ay += a4 * bfhi(v4);
        ax += a5 * bflo(v5);
        ay += a5 * bfhi(v5);
        ax += a6 * bflo(v6);
        ay += a6 * bfhi(v6);
        ax += a7 * bflo(v7);
        ay += a7 * bfhi(v7);
      }
    }
    __hip_bfloat16 bx = __float2bfloat16(ax), by = __float2bfloat16(ay);
    unsigned pk = (unsigned)*(unsigned short*)&bx |
                  ((unsigned)*(unsigned short*)&by << 16);
    ((unsigned*)((char*)accs + (w * 4 + j) * 272))[l] = pk;
  }
  __syncthreads();

  // epilogue: out[n0..n0+32) = accs @ wo + bo ; wave w -> cols [16w,16w+16)
  int lr = l & 15, lg = l >> 4;
  int colb = w * 16;
  float bc = bo[colb + lr];
  f32x4 acc0 = {bc, bc, bc, bc}, acc1 = {bc, bc, bc, bc};
#pragma unroll
  for (int kk = 0; kk < 4; ++kk) {
    short8 aA0 = *(const short8*)((const char*)accs + lr * 272 +
                                  (kk * 32 + lg * 8) * 2);
    short8 aA1 = *(const short8*)((const char*)accs + (16 + lr) * 272 +
                                  (kk * 32 + lg * 8) * 2);
    short8 bB = *(const short8*)(woT + (size_t)(colb + lr) * CIN + kk * 32 +
                                 lg * 8);
    acc0 = __builtin_amdgcn_mfma_f32_16x16x32_bf16(aA0, bB, acc0, 0, 0, 0);
    acc1 = __builtin_amdgcn_mfma_f32_16x16x32_bf16(aA1, bB, acc1, 0, 0, 0);
  }
#pragma unroll
  for (int r = 0; r < 4; ++r) {
    int nr0 = n0 + lg * 4 + r;
    int nr1 = nr0 + 16;
    if (nr0 < N) out[(size_t)nr0 * CIN + colb + lr] = acc0[r];
    if (nr1 < N) out[(size_t)nr1 * CIN + colb + lr] = acc1[r];
  }
}

// ---------------- launch -------------------------------------------------------
extern "C" void kernel_launch(void* const* d_in, const int* in_sizes, int n_in,
                              void* d_out, int out_size, void* d_ws,
                              size_t ws_size, hipStream_t stream) {
  const float* points = (const float*)d_in[0];
  const float* feats = (const float*)d_in[1];
  const int* k_idx = (const int*)d_in[2];
  const int* q_idx = (const int*)d_in[3];
  const int* kernel_idx = (const int*)d_in[4];
  const float* w1 = (const float*)d_in[5];
  const float* g1 = (const float*)d_in[6];
  const float* b1 = (const float*)d_in[7];
  const float* w2 = (const float*)d_in[8];
  const float* g2 = (const float*)d_in[9];
  const float* b2 = (const float*)d_in[10];
  const float* w3 = (const float*)d_in[11];
  const float* b3 = (const float*)d_in[12];
  const float* wq = (const float*)d_in[13];
  const float* bq = (const float*)d_in[14];
  const float* wv = (const float*)d_in[15];
  const float* bv = (const float*)d_in[16];
  const float* wo = (const float*)d_in[17];
  const float* bo = (const float*)d_in[18];
  const float* pos_enc = (const float*)d_in[19];

  int N = in_sizes[0] / 3;
  int M = in_sizes[2];
  int NB = (N + 1023) / 1024;  // <= 256
  int Np = (N + 4) & ~3;       // >= N+1, multiple of 4 (keeps regions 16B-aligned)

  float* ws = (float*)d_ws;
  float* stats1 = ws;                                    // 8
  float* stats2 = ws + 8;                                // 256 (ends 264)
  __hip_bfloat16* pnb = (__hip_bfloat16*)(ws + 264);     // 32*128 bf16 (ends 2312)
  int* cnt = (int*)(ws + 4096);                          // Np
  int* poffs = cnt + Np;                                 // Np (N+1 used)
  int* cursor = poffs + Np;                              // Np
  int* bsum = cursor + Np;                               // 512
  int* bbase = bsum + 512;                               // 512
  unsigned* recs = (unsigned*)(bbase + 512);             // M + 8N (padded)
  size_t recn = ((size_t)M + 8 * (size_t)N + 7) & ~(size_t)7;
  __hip_bfloat16* dotsb = (__hip_bfloat16*)(recs + recn);  // N*224
  __hip_bfloat16* qn = dotsb + (size_t)N * 224;
  __hip_bfloat16* vb = qn + (size_t)N * CIN;
  __hip_bfloat16* wqT = vb + (size_t)N * CIN;
  __hip_bfloat16* wvT = wqT + CIN * CIN;
  __hip_bfloat16* w3T = wvT + CIN * CIN;
  __hip_bfloat16* woT = w3T + CIN * CIN;
  float* outf = (float*)d_out;

  hipMemsetAsync(ws, 0, 4096 * sizeof(float), stream);
  hipMemsetAsync(cnt, 0, (size_t)Np * sizeof(int), stream);

  k_bn1_stats<<<256, 256, 0, stream>>>(points, w1, stats1, N);
  k_bn2_stats<<<512, 128, 0, stream>>>(points, w1, g1, b1, w2, stats1, stats2, N);
  k_prep<<<64, 256, 0, stream>>>(pos_enc, wq, wv, w3, wo, pnb, wqT, wvT, w3T, woT);
  k_hist<<<2048, 256, 0, stream>>>(q_idx, cnt, M);
  k_scan1<<<NB, 256, 0, stream>>>(cnt, poffs, bsum, N);
  k_scan2<<<1, 256, 0, stream>>>(bsum, bbase, NB, poffs + N);
  k_scan3<<<NB, 256, 0, stream>>>(cnt, poffs, bbase, cursor, recs, N);
  k_scatter_rec<<<2048, 256, 0, stream>>>(q_idx, k_idx, kernel_idx, cursor, recs, M);
  k_qv<<<(N + 31) / 32, 256, 0, stream>>>(points, feats, w1, g1, b1, w2, g2, b2,
                                          b3, bq, bv, w3T, wqT, wvT, stats1,
                                          stats2, qn, vb, N);
  k_dots<<<(N + 63) / 64, 256, 0, stream>>>(qn, pnb, dotsb, N);
  k_gather_out<<<(N + 31) / 32, 512, 0, stream>>>(recs, poffs,
                                                  (const unsigned*)dotsb, vb,
                                                  woT, bo, outf, N);
}

// Round 9
// 438.348 us; speedup vs baseline: 2.0485x; 1.0246x over previous
//
#include <hip/hip_runtime.h>
#include <hip/hip_bf16.h>

#define CIN 128
#define NHEAD 8
#define CHD 16
#define KVOL 27

constexpr float EPS_BN = 1e-5f;
constexpr float EPS_NORM = 1e-12f;

typedef __attribute__((ext_vector_type(8))) short short8;
typedef __attribute__((ext_vector_type(4))) float f32x4;

__device__ __forceinline__ float bflo(unsigned u) {
  return __uint_as_float(u << 16);
}
__device__ __forceinline__ float bfhi(unsigned u) {
  return __uint_as_float(u & 0xffff0000u);
}

// ---------------- BN1 statistics ----------------------------------------------
__global__ void k_bn1_stats(const float* __restrict__ points,
                            const float* __restrict__ w1,
                            float* __restrict__ stats1, int N) {
  float w[9];
#pragma unroll
  for (int i = 0; i < 9; ++i) w[i] = w1[i];
  float s[3] = {0.f, 0.f, 0.f}, ss[3] = {0.f, 0.f, 0.f};
  for (int n = blockIdx.x * blockDim.x + threadIdx.x; n < N;
       n += gridDim.x * blockDim.x) {
    float p0 = points[3 * n], p1 = points[3 * n + 1], p2 = points[3 * n + 2];
#pragma unroll
    for (int j = 0; j < 3; ++j) {
      float y = p0 * w[j] + p1 * w[3 + j] + p2 * w[6 + j];
      s[j] += y;
      ss[j] += y * y;
    }
  }
#pragma unroll
  for (int j = 0; j < 3; ++j) {
    for (int off = 32; off > 0; off >>= 1) {
      s[j] += __shfl_down(s[j], off);
      ss[j] += __shfl_down(ss[j], off);
    }
  }
  if ((threadIdx.x & 63) == 0) {
#pragma unroll
    for (int j = 0; j < 3; ++j) {
      atomicAdd(&stats1[j], s[j]);
      atomicAdd(&stats1[3 + j], ss[j]);
    }
  }
}

// ---------------- BN2 statistics ----------------------------------------------
__global__ void k_bn2_stats(const float* __restrict__ points,
                            const float* __restrict__ w1,
                            const float* __restrict__ g1,
                            const float* __restrict__ b1,
                            const float* __restrict__ w2,
                            const float* __restrict__ stats1,
                            float* __restrict__ stats2, int N) {
  int c = threadIdx.x;
  float w[9];
#pragma unroll
  for (int i = 0; i < 9; ++i) w[i] = w1[i];
  float sc1[3], sh1[3];
#pragma unroll
  for (int j = 0; j < 3; ++j) {
    float m = stats1[j] / (float)N;
    float var = stats1[3 + j] / (float)N - m * m;
    float sc = rsqrtf(var + EPS_BN) * g1[j];
    sc1[j] = sc;
    sh1[j] = b1[j] - m * sc;
  }
  float wc0 = w2[c], wc1 = w2[CIN + c], wc2 = w2[2 * CIN + c];
  float s = 0.f, ss = 0.f;
  for (int n = blockIdx.x; n < N; n += gridDim.x) {
    float p0 = points[3 * n], p1 = points[3 * n + 1], p2 = points[3 * n + 2];
    float y0 = p0 * w[0] + p1 * w[3] + p2 * w[6];
    float y1 = p0 * w[1] + p1 * w[4] + p2 * w[7];
    float y2 = p0 * w[2] + p1 * w[5] + p2 * w[8];
    float a0 = fmaxf(y0 * sc1[0] + sh1[0], 0.f);
    float a1 = fmaxf(y1 * sc1[1] + sh1[1], 0.f);
    float a2 = fmaxf(y2 * sc1[2] + sh1[2], 0.f);
    float y = a0 * wc0 + a1 * wc1 + a2 * wc2;
    s += y;
    ss += y * y;
  }
  atomicAdd(&stats2[c], s);
  atomicAdd(&stats2[CIN + c], ss);
}

// ---------------- prep: pnb (normalized bf16, 32 rows) + bf16 weights^T --------
__global__ void k_prep(const float* __restrict__ pos_enc,
                       const float* __restrict__ wq,
                       const float* __restrict__ wv,
                       const float* __restrict__ w3,
                       const float* __restrict__ wo,
                       __hip_bfloat16* __restrict__ pnb,
                       __hip_bfloat16* __restrict__ wqT,
                       __hip_bfloat16* __restrict__ wvT,
                       __hip_bfloat16* __restrict__ w3T,
                       __hip_bfloat16* __restrict__ woT) {
  int g = blockIdx.x * 256 + threadIdx.x;
  if (g < 256) {  // (kk,h) pair; rows 27..31 zeroed
    int kk = g >> 3, h = g & 7;
    if (kk < KVOL) {
      const float* src = pos_enc + (kk * NHEAD + h) * CHD;
      float vals[CHD];
      float s = 0.f;
#pragma unroll
      for (int i = 0; i < CHD; ++i) {
        vals[i] = src[i];
        s += vals[i] * vals[i];
      }
      float inv = 1.f / fmaxf(sqrtf(s), EPS_NORM);
#pragma unroll
      for (int i = 0; i < CHD; ++i)
        pnb[kk * CIN + h * CHD + i] = __float2bfloat16(vals[i] * inv);
    } else {
#pragma unroll
      for (int i = 0; i < CHD; ++i)
        pnb[kk * CIN + h * CHD + i] = __float2bfloat16(0.f);
    }
  }
  if (g < CIN * CIN) {
    int k = g >> 7, c = g & 127;
    int gt = c * CIN + k;
    wqT[gt] = __float2bfloat16(wq[g]);
    wvT[gt] = __float2bfloat16(wv[g]);
    w3T[gt] = __float2bfloat16(w3[g]);
    woT[gt] = __float2bfloat16(wo[g]);
  }
}

// ---------------- sort: histogram / hierarchical padded scan / scatter ---------
__global__ void k_hist(const int* __restrict__ q_idx, int* __restrict__ cnt,
                       int M) {
  for (int i = blockIdx.x * blockDim.x + threadIdx.x; i < M;
       i += gridDim.x * blockDim.x)
    atomicAdd(&cnt[q_idx[i]], 1);
}

__global__ __launch_bounds__(256) void k_scan1(const int* __restrict__ cnt,
                                               int* __restrict__ poffs,
                                               int* __restrict__ bsum, int N) {
  __shared__ int ws_[4];
  int t = threadIdx.x;
  int l = t & 63, w = t >> 6;
  int base = blockIdx.x * 1024 + t * 4;
  int pc[4];
  int s = 0;
#pragma unroll
  for (int j = 0; j < 4; ++j) {
    int c = (base + j < N) ? cnt[base + j] : 0;
    pc[j] = (c + 7) & ~7;
    s += pc[j];
  }
  int own = s;
  for (int off = 1; off < 64; off <<= 1) {
    int v = __shfl_up(s, off);
    if (l >= off) s += v;
  }
  if (l == 63) ws_[w] = s;
  __syncthreads();
  int wbase = 0;
#pragma unroll
  for (int i = 0; i < 4; ++i)
    if (i < w) wbase += ws_[i];
  int ex = wbase + s - own;
#pragma unroll
  for (int j = 0; j < 4; ++j) {
    if (base + j < N) poffs[base + j] = ex;
    ex += pc[j];
  }
  if (t == 255) bsum[blockIdx.x] = wbase + s;
}

__global__ __launch_bounds__(256) void k_scan2(int* __restrict__ bsum,
                                               int* __restrict__ bbase, int NB,
                                               int* __restrict__ poffsN) {
  __shared__ int ws_[4];
  int t = threadIdx.x;
  int l = t & 63, w = t >> 6;
  int s = (t < NB) ? bsum[t] : 0;
  int own = s;
  for (int off = 1; off < 64; off <<= 1) {
    int v = __shfl_up(s, off);
    if (l >= off) s += v;
  }
  if (l == 63) ws_[w] = s;
  __syncthreads();
  int wbase = 0;
#pragma unroll
  for (int i = 0; i < 4; ++i)
    if (i < w) wbase += ws_[i];
  if (t < NB) bbase[t] = wbase + s - own;
  if (t == 255) *poffsN = wbase + s;
}

__global__ __launch_bounds__(256) void k_scan3(const int* __restrict__ cnt,
                                               int* __restrict__ poffs,
                                               const int* __restrict__ bbase,
                                               int* __restrict__ cursor,
                                               unsigned* __restrict__ recs,
                                               int N) {
  int t = threadIdx.x;
  int base = blockIdx.x * 1024 + t * 4;
  int bb = bbase[blockIdx.x];
#pragma unroll
  for (int j = 0; j < 4; ++j) {
    int i = base + j;
    if (i >= N) break;
    int o = poffs[i] + bb;
    poffs[i] = o;
    cursor[i] = o;
    int c = cnt[i];
    int pcend = o + ((c + 7) & ~7);
    for (int p = o + c; p < pcend; ++p) recs[p] = 27u << 17;
  }
}

__global__ void k_scatter_rec(const int* __restrict__ q_idx,
                              const int* __restrict__ k_idx,
                              const int* __restrict__ kernel_idx,
                              int* __restrict__ cursor,
                              unsigned* __restrict__ recs, int M) {
  for (int i = blockIdx.x * blockDim.x + threadIdx.x; i < M;
       i += gridDim.x * blockDim.x) {
    int qi = q_idx[i];
    int pos = atomicAdd(&cursor[qi], 1);
    recs[pos] = (unsigned)k_idx[i] | ((unsigned)kernel_idx[i] << 17);
  }
}

// ---------------- qv: per-point chain + fused dots, all MFMA -------------------
// 256 thr = 4 waves, 32 points/block. Outputs: v (coalesced), dots (coalesced).
__global__ __launch_bounds__(256) void k_qv(
    const float* __restrict__ points, const float* __restrict__ feats,
    const float* __restrict__ w1, const float* __restrict__ g1,
    const float* __restrict__ b1, const float* __restrict__ w2,
    const float* __restrict__ g2, const float* __restrict__ b2,
    const float* __restrict__ b3, const float* __restrict__ bq,
    const float* __restrict__ bv, const __hip_bfloat16* __restrict__ w3T,
    const __hip_bfloat16* __restrict__ wqT,
    const __hip_bfloat16* __restrict__ wvT,
    const __hip_bfloat16* __restrict__ pnb, const float* __restrict__ stats1,
    const float* __restrict__ stats2, __hip_bfloat16* __restrict__ dotsb,
    __hip_bfloat16* __restrict__ vout, int N) {
  __shared__ float h0s[32][3];
  __shared__ __hip_bfloat16 h1s[32][136];       // h1, then v staging
  __shared__ __hip_bfloat16 xs[32][136];        // x, then qn staging
  __shared__ unsigned short dotlds[32][224];    // dots staging

  int t = threadIdx.x;
  int n0 = blockIdx.x * 32;

  // phase 0: h0 = relu(bn1(points@w1))
  if (t < 32) {
    int n = n0 + t;
    float p0 = 0.f, p1 = 0.f, p2 = 0.f;
    if (n < N) {
      p0 = points[3 * n];
      p1 = points[3 * n + 1];
      p2 = points[3 * n + 2];
    }
#pragma unroll
    for (int j = 0; j < 3; ++j) {
      float m = stats1[j] / (float)N;
      float var = stats1[3 + j] / (float)N - m * m;
      float sc = rsqrtf(var + EPS_BN) * g1[j];
      float sh = b1[j] - m * sc;
      float y = p0 * w1[j] + p1 * w1[3 + j] + p2 * w1[6 + j];
      h0s[t][j] = fmaxf(y * sc + sh, 0.f);
    }
  }
  __syncthreads();

  // phase 1: h1 = relu(bn2(h0@w2)) -> LDS bf16
  {
    int c = t & 127, half = t >> 7;
    float m2 = stats2[c] / (float)N;
    float v2 = stats2[CIN + c] / (float)N - m2 * m2;
    float sc2 = rsqrtf(v2 + EPS_BN) * g2[c];
    float sh2 = b2[c] - m2 * sc2;
    float wc0 = w2[c], wc1 = w2[CIN + c], wc2 = w2[2 * CIN + c];
#pragma unroll
    for (int i = 0; i < 16; ++i) {
      int p = i * 2 + half;
      float y = h0s[p][0] * wc0 + h0s[p][1] * wc1 + h0s[p][2] * wc2;
      h1s[p][c] = __float2bfloat16(fmaxf(y * sc2 + sh2, 0.f));
    }
  }
  __syncthreads();

  int w = t >> 6, l = t & 63;
  int lr = l & 15, lg = l >> 4;
  int colbase = w * 32;

  // phase 2: x = feats + h1@w3 + b3 -> LDS bf16
  {
    f32x4 acc[2][2];
#pragma unroll
    for (int nt = 0; nt < 2; ++nt) {
      float bc = b3[colbase + nt * 16 + lr];
#pragma unroll
      for (int mt = 0; mt < 2; ++mt) acc[mt][nt] = {bc, bc, bc, bc};
    }
#pragma unroll
    for (int kk = 0; kk < 4; ++kk) {
      short8 aA[2], bB[2];
#pragma unroll
      for (int mt = 0; mt < 2; ++mt)
        aA[mt] = *(const short8*)((const char*)h1s + (mt * 16 + lr) * 272 +
                                  (kk * 32 + lg * 8) * 2);
#pragma unroll
      for (int nt = 0; nt < 2; ++nt)
        bB[nt] = *(const short8*)((const char*)w3T +
                                  ((size_t)(colbase + nt * 16 + lr) * CIN +
                                   kk * 32 + lg * 8) *
                                      2);
#pragma unroll
      for (int mt = 0; mt < 2; ++mt)
#pragma unroll
        for (int nt = 0; nt < 2; ++nt)
          acc[mt][nt] = __builtin_amdgcn_mfma_f32_16x16x32_bf16(
              aA[mt], bB[nt], acc[mt][nt], 0, 0, 0);
    }
#pragma unroll
    for (int mt = 0; mt < 2; ++mt)
#pragma unroll
      for (int nt = 0; nt < 2; ++nt)
#pragma unroll
        for (int r = 0; r < 4; ++r) {
          int row = mt * 16 + lg * 4 + r;
          int col = colbase + nt * 16 + lr;
          int n = n0 + row;
          float f = (n < N) ? feats[(size_t)n * CIN + col] : 0.f;
          xs[row][col] = __float2bfloat16(acc[mt][nt][r] + f);
        }
  }
  __syncthreads();

  // phase 3: q = x@wq + bq, v = x@wv + bv
  f32x4 aq[2][2], av[2][2];
#pragma unroll
  for (int nt = 0; nt < 2; ++nt) {
    float bqc = bq[colbase + nt * 16 + lr];
    float bvc = bv[colbase + nt * 16 + lr];
#pragma unroll
    for (int mt = 0; mt < 2; ++mt) {
      aq[mt][nt] = {bqc, bqc, bqc, bqc};
      av[mt][nt] = {bvc, bvc, bvc, bvc};
    }
  }
#pragma unroll
  for (int kk = 0; kk < 4; ++kk) {
    short8 aA[2], bQ[2], bV[2];
#pragma unroll
    for (int mt = 0; mt < 2; ++mt)
      aA[mt] = *(const short8*)((const char*)xs + (mt * 16 + lr) * 272 +
                                (kk * 32 + lg * 8) * 2);
#pragma unroll
    for (int nt = 0; nt < 2; ++nt) {
      size_t off =
          ((size_t)(colbase + nt * 16 + lr) * CIN + kk * 32 + lg * 8) * 2;
      bQ[nt] = *(const short8*)((const char*)wqT + off);
      bV[nt] = *(const short8*)((const char*)wvT + off);
    }
#pragma unroll
    for (int mt = 0; mt < 2; ++mt)
#pragma unroll
      for (int nt = 0; nt < 2; ++nt) {
        aq[mt][nt] = __builtin_amdgcn_mfma_f32_16x16x32_bf16(aA[mt], bQ[nt],
                                                             aq[mt][nt], 0, 0, 0);
        av[mt][nt] = __builtin_amdgcn_mfma_f32_16x16x32_bf16(aA[mt], bV[nt],
                                                             av[mt][nt], 0, 0, 0);
      }
  }
  __syncthreads();  // all xs/h1s reads complete

  // phase 4: L2-norm q -> qn into xs; v -> h1s (both LDS, row-major)
#pragma unroll
  for (int mt = 0; mt < 2; ++mt)
#pragma unroll
    for (int nt = 0; nt < 2; ++nt)
#pragma unroll
      for (int r = 0; r < 4; ++r) {
        float q = aq[mt][nt][r];
        float s = q * q;
        s += __shfl_xor(s, 1);
        s += __shfl_xor(s, 2);
        s += __shfl_xor(s, 4);
        s += __shfl_xor(s, 8);
        float inv = 1.f / fmaxf(sqrtf(s), EPS_NORM);
        int row = mt * 16 + lg * 4 + r;
        int col = colbase + nt * 16 + lr;
        xs[row][col] = __float2bfloat16(q * inv);
        h1s[row][col] = __float2bfloat16(av[mt][nt][r]);
      }
  __syncthreads();

  // phase 5a: coalesced v store (32 rows x 256B)
  {
    int row = t >> 3, part = t & 7;
    int n = n0 + row;
    if (n < N) {
      const char* src = (const char*)&h1s[row][0] + part * 32;
      char* dst = (char*)vout + (size_t)n * 256 + part * 32;
      *(uint4*)dst = *(const uint4*)src;
      *(uint4*)(dst + 16) = *(const uint4*)(src + 16);
    }
  }

  // phase 5b: dots MFMAs from LDS qn vs pnb. wave w: rowgroup w&1, heads (w>>1)*4..+4
  {
    int rg = w & 1;
    int hbase = (w >> 1) * 4;
    const short8 zero8 = {0, 0, 0, 0, 0, 0, 0, 0};
#pragma unroll
    for (int hh = 0; hh < 4; ++hh) {
      int h = hbase + hh;
      short8 aA = zero8, bB0 = zero8, bB1 = zero8;
      if (lg < 2) {
        aA = *(const short8*)&xs[rg * 16 + lr][h * CHD + lg * 8];
        bB0 = *(const short8*)(pnb + lr * CIN + h * CHD + lg * 8);
        bB1 = *(const short8*)(pnb + (16 + lr) * CIN + h * CHD + lg * 8);
      }
      f32x4 c0 = {0.f, 0.f, 0.f, 0.f}, c1 = {0.f, 0.f, 0.f, 0.f};
      c0 = __builtin_amdgcn_mfma_f32_16x16x32_bf16(aA, bB0, c0, 0, 0, 0);
      c1 = __builtin_amdgcn_mfma_f32_16x16x32_bf16(aA, bB1, c1, 0, 0, 0);
#pragma unroll
      for (int r = 0; r < 4; ++r) {
        int row = rg * 16 + lg * 4 + r;
        __hip_bfloat16 b0 = __float2bfloat16(c0[r]);
        dotlds[row][lr * 8 + h] = *(unsigned short*)&b0;
        if (lr < KVOL - 16) {
          __hip_bfloat16 b1 = __float2bfloat16(c1[r]);
          dotlds[row][(16 + lr) * 8 + h] = *(unsigned short*)&b1;
        }
      }
    }
  }
  __syncthreads();

  // phase 6: coalesced dots store; wave w rows w*8..w*8+8 (448B per row)
#pragma unroll
  for (int rr = 0; rr < 8; ++rr) {
    int row = w * 8 + rr;
    int n = n0 + row;
    if (n < N) {
      const unsigned* ldw_ = (const unsigned*)&dotlds[row][0];
      unsigned* dst = (unsigned*)(dotsb + (size_t)n * 224);
      dst[l] = ldw_[l];
      if (l < 48) dst[64 + l] = ldw_[64 + l];
    }
  }
}

// ---------------- gather + out projection fused --------------------------------
// 512 thr = 8 waves; block owns 32 points (4/wave); epilogue MFMA from LDS.
__global__ __launch_bounds__(512) void k_gather_out(
    const unsigned* __restrict__ recs, const int* __restrict__ poffs,
    const unsigned* __restrict__ dotsdw, const __hip_bfloat16* __restrict__ v,
    const __hip_bfloat16* __restrict__ woT, const float* __restrict__ bo,
    float* __restrict__ out, int N) {
  __shared__ __hip_bfloat16 accs[32][136];
  __shared__ float lds_dots[8][224];
  int t = threadIdx.x;
  int w = t >> 6, l = t & 63;
  int h = l >> 3;
  int n0 = blockIdx.x * 32;
  const char* vbase = (const char*)v + 4 * l;

#pragma unroll 1
  for (int j = 0; j < 4; ++j) {
    int n = n0 + w * 4 + j;
    float ax = 0.f, ay = 0.f;
    if (n < N) {
      const unsigned* dr = dotsdw + (size_t)n * 112;
      unsigned u0 = dr[l];
      unsigned u1 = (l < 48) ? dr[64 + l] : 0u;
      lds_dots[w][2 * l] = bflo(u0);
      lds_dots[w][2 * l + 1] = bfhi(u0);
      if (l < 48) {
        lds_dots[w][128 + 2 * l] = bflo(u1);
        lds_dots[w][129 + 2 * l] = bfhi(u1);
      }
      if (l < 8) lds_dots[w][216 + l] = 0.f;  // pad-record slot (kk=27)

      int beg = poffs[n], end = poffs[n + 1];
      for (int idx = beg; idx < end; idx += 8) {
        unsigned r0 = recs[idx + 0], r1 = recs[idx + 1], r2 = recs[idx + 2],
                 r3 = recs[idx + 3], r4 = recs[idx + 4], r5 = recs[idx + 5],
                 r6 = recs[idx + 6], r7 = recs[idx + 7];
        unsigned v0 = *(const unsigned*)(vbase + (size_t)(r0 & 0x1FFFF) * 256);
        unsigned v1 = *(const unsigned*)(vbase + (size_t)(r1 & 0x1FFFF) * 256);
        unsigned v2 = *(const unsigned*)(vbase + (size_t)(r2 & 0x1FFFF) * 256);
        unsigned v3 = *(const unsigned*)(vbase + (size_t)(r3 & 0x1FFFF) * 256);
        unsigned v4 = *(const unsigned*)(vbase + (size_t)(r4 & 0x1FFFF) * 256);
        unsigned v5 = *(const unsigned*)(vbase + (size_t)(r5 & 0x1FFFF) * 256);
        unsigned v6 = *(const unsigned*)(vbase + (size_t)(r6 & 0x1FFFF) * 256);
        unsigned v7 = *(const unsigned*)(vbase + (size_t)(r7 & 0x1FFFF) * 256);
        float a0 = lds_dots[w][(r0 >> 17) * 8 + h];
        float a1 = lds_dots[w][(r1 >> 17) * 8 + h];
        float a2 = lds_dots[w][(r2 >> 17) * 8 + h];
        float a3 = lds_dots[w][(r3 >> 17) * 8 + h];
        float a4 = lds_dots[w][(r4 >> 17) * 8 + h];
        float a5 = lds_dots[w][(r5 >> 17) * 8 + h];
        float a6 = lds_dots[w][(r6 >> 17) * 8 + h];
        float a7 = lds_dots[w][(r7 >> 17) * 8 + h];
        ax += a0 * bflo(v0);
        ay += a0 * bfhi(v0);
        ax += a1 * bflo(v1);
        ay += a1 * bfhi(v1);
        ax += a2 * bflo(v2);
        ay += a2 * bfhi(v2);
        ax += a3 * bflo(v3);
        ay += a3 * bfhi(v3);
        ax += a4 * bflo(v4);
        ay += a4 * bfhi(v4);
        ax += a5 * bflo(v5);
        ay += a5 * bfhi(v5);
        ax += a6 * bflo(v6);
        ay += a6 * bfhi(v6);
        ax += a7 * bflo(v7);
        ay += a7 * bfhi(v7);
      }
    }
    __hip_bfloat16 bx = __float2bfloat16(ax), by = __float2bfloat16(ay);
    unsigned pk = (unsigned)*(unsigned short*)&bx |
                  ((unsigned)*(unsigned short*)&by << 16);
    ((unsigned*)((char*)accs + (w * 4 + j) * 272))[l] = pk;
  }
  __syncthreads();

  // epilogue: out[n0..n0+32) = accs @ wo + bo ; wave w -> cols [16w,16w+16)
  int lr = l & 15, lg = l >> 4;
  int colb = w * 16;
  float bc = bo[colb + lr];
  f32x4 acc0 = {bc, bc, bc, bc}, acc1 = {bc, bc, bc, bc};
#pragma unroll
  for (int kk = 0; kk < 4; ++kk) {
    short8 aA0 = *(const short8*)((const char*)accs + lr * 272 +
                                  (kk * 32 + lg * 8) * 2);
    short8 aA1 = *(const short8*)((const char*)accs + (16 + lr) * 272 +
                                  (kk * 32 + lg * 8) * 2);
    short8 bB = *(const short8*)(woT + (size_t)(colb + lr) * CIN + kk * 32 +
                                 lg * 8);
    acc0 = __builtin_amdgcn_mfma_f32_16x16x32_bf16(aA0, bB, acc0, 0, 0, 0);
    acc1 = __builtin_amdgcn_mfma_f32_16x16x32_bf16(aA1, bB, acc1, 0, 0, 0);
  }
#pragma unroll
  for (int r = 0; r < 4; ++r) {
    int nr0 = n0 + lg * 4 + r;
    int nr1 = nr0 + 16;
    if (nr0 < N) out[(size_t)nr0 * CIN + colb + lr] = acc0[r];
    if (nr1 < N) out[(size_t)nr1 * CIN + colb + lr] = acc1[r];
  }
}

// ---------------- launch -------------------------------------------------------
extern "C" void kernel_launch(void* const* d_in, const int* in_sizes, int n_in,
                              void* d_out, int out_size, void* d_ws,
                              size_t ws_size, hipStream_t stream) {
  const float* points = (const float*)d_in[0];
  const float* feats = (const float*)d_in[1];
  const int* k_idx = (const int*)d_in[2];
  const int* q_idx = (const int*)d_in[3];
  const int* kernel_idx = (const int*)d_in[4];
  const float* w1 = (const float*)d_in[5];
  const float* g1 = (const float*)d_in[6];
  const float* b1 = (const float*)d_in[7];
  const float* w2 = (const float*)d_in[8];
  const float* g2 = (const float*)d_in[9];
  const float* b2 = (const float*)d_in[10];
  const float* w3 = (const float*)d_in[11];
  const float* b3 = (const float*)d_in[12];
  const float* wq = (const float*)d_in[13];
  const float* bq = (const float*)d_in[14];
  const float* wv = (const float*)d_in[15];
  const float* bv = (const float*)d_in[16];
  const float* wo = (const float*)d_in[17];
  const float* bo = (const float*)d_in[18];
  const float* pos_enc = (const float*)d_in[19];

  int N = in_sizes[0] / 3;
  int M = in_sizes[2];
  int NB = (N + 1023) / 1024;  // <= 256
  int Np = (N + 4) & ~3;

  float* ws = (float*)d_ws;
  float* stats1 = ws;                                    // 8
  float* stats2 = ws + 8;                                // 256 (ends 264)
  __hip_bfloat16* pnb = (__hip_bfloat16*)(ws + 264);     // 32*128 bf16
  int* cnt = (int*)(ws + 4096);                          // Np
  int* poffs = cnt + Np;                                 // Np (N+1 used)
  int* cursor = poffs + Np;                              // Np
  int* bsum = cursor + Np;                               // 512
  int* bbase = bsum + 512;                               // 512
  unsigned* recs = (unsigned*)(bbase + 512);             // M + 8N (padded)
  size_t recn = ((size_t)M + 8 * (size_t)N + 7) & ~(size_t)7;
  __hip_bfloat16* dotsb = (__hip_bfloat16*)(recs + recn);  // N*224
  __hip_bfloat16* vb = dotsb + (size_t)N * 224;            // N*128
  __hip_bfloat16* wqT = vb + (size_t)N * CIN;
  __hip_bfloat16* wvT = wqT + CIN * CIN;
  __hip_bfloat16* w3T = wvT + CIN * CIN;
  __hip_bfloat16* woT = w3T + CIN * CIN;
  float* outf = (float*)d_out;

  hipMemsetAsync(ws, 0, 4096 * sizeof(float), stream);
  hipMemsetAsync(cnt, 0, (size_t)Np * sizeof(int), stream);

  k_bn1_stats<<<256, 256, 0, stream>>>(points, w1, stats1, N);
  k_bn2_stats<<<512, 128, 0, stream>>>(points, w1, g1, b1, w2, stats1, stats2, N);
  k_prep<<<64, 256, 0, stream>>>(pos_enc, wq, wv, w3, wo, pnb, wqT, wvT, w3T, woT);
  k_hist<<<2048, 256, 0, stream>>>(q_idx, cnt, M);
  k_scan1<<<NB, 256, 0, stream>>>(cnt, poffs, bsum, N);
  k_scan2<<<1, 256, 0, stream>>>(bsum, bbase, NB, poffs + N);
  k_scan3<<<NB, 256, 0, stream>>>(cnt, poffs, bbase, cursor, recs, N);
  k_scatter_rec<<<2048, 256, 0, stream>>>(q_idx, k_idx, kernel_idx, cursor, recs, M);
  k_qv<<<(N + 31) / 32, 256, 0, stream>>>(points, feats, w1, g1, b1, w2, g2, b2,
                                          b3, bq, bv, w3T, wqT, wvT, pnb,
                                          stats1, stats2, dotsb, vb, N);
  k_gather_out<<<(N + 31) / 32, 512, 0, stream>>>(recs, poffs,
                                                  (const unsigned*)dotsb, vb,
                                                  woT, bo, outf, N);
}

// Round 10
// 428.069 us; speedup vs baseline: 2.0977x; 1.0240x over previous
//
#include <hip/hip_runtime.h>
#include <hip/hip_bf16.h>

#define CIN 128
#define NHEAD 8
#define CHD 16
#define KVOL 27

constexpr float EPS_BN = 1e-5f;
constexpr float EPS_NORM = 1e-12f;

typedef __attribute__((ext_vector_type(8))) short short8;
typedef __attribute__((ext_vector_type(4))) float f32x4;

__device__ __forceinline__ float bflo(unsigned u) {
  return __uint_as_float(u << 16);
}
__device__ __forceinline__ float bfhi(unsigned u) {
  return __uint_as_float(u & 0xffff0000u);
}
__device__ __forceinline__ float bfus(unsigned short u) {
  return __uint_as_float((unsigned)u << 16);
}

// ---------------- BN1 statistics ----------------------------------------------
__global__ void k_bn1_stats(const float* __restrict__ points,
                            const float* __restrict__ w1,
                            float* __restrict__ stats1, int N) {
  float w[9];
#pragma unroll
  for (int i = 0; i < 9; ++i) w[i] = w1[i];
  float s[3] = {0.f, 0.f, 0.f}, ss[3] = {0.f, 0.f, 0.f};
  for (int n = blockIdx.x * blockDim.x + threadIdx.x; n < N;
       n += gridDim.x * blockDim.x) {
    float p0 = points[3 * n], p1 = points[3 * n + 1], p2 = points[3 * n + 2];
#pragma unroll
    for (int j = 0; j < 3; ++j) {
      float y = p0 * w[j] + p1 * w[3 + j] + p2 * w[6 + j];
      s[j] += y;
      ss[j] += y * y;
    }
  }
#pragma unroll
  for (int j = 0; j < 3; ++j) {
    for (int off = 32; off > 0; off >>= 1) {
      s[j] += __shfl_down(s[j], off);
      ss[j] += __shfl_down(ss[j], off);
    }
  }
  if ((threadIdx.x & 63) == 0) {
#pragma unroll
    for (int j = 0; j < 3; ++j) {
      atomicAdd(&stats1[j], s[j]);
      atomicAdd(&stats1[3 + j], ss[j]);
    }
  }
}

// ---------------- BN2 statistics ----------------------------------------------
__global__ void k_bn2_stats(const float* __restrict__ points,
                            const float* __restrict__ w1,
                            const float* __restrict__ g1,
                            const float* __restrict__ b1,
                            const float* __restrict__ w2,
                            const float* __restrict__ stats1,
                            float* __restrict__ stats2, int N) {
  int c = threadIdx.x;
  float w[9];
#pragma unroll
  for (int i = 0; i < 9; ++i) w[i] = w1[i];
  float sc1[3], sh1[3];
#pragma unroll
  for (int j = 0; j < 3; ++j) {
    float m = stats1[j] / (float)N;
    float var = stats1[3 + j] / (float)N - m * m;
    float sc = rsqrtf(var + EPS_BN) * g1[j];
    sc1[j] = sc;
    sh1[j] = b1[j] - m * sc;
  }
  float wc0 = w2[c], wc1 = w2[CIN + c], wc2 = w2[2 * CIN + c];
  float s = 0.f, ss = 0.f;
  for (int n = blockIdx.x; n < N; n += gridDim.x) {
    float p0 = points[3 * n], p1 = points[3 * n + 1], p2 = points[3 * n + 2];
    float y0 = p0 * w[0] + p1 * w[3] + p2 * w[6];
    float y1 = p0 * w[1] + p1 * w[4] + p2 * w[7];
    float y2 = p0 * w[2] + p1 * w[5] + p2 * w[8];
    float a0 = fmaxf(y0 * sc1[0] + sh1[0], 0.f);
    float a1 = fmaxf(y1 * sc1[1] + sh1[1], 0.f);
    float a2 = fmaxf(y2 * sc1[2] + sh1[2], 0.f);
    float y = a0 * wc0 + a1 * wc1 + a2 * wc2;
    s += y;
    ss += y * y;
  }
  atomicAdd(&stats2[c], s);
  atomicAdd(&stats2[CIN + c], ss);
}

// ---------------- prep: pnb (normalized bf16, rows 27..31 zero) + weights^T ----
__global__ void k_prep(const float* __restrict__ pos_enc,
                       const float* __restrict__ wq,
                       const float* __restrict__ wv,
                       const float* __restrict__ w3,
                       const float* __restrict__ wo,
                       __hip_bfloat16* __restrict__ pnb,
                       __hip_bfloat16* __restrict__ wqT,
                       __hip_bfloat16* __restrict__ wvT,
                       __hip_bfloat16* __restrict__ w3T,
                       __hip_bfloat16* __restrict__ woT) {
  int g = blockIdx.x * 256 + threadIdx.x;
  if (g < 256) {  // (kk,h) pair
    int kk = g >> 3, h = g & 7;
    if (kk < KVOL) {
      const float* src = pos_enc + (kk * NHEAD + h) * CHD;
      float vals[CHD];
      float s = 0.f;
#pragma unroll
      for (int i = 0; i < CHD; ++i) {
        vals[i] = src[i];
        s += vals[i] * vals[i];
      }
      float inv = 1.f / fmaxf(sqrtf(s), EPS_NORM);
#pragma unroll
      for (int i = 0; i < CHD; ++i)
        pnb[kk * CIN + h * CHD + i] = __float2bfloat16(vals[i] * inv);
    } else {
#pragma unroll
      for (int i = 0; i < CHD; ++i)
        pnb[kk * CIN + h * CHD + i] = __float2bfloat16(0.f);
    }
  }
  if (g < CIN * CIN) {
    int k = g >> 7, c = g & 127;
    int gt = c * CIN + k;
    wqT[gt] = __float2bfloat16(wq[g]);
    wvT[gt] = __float2bfloat16(wv[g]);
    w3T[gt] = __float2bfloat16(w3[g]);
    woT[gt] = __float2bfloat16(wo[g]);
  }
}

// ---------------- sort: histogram / hierarchical padded scan / scatter ---------
__global__ void k_hist(const int* __restrict__ q_idx, int* __restrict__ cnt,
                       int M) {
  for (int i = blockIdx.x * blockDim.x + threadIdx.x; i < M;
       i += gridDim.x * blockDim.x)
    atomicAdd(&cnt[q_idx[i]], 1);
}

__global__ __launch_bounds__(256) void k_scan1(const int* __restrict__ cnt,
                                               int* __restrict__ poffs,
                                               int* __restrict__ bsum, int N) {
  __shared__ int ws_[4];
  int t = threadIdx.x;
  int l = t & 63, w = t >> 6;
  int base = blockIdx.x * 1024 + t * 4;
  int pc[4];
  int s = 0;
#pragma unroll
  for (int j = 0; j < 4; ++j) {
    int c = (base + j < N) ? cnt[base + j] : 0;
    pc[j] = (c + 7) & ~7;
    s += pc[j];
  }
  int own = s;
  for (int off = 1; off < 64; off <<= 1) {
    int v = __shfl_up(s, off);
    if (l >= off) s += v;
  }
  if (l == 63) ws_[w] = s;
  __syncthreads();
  int wbase = 0;
#pragma unroll
  for (int i = 0; i < 4; ++i)
    if (i < w) wbase += ws_[i];
  int ex = wbase + s - own;
#pragma unroll
  for (int j = 0; j < 4; ++j) {
    if (base + j < N) poffs[base + j] = ex;
    ex += pc[j];
  }
  if (t == 255) bsum[blockIdx.x] = wbase + s;
}

__global__ __launch_bounds__(256) void k_scan2(int* __restrict__ bsum,
                                               int* __restrict__ bbase, int NB,
                                               int* __restrict__ poffsN) {
  __shared__ int ws_[4];
  int t = threadIdx.x;
  int l = t & 63, w = t >> 6;
  int s = (t < NB) ? bsum[t] : 0;
  int own = s;
  for (int off = 1; off < 64; off <<= 1) {
    int v = __shfl_up(s, off);
    if (l >= off) s += v;
  }
  if (l == 63) ws_[w] = s;
  __syncthreads();
  int wbase = 0;
#pragma unroll
  for (int i = 0; i < 4; ++i)
    if (i < w) wbase += ws_[i];
  if (t < NB) bbase[t] = wbase + s - own;
  if (t == 255) *poffsN = wbase + s;
}

__global__ __launch_bounds__(256) void k_scan3(const int* __restrict__ cnt,
                                               int* __restrict__ poffs,
                                               const int* __restrict__ bbase,
                                               int* __restrict__ cursor,
                                               unsigned* __restrict__ recs,
                                               int N) {
  int t = threadIdx.x;
  int base = blockIdx.x * 1024 + t * 4;
  int bb = bbase[blockIdx.x];
#pragma unroll
  for (int j = 0; j < 4; ++j) {
    int i = base + j;
    if (i >= N) break;
    int o = poffs[i] + bb;
    poffs[i] = o;
    cursor[i] = o;
    int c = cnt[i];
    int pcend = o + ((c + 7) & ~7);
    for (int p = o + c; p < pcend; ++p) recs[p] = 27u << 17;
  }
}

__global__ void k_scatter_rec(const int* __restrict__ q_idx,
                              const int* __restrict__ k_idx,
                              const int* __restrict__ kernel_idx,
                              int* __restrict__ cursor,
                              unsigned* __restrict__ recs, int M) {
  for (int i = blockIdx.x * blockDim.x + threadIdx.x; i < M;
       i += gridDim.x * blockDim.x) {
    int qi = q_idx[i];
    int pos = atomicAdd(&cursor[qi], 1);
    unsigned rec = (unsigned)k_idx[i] | ((unsigned)kernel_idx[i] << 17);
    __builtin_nontemporal_store(rec, &recs[pos]);
  }
}

// ---------------- qv: per-point chain via MFMA; coalesced qn+v stores ----------
// 256 thr = 4 waves, 32 points/block.
__global__ __launch_bounds__(256) void k_qv(
    const float* __restrict__ points, const float* __restrict__ feats,
    const float* __restrict__ w1, const float* __restrict__ g1,
    const float* __restrict__ b1, const float* __restrict__ w2,
    const float* __restrict__ g2, const float* __restrict__ b2,
    const float* __restrict__ b3, const float* __restrict__ bq,
    const float* __restrict__ bv, const __hip_bfloat16* __restrict__ w3T,
    const __hip_bfloat16* __restrict__ wqT,
    const __hip_bfloat16* __restrict__ wvT, const float* __restrict__ stats1,
    const float* __restrict__ stats2, __hip_bfloat16* __restrict__ qnout,
    __hip_bfloat16* __restrict__ vout, int N) {
  __shared__ float h0s[32][3];
  __shared__ __hip_bfloat16 h1s[32][136];  // h1, then v staging
  __shared__ __hip_bfloat16 xs[32][136];   // x, then qn staging

  int t = threadIdx.x;
  int n0 = blockIdx.x * 32;

  // phase 0: h0 = relu(bn1(points@w1))
  if (t < 32) {
    int n = n0 + t;
    float p0 = 0.f, p1 = 0.f, p2 = 0.f;
    if (n < N) {
      p0 = points[3 * n];
      p1 = points[3 * n + 1];
      p2 = points[3 * n + 2];
    }
#pragma unroll
    for (int j = 0; j < 3; ++j) {
      float m = stats1[j] / (float)N;
      float var = stats1[3 + j] / (float)N - m * m;
      float sc = rsqrtf(var + EPS_BN) * g1[j];
      float sh = b1[j] - m * sc;
      float y = p0 * w1[j] + p1 * w1[3 + j] + p2 * w1[6 + j];
      h0s[t][j] = fmaxf(y * sc + sh, 0.f);
    }
  }
  __syncthreads();

  // phase 1: h1 = relu(bn2(h0@w2)) -> LDS bf16
  {
    int c = t & 127, half = t >> 7;
    float m2 = stats2[c] / (float)N;
    float v2 = stats2[CIN + c] / (float)N - m2 * m2;
    float sc2 = rsqrtf(v2 + EPS_BN) * g2[c];
    float sh2 = b2[c] - m2 * sc2;
    float wc0 = w2[c], wc1 = w2[CIN + c], wc2 = w2[2 * CIN + c];
#pragma unroll
    for (int i = 0; i < 16; ++i) {
      int p = i * 2 + half;
      float y = h0s[p][0] * wc0 + h0s[p][1] * wc1 + h0s[p][2] * wc2;
      h1s[p][c] = __float2bfloat16(fmaxf(y * sc2 + sh2, 0.f));
    }
  }
  __syncthreads();

  int w = t >> 6, l = t & 63;
  int lr = l & 15, lg = l >> 4;
  int colbase = w * 32;

  // phase 2: x = feats + h1@w3 + b3 -> LDS bf16
  {
    f32x4 acc[2][2];
#pragma unroll
    for (int nt = 0; nt < 2; ++nt) {
      float bc = b3[colbase + nt * 16 + lr];
#pragma unroll
      for (int mt = 0; mt < 2; ++mt) acc[mt][nt] = {bc, bc, bc, bc};
    }
#pragma unroll
    for (int kk = 0; kk < 4; ++kk) {
      short8 aA[2], bB[2];
#pragma unroll
      for (int mt = 0; mt < 2; ++mt)
        aA[mt] = *(const short8*)((const char*)h1s + (mt * 16 + lr) * 272 +
                                  (kk * 32 + lg * 8) * 2);
#pragma unroll
      for (int nt = 0; nt < 2; ++nt)
        bB[nt] = *(const short8*)((const char*)w3T +
                                  ((size_t)(colbase + nt * 16 + lr) * CIN +
                                   kk * 32 + lg * 8) *
                                      2);
#pragma unroll
      for (int mt = 0; mt < 2; ++mt)
#pragma unroll
        for (int nt = 0; nt < 2; ++nt)
          acc[mt][nt] = __builtin_amdgcn_mfma_f32_16x16x32_bf16(
              aA[mt], bB[nt], acc[mt][nt], 0, 0, 0);
    }
#pragma unroll
    for (int mt = 0; mt < 2; ++mt)
#pragma unroll
      for (int nt = 0; nt < 2; ++nt)
#pragma unroll
        for (int r = 0; r < 4; ++r) {
          int row = mt * 16 + lg * 4 + r;
          int col = colbase + nt * 16 + lr;
          int n = n0 + row;
          float f = (n < N) ? feats[(size_t)n * CIN + col] : 0.f;
          xs[row][col] = __float2bfloat16(acc[mt][nt][r] + f);
        }
  }
  __syncthreads();

  // phase 3: q = x@wq + bq, v = x@wv + bv
  f32x4 aq[2][2], av[2][2];
#pragma unroll
  for (int nt = 0; nt < 2; ++nt) {
    float bqc = bq[colbase + nt * 16 + lr];
    float bvc = bv[colbase + nt * 16 + lr];
#pragma unroll
    for (int mt = 0; mt < 2; ++mt) {
      aq[mt][nt] = {bqc, bqc, bqc, bqc};
      av[mt][nt] = {bvc, bvc, bvc, bvc};
    }
  }
#pragma unroll
  for (int kk = 0; kk < 4; ++kk) {
    short8 aA[2], bQ[2], bV[2];
#pragma unroll
    for (int mt = 0; mt < 2; ++mt)
      aA[mt] = *(const short8*)((const char*)xs + (mt * 16 + lr) * 272 +
                                (kk * 32 + lg * 8) * 2);
#pragma unroll
    for (int nt = 0; nt < 2; ++nt) {
      size_t off =
          ((size_t)(colbase + nt * 16 + lr) * CIN + kk * 32 + lg * 8) * 2;
      bQ[nt] = *(const short8*)((const char*)wqT + off);
      bV[nt] = *(const short8*)((const char*)wvT + off);
    }
#pragma unroll
    for (int mt = 0; mt < 2; ++mt)
#pragma unroll
      for (int nt = 0; nt < 2; ++nt) {
        aq[mt][nt] = __builtin_amdgcn_mfma_f32_16x16x32_bf16(aA[mt], bQ[nt],
                                                             aq[mt][nt], 0, 0, 0);
        av[mt][nt] = __builtin_amdgcn_mfma_f32_16x16x32_bf16(aA[mt], bV[nt],
                                                             av[mt][nt], 0, 0, 0);
      }
  }
  __syncthreads();  // xs/h1s reads complete

  // phase 4: L2-norm q -> qn into xs; v -> h1s
#pragma unroll
  for (int mt = 0; mt < 2; ++mt)
#pragma unroll
    for (int nt = 0; nt < 2; ++nt)
#pragma unroll
      for (int r = 0; r < 4; ++r) {
        float q = aq[mt][nt][r];
        float s = q * q;
        s += __shfl_xor(s, 1);
        s += __shfl_xor(s, 2);
        s += __shfl_xor(s, 4);
        s += __shfl_xor(s, 8);
        float inv = 1.f / fmaxf(sqrtf(s), EPS_NORM);
        int row = mt * 16 + lg * 4 + r;
        int col = colbase + nt * 16 + lr;
        xs[row][col] = __float2bfloat16(q * inv);
        h1s[row][col] = __float2bfloat16(av[mt][nt][r]);
      }
  __syncthreads();

  // phase 5: coalesced stores (32 rows x 256 B each)
  {
    int row = t >> 3, part = t & 7;
    int n = n0 + row;
    if (n < N) {
      const char* srcq = (const char*)&xs[row][0] + part * 32;
      char* dstq = (char*)qnout + (size_t)n * 256 + part * 32;
      *(uint4*)dstq = *(const uint4*)srcq;
      *(uint4*)(dstq + 16) = *(const uint4*)(srcq + 16);
      const char* srcv = (const char*)&h1s[row][0] + part * 32;
      char* dstv = (char*)vout + (size_t)n * 256 + part * 32;
      *(uint4*)dstv = *(const uint4*)srcv;
      *(uint4*)(dstv + 16) = *(const uint4*)(srcv + 16);
    }
  }
}

// ---------------- gather + in-block dots + out projection ----------------------
// 512 thr = 8 waves; block owns 32 points (4/wave).
__global__ __launch_bounds__(512) void k_gather_out(
    const unsigned* __restrict__ recs, const int* __restrict__ poffs,
    const __hip_bfloat16* __restrict__ qn, const __hip_bfloat16* __restrict__ v,
    const __hip_bfloat16* __restrict__ pnb,
    const __hip_bfloat16* __restrict__ woT, const float* __restrict__ bo,
    float* __restrict__ out, int N) {
  __shared__ __hip_bfloat16 accs[32][136];    // qn staging, then attn acc
  __shared__ unsigned short dotlds[32][256];  // bf16 dots [n-local][kk*8+h]
  int t = threadIdx.x;
  int w = t >> 6, l = t & 63;
  int h = l >> 3;
  int n0 = blockIdx.x * 32;
  const char* vbase = (const char*)v + 4 * l;

  // stage qn rows (32 x 256B, coalesced)
  {
    int row = t >> 4, part = t & 15;
    int n = n0 + row;
    uint4 val = {0u, 0u, 0u, 0u};
    if (n < N)
      val = *(const uint4*)((const char*)qn + (size_t)n * 256 + part * 16);
    *(uint4*)((char*)&accs[row][0] + part * 16) = val;
  }
  __syncthreads();

  // dots MFMAs: wave w -> rowgroup w&1, heads {(w>>1)*2, +1}; kk halves 0/1
  {
    int lr = l & 15, lg = l >> 4;
    int rg = w & 1;
    const short8 zero8 = {0, 0, 0, 0, 0, 0, 0, 0};
#pragma unroll
    for (int hh = 0; hh < 2; ++hh) {
      int hx = (w >> 1) * 2 + hh;
      short8 aA = zero8, bB0 = zero8, bB1 = zero8;
      if (lg < 2) {
        aA = *(const short8*)((const char*)&accs[rg * 16 + lr][0] +
                              (hx * CHD + lg * 8) * 2);
        bB0 = *(const short8*)(pnb + lr * CIN + hx * CHD + lg * 8);
        bB1 = *(const short8*)(pnb + (16 + lr) * CIN + hx * CHD + lg * 8);
      }
      f32x4 c0 = {0.f, 0.f, 0.f, 0.f}, c1 = {0.f, 0.f, 0.f, 0.f};
      c0 = __builtin_amdgcn_mfma_f32_16x16x32_bf16(aA, bB0, c0, 0, 0, 0);
      c1 = __builtin_amdgcn_mfma_f32_16x16x32_bf16(aA, bB1, c1, 0, 0, 0);
#pragma unroll
      for (int r = 0; r < 4; ++r) {
        int row = rg * 16 + lg * 4 + r;
        __hip_bfloat16 b0 = __float2bfloat16(c0[r]);
        __hip_bfloat16 b1 = __float2bfloat16(c1[r]);
        dotlds[row][lr * 8 + hx] = *(unsigned short*)&b0;
        dotlds[row][(16 + lr) * 8 + hx] = *(unsigned short*)&b1;
      }
    }
  }
  __syncthreads();

  // gather: wave w handles points w*4..w*4+4
#pragma unroll 1
  for (int j = 0; j < 4; ++j) {
    int nl = w * 4 + j;
    int n = n0 + nl;
    float ax = 0.f, ay = 0.f;
    if (n < N) {
      const unsigned short* dptr = &dotlds[nl][0];
      int beg = poffs[n], end = poffs[n + 1];
      for (int idx = beg; idx < end; idx += 8) {
        unsigned r0 = recs[idx + 0], r1 = recs[idx + 1], r2 = recs[idx + 2],
                 r3 = recs[idx + 3], r4 = recs[idx + 4], r5 = recs[idx + 5],
                 r6 = recs[idx + 6], r7 = recs[idx + 7];
        unsigned v0 = *(const unsigned*)(vbase + (size_t)(r0 & 0x1FFFF) * 256);
        unsigned v1 = *(const unsigned*)(vbase + (size_t)(r1 & 0x1FFFF) * 256);
        unsigned v2 = *(const unsigned*)(vbase + (size_t)(r2 & 0x1FFFF) * 256);
        unsigned v3 = *(const unsigned*)(vbase + (size_t)(r3 & 0x1FFFF) * 256);
        unsigned v4 = *(const unsigned*)(vbase + (size_t)(r4 & 0x1FFFF) * 256);
        unsigned v5 = *(const unsigned*)(vbase + (size_t)(r5 & 0x1FFFF) * 256);
        unsigned v6 = *(const unsigned*)(vbase + (size_t)(r6 & 0x1FFFF) * 256);
        unsigned v7 = *(const unsigned*)(vbase + (size_t)(r7 & 0x1FFFF) * 256);
        float a0 = bfus(dptr[(r0 >> 17) * 8 + h]);
        float a1 = bfus(dptr[(r1 >> 17) * 8 + h]);
        float a2 = bfus(dptr[(r2 >> 17) * 8 + h]);
        float a3 = bfus(dptr[(r3 >> 17) * 8 + h]);
        float a4 = bfus(dptr[(r4 >> 17) * 8 + h]);
        float a5 = bfus(dptr[(r5 >> 17) * 8 + h]);
        float a6 = bfus(dptr[(r6 >> 17) * 8 + h]);
        float a7 = bfus(dptr[(r7 >> 17) * 8 + h]);
        ax += a0 * bflo(v0);
        ay += a0 * bfhi(v0);
        ax += a1 * bflo(v1);
        ay += a1 * bfhi(v1);
        ax += a2 * bflo(v2);
        ay += a2 * bfhi(v2);
        ax += a3 * bflo(v3);
        ay += a3 * bfhi(v3);
        ax += a4 * bflo(v4);
        ay += a4 * bfhi(v4);
        ax += a5 * bflo(v5);
        ay += a5 * bfhi(v5);
        ax += a6 * bflo(v6);
        ay += a6 * bfhi(v6);
        ax += a7 * bflo(v7);
        ay += a7 * bfhi(v7);
      }
    }
    __hip_bfloat16 bx = __float2bfloat16(ax), by = __float2bfloat16(ay);
    unsigned pk = (unsigned)*(unsigned short*)&bx |
                  ((unsigned)*(unsigned short*)&by << 16);
    ((unsigned*)((char*)accs + nl * 272))[l] = pk;
  }
  __syncthreads();

  // epilogue: out[n0..n0+32) = accs @ wo + bo ; wave w -> cols [16w,16w+16)
  int lr = l & 15, lg = l >> 4;
  int colb = w * 16;
  float bc = bo[colb + lr];
  f32x4 acc0 = {bc, bc, bc, bc}, acc1 = {bc, bc, bc, bc};
#pragma unroll
  for (int kk = 0; kk < 4; ++kk) {
    short8 aA0 = *(const short8*)((const char*)accs + lr * 272 +
                                  (kk * 32 + lg * 8) * 2);
    short8 aA1 = *(const short8*)((const char*)accs + (16 + lr) * 272 +
                                  (kk * 32 + lg * 8) * 2);
    short8 bB = *(const short8*)(woT + (size_t)(colb + lr) * CIN + kk * 32 +
                                 lg * 8);
    acc0 = __builtin_amdgcn_mfma_f32_16x16x32_bf16(aA0, bB, acc0, 0, 0, 0);
    acc1 = __builtin_amdgcn_mfma_f32_16x16x32_bf16(aA1, bB, acc1, 0, 0, 0);
  }
#pragma unroll
  for (int r = 0; r < 4; ++r) {
    int nr0 = n0 + lg * 4 + r;
    int nr1 = nr0 + 16;
    if (nr0 < N) out[(size_t)nr0 * CIN + colb + lr] = acc0[r];
    if (nr1 < N) out[(size_t)nr1 * CIN + colb + lr] = acc1[r];
  }
}

// ---------------- launch -------------------------------------------------------
extern "C" void kernel_launch(void* const* d_in, const int* in_sizes, int n_in,
                              void* d_out, int out_size, void* d_ws,
                              size_t ws_size, hipStream_t stream) {
  const float* points = (const float*)d_in[0];
  const float* feats = (const float*)d_in[1];
  const int* k_idx = (const int*)d_in[2];
  const int* q_idx = (const int*)d_in[3];
  const int* kernel_idx = (const int*)d_in[4];
  const float* w1 = (const float*)d_in[5];
  const float* g1 = (const float*)d_in[6];
  const float* b1 = (const float*)d_in[7];
  const float* w2 = (const float*)d_in[8];
  const float* g2 = (const float*)d_in[9];
  const float* b2 = (const float*)d_in[10];
  const float* w3 = (const float*)d_in[11];
  const float* b3 = (const float*)d_in[12];
  const float* wq = (const float*)d_in[13];
  const float* bq = (const float*)d_in[14];
  const float* wv = (const float*)d_in[15];
  const float* bv = (const float*)d_in[16];
  const float* wo = (const float*)d_in[17];
  const float* bo = (const float*)d_in[18];
  const float* pos_enc = (const float*)d_in[19];

  int N = in_sizes[0] / 3;
  int M = in_sizes[2];
  int NB = (N + 1023) / 1024;  // <= 256
  int Np = (N + 4) & ~3;

  float* ws = (float*)d_ws;
  float* stats1 = ws;                                 // 8
  float* stats2 = ws + 8;                             // 256 (ends 264)
  __hip_bfloat16* pnb = (__hip_bfloat16*)(ws + 264);  // 32*128 bf16 (ends 2312)
  int* cnt = (int*)(ws + 4096);                       // Np
  int* poffs = cnt + Np;                              // Np (N+1 used)
  int* cursor = poffs + Np;                           // Np
  int* bsum = cursor + Np;                            // 512
  int* bbase = bsum + 512;                            // 512
  unsigned* recs = (unsigned*)(bbase + 512);          // M + 8N (padded)
  size_t recn = ((size_t)M + 8 * (size_t)N + 7) & ~(size_t)7;
  __hip_bfloat16* qnb = (__hip_bfloat16*)(recs + recn);  // N*128
  __hip_bfloat16* vb = qnb + (size_t)N * CIN;            // N*128
  __hip_bfloat16* wqT = vb + (size_t)N * CIN;
  __hip_bfloat16* wvT = wqT + CIN * CIN;
  __hip_bfloat16* w3T = wvT + CIN * CIN;
  __hip_bfloat16* woT = w3T + CIN * CIN;
  float* outf = (float*)d_out;

  hipMemsetAsync(ws, 0, 4096 * sizeof(float), stream);
  hipMemsetAsync(cnt, 0, (size_t)Np * sizeof(int), stream);

  k_bn1_stats<<<256, 256, 0, stream>>>(points, w1, stats1, N);
  k_bn2_stats<<<512, 128, 0, stream>>>(points, w1, g1, b1, w2, stats1, stats2, N);
  k_prep<<<64, 256, 0, stream>>>(pos_enc, wq, wv, w3, wo, pnb, wqT, wvT, w3T, woT);
  k_hist<<<4096, 256, 0, stream>>>(q_idx, cnt, M);
  k_scan1<<<NB, 256, 0, stream>>>(cnt, poffs, bsum, N);
  k_scan2<<<1, 256, 0, stream>>>(bsum, bbase, NB, poffs + N);
  k_scan3<<<NB, 256, 0, stream>>>(cnt, poffs, bbase, cursor, recs, N);
  k_scatter_rec<<<4096, 256, 0, stream>>>(q_idx, k_idx, kernel_idx, cursor, recs, M);
  k_qv<<<(N + 31) / 32, 256, 0, stream>>>(points, feats, w1, g1, b1, w2, g2, b2,
                                          b3, bq, bv, w3T, wqT, wvT, stats1,
                                          stats2, qnb, vb, N);
  k_gather_out<<<(N + 31) / 32, 512, 0, stream>>>(recs, poffs, qnb, vb, pnb,
                                                  woT, bo, outf, N);
}

// Round 11
// 380.339 us; speedup vs baseline: 2.3610x; 1.1255x over previous
//
#include <hip/hip_runtime.h>
#include <hip/hip_bf16.h>

#define CIN 128
#define NHEAD 8
#define CHD 16
#define KVOL 27
#define NBKT_MAX 512
#define CH 4096

constexpr float EPS_BN = 1e-5f;
constexpr float EPS_NORM = 1e-12f;

typedef __attribute__((ext_vector_type(8))) short short8;
typedef __attribute__((ext_vector_type(4))) float f32x4;

__device__ __forceinline__ float bflo(unsigned u) {
  return __uint_as_float(u << 16);
}
__device__ __forceinline__ float bfhi(unsigned u) {
  return __uint_as_float(u & 0xffff0000u);
}
__device__ __forceinline__ float bfus(unsigned short u) {
  return __uint_as_float((unsigned)u << 16);
}

// ---------------- BN1 statistics ----------------------------------------------
__global__ void k_bn1_stats(const float* __restrict__ points,
                            const float* __restrict__ w1,
                            float* __restrict__ stats1, int N) {
  float w[9];
#pragma unroll
  for (int i = 0; i < 9; ++i) w[i] = w1[i];
  float s[3] = {0.f, 0.f, 0.f}, ss[3] = {0.f, 0.f, 0.f};
  for (int n = blockIdx.x * blockDim.x + threadIdx.x; n < N;
       n += gridDim.x * blockDim.x) {
    float p0 = points[3 * n], p1 = points[3 * n + 1], p2 = points[3 * n + 2];
#pragma unroll
    for (int j = 0; j < 3; ++j) {
      float y = p0 * w[j] + p1 * w[3 + j] + p2 * w[6 + j];
      s[j] += y;
      ss[j] += y * y;
    }
  }
#pragma unroll
  for (int j = 0; j < 3; ++j) {
    for (int off = 32; off > 0; off >>= 1) {
      s[j] += __shfl_down(s[j], off);
      ss[j] += __shfl_down(ss[j], off);
    }
  }
  if ((threadIdx.x & 63) == 0) {
#pragma unroll
    for (int j = 0; j < 3; ++j) {
      atomicAdd(&stats1[j], s[j]);
      atomicAdd(&stats1[3 + j], ss[j]);
    }
  }
}

// ---------------- BN2 statistics ----------------------------------------------
__global__ void k_bn2_stats(const float* __restrict__ points,
                            const float* __restrict__ w1,
                            const float* __restrict__ g1,
                            const float* __restrict__ b1,
                            const float* __restrict__ w2,
                            const float* __restrict__ stats1,
                            float* __restrict__ stats2, int N) {
  int c = threadIdx.x;
  float w[9];
#pragma unroll
  for (int i = 0; i < 9; ++i) w[i] = w1[i];
  float sc1[3], sh1[3];
#pragma unroll
  for (int j = 0; j < 3; ++j) {
    float m = stats1[j] / (float)N;
    float var = stats1[3 + j] / (float)N - m * m;
    float sc = rsqrtf(var + EPS_BN) * g1[j];
    sc1[j] = sc;
    sh1[j] = b1[j] - m * sc;
  }
  float wc0 = w2[c], wc1 = w2[CIN + c], wc2 = w2[2 * CIN + c];
  float s = 0.f, ss = 0.f;
  for (int n = blockIdx.x; n < N; n += gridDim.x) {
    float p0 = points[3 * n], p1 = points[3 * n + 1], p2 = points[3 * n + 2];
    float y0 = p0 * w[0] + p1 * w[3] + p2 * w[6];
    float y1 = p0 * w[1] + p1 * w[4] + p2 * w[7];
    float y2 = p0 * w[2] + p1 * w[5] + p2 * w[8];
    float a0 = fmaxf(y0 * sc1[0] + sh1[0], 0.f);
    float a1 = fmaxf(y1 * sc1[1] + sh1[1], 0.f);
    float a2 = fmaxf(y2 * sc1[2] + sh1[2], 0.f);
    float y = a0 * wc0 + a1 * wc1 + a2 * wc2;
    s += y;
    ss += y * y;
  }
  atomicAdd(&stats2[c], s);
  atomicAdd(&stats2[CIN + c], ss);
}

// ---------------- prep: pnb (normalized bf16, rows 27..31 zero) + weights^T ----
__global__ void k_prep(const float* __restrict__ pos_enc,
                       const float* __restrict__ wq,
                       const float* __restrict__ wv,
                       const float* __restrict__ w3,
                       const float* __restrict__ wo,
                       __hip_bfloat16* __restrict__ pnb,
                       __hip_bfloat16* __restrict__ wqT,
                       __hip_bfloat16* __restrict__ wvT,
                       __hip_bfloat16* __restrict__ w3T,
                       __hip_bfloat16* __restrict__ woT) {
  int g = blockIdx.x * 256 + threadIdx.x;
  if (g < 256) {  // (kk,h) pair
    int kk = g >> 3, h = g & 7;
    if (kk < KVOL) {
      const float* src = pos_enc + (kk * NHEAD + h) * CHD;
      float vals[CHD];
      float s = 0.f;
#pragma unroll
      for (int i = 0; i < CHD; ++i) {
        vals[i] = src[i];
        s += vals[i] * vals[i];
      }
      float inv = 1.f / fmaxf(sqrtf(s), EPS_NORM);
#pragma unroll
      for (int i = 0; i < CHD; ++i)
        pnb[kk * CIN + h * CHD + i] = __float2bfloat16(vals[i] * inv);
    } else {
#pragma unroll
      for (int i = 0; i < CHD; ++i)
        pnb[kk * CIN + h * CHD + i] = __float2bfloat16(0.f);
    }
  }
  if (g < CIN * CIN) {
    int k = g >> 7, c = g & 127;
    int gt = c * CIN + k;
    wqT[gt] = __float2bfloat16(wq[g]);
    wvT[gt] = __float2bfloat16(wv[g]);
    w3T[gt] = __float2bfloat16(w3[g]);
    woT[gt] = __float2bfloat16(wo[g]);
  }
}

// ---------------- sort: histogram / scan / bucketed counting sort --------------
__global__ void k_hist(const int* __restrict__ q_idx, int* __restrict__ cnt,
                       int M) {
  for (int i = blockIdx.x * blockDim.x + threadIdx.x; i < M;
       i += gridDim.x * blockDim.x)
    atomicAdd(&cnt[q_idx[i]], 1);
}

__global__ __launch_bounds__(256) void k_scan1(const int* __restrict__ cnt,
                                               int* __restrict__ poffs,
                                               int* __restrict__ bsum, int N) {
  __shared__ int ws_[4];
  int t = threadIdx.x;
  int l = t & 63, w = t >> 6;
  int base = blockIdx.x * 1024 + t * 4;
  int pc[4];
  int s = 0;
#pragma unroll
  for (int j = 0; j < 4; ++j) {
    int c = (base + j < N) ? cnt[base + j] : 0;
    pc[j] = (c + 7) & ~7;
    s += pc[j];
  }
  int own = s;
  for (int off = 1; off < 64; off <<= 1) {
    int v = __shfl_up(s, off);
    if (l >= off) s += v;
  }
  if (l == 63) ws_[w] = s;
  __syncthreads();
  int wbase = 0;
#pragma unroll
  for (int i = 0; i < 4; ++i)
    if (i < w) wbase += ws_[i];
  int ex = wbase + s - own;
#pragma unroll
  for (int j = 0; j < 4; ++j) {
    if (base + j < N) poffs[base + j] = ex;
    ex += pc[j];
  }
  if (t == 255) bsum[blockIdx.x] = wbase + s;
}

__global__ __launch_bounds__(256) void k_scan2(int* __restrict__ bsum,
                                               int* __restrict__ bbase, int NB,
                                               int* __restrict__ poffsN) {
  __shared__ int ws_[4];
  int t = threadIdx.x;
  int l = t & 63, w = t >> 6;
  int s = (t < NB) ? bsum[t] : 0;
  int own = s;
  for (int off = 1; off < 64; off <<= 1) {
    int v = __shfl_up(s, off);
    if (l >= off) s += v;
  }
  if (l == 63) ws_[w] = s;
  __syncthreads();
  int wbase = 0;
#pragma unroll
  for (int i = 0; i < 4; ++i)
    if (i < w) wbase += ws_[i];
  if (t < NB) bbase[t] = wbase + s - own;
  if (t == 255) *poffsN = wbase + s;
}

// finalize poffs (+bbase) and fill pad records
__global__ __launch_bounds__(256) void k_scan3(const int* __restrict__ cnt,
                                               int* __restrict__ poffs,
                                               const int* __restrict__ bbase,
                                               unsigned* __restrict__ recs,
                                               int N) {
  int t = threadIdx.x;
  int base = blockIdx.x * 1024 + t * 4;
  int bb = bbase[blockIdx.x];
#pragma unroll
  for (int j = 0; j < 4; ++j) {
    int i = base + j;
    if (i >= N) break;
    int o = poffs[i] + bb;
    poffs[i] = o;
    int c = cnt[i];
    int pcend = o + ((c + 7) & ~7);
    for (int p = o + c; p < pcend; ++p) recs[p] = 27u << 17;
  }
}

// bucket cursors: bcur[b] = poffs[min(b<<8, N)]
__global__ void k_binit(const int* __restrict__ poffs, int* __restrict__ bcur,
                        int N) {
  int b = threadIdx.x + blockIdx.x * 256;
  if (b < NBKT_MAX) {
    int q = b << 8;
    bcur[b] = poffs[q < N ? q : N];
  }
}

// pass 1: LDS-staged multi-split into 512 coarse buckets (q>>8).
// entry u32 = k(17) | kk(5)<<17 | (q&255)<<22
__global__ __launch_bounds__(256) void k_bucket1(
    const int* __restrict__ q_idx, const int* __restrict__ k_idx,
    const int* __restrict__ kernel_idx, int* __restrict__ bcur,
    unsigned* __restrict__ stg, int M) {
  __shared__ int lhist[NBKT_MAX];
  __shared__ int loffs[NBKT_MAX];
  __shared__ int lcur[NBKT_MAX];
  __shared__ int wsum[4];
  __shared__ unsigned buf[CH];
  int t = threadIdx.x;
  int base = blockIdx.x * CH;
  for (int b = t; b < NBKT_MAX; b += 256) lhist[b] = 0;
  __syncthreads();

  int qv[16];
#pragma unroll
  for (int j = 0; j < 16; ++j) {
    int i = base + t + j * 256;
    int q = (i < M) ? q_idx[i] : -1;
    qv[j] = q;
    if (q >= 0) atomicAdd(&lhist[q >> 8], 1);
  }
  __syncthreads();

  // exclusive scan of lhist[512]: thread t owns entries 2t, 2t+1
  {
    int s0 = lhist[2 * t], s1 = lhist[2 * t + 1];
    int s = s0 + s1;
    int l = t & 63, w = t >> 6;
    int ss = s;
    for (int off = 1; off < 64; off <<= 1) {
      int v = __shfl_up(ss, off);
      if (l >= off) ss += v;
    }
    if (l == 63) wsum[w] = ss;
    __syncthreads();
    int wb = 0;
#pragma unroll
    for (int i = 0; i < 4; ++i)
      if (i < w) wb += wsum[i];
    int ex = wb + ss - s;
    loffs[2 * t] = ex;
    loffs[2 * t + 1] = ex + s0;
    lcur[2 * t] = ex;
    lcur[2 * t + 1] = ex + s0;
  }
  __syncthreads();

  // reorder chunk into LDS by bucket
#pragma unroll
  for (int j = 0; j < 16; ++j) {
    int q = qv[j];
    if (q >= 0) {
      int i = base + t + j * 256;
      unsigned e = (unsigned)k_idx[i] | ((unsigned)kernel_idx[i] << 17) |
                   ((unsigned)(q & 255) << 22);
      int d = atomicAdd(&lcur[q >> 8], 1);
      buf[d] = e;
    }
  }
  __syncthreads();

  // bulk flush: one cursor bump per bucket, contiguous copy
  for (int b = t; b < NBKT_MAX; b += 256) {
    int cntb = lhist[b];
    if (cntb > 0) {
      int g = atomicAdd(&bcur[b], cntb);
      int lo = loffs[b];
      for (int j = 0; j < cntb; ++j) stg[g + j] = buf[lo + j];
    }
  }
}

// pass 2: one block per bucket; scatter within ~15KB region (single XCD).
__global__ __launch_bounds__(256) void k_bucket2(
    const unsigned* __restrict__ stg, const int* __restrict__ poffs,
    const int* __restrict__ bcur, unsigned* __restrict__ recs, int N) {
  __shared__ int qcur[256];
  int b = blockIdx.x;
  int t = threadIdx.x;
  int qbase = b << 8;
  int q = qbase + t;
  qcur[t] = (q < N) ? poffs[q] : 0;
  __syncthreads();
  int start = poffs[qbase];
  int bcnt = bcur[b] - start;
  for (int i = t; i < bcnt; i += 256) {
    unsigned e = stg[start + i];
    int ql = e >> 22;
    unsigned rec = e & 0x3FFFFFu;
    int pos = atomicAdd(&qcur[ql], 1);
    recs[pos] = rec;
  }
}

// ---------------- qv: per-point chain via MFMA; coalesced qn+v stores ----------
__global__ __launch_bounds__(256) void k_qv(
    const float* __restrict__ points, const float* __restrict__ feats,
    const float* __restrict__ w1, const float* __restrict__ g1,
    const float* __restrict__ b1, const float* __restrict__ w2,
    const float* __restrict__ g2, const float* __restrict__ b2,
    const float* __restrict__ b3, const float* __restrict__ bq,
    const float* __restrict__ bv, const __hip_bfloat16* __restrict__ w3T,
    const __hip_bfloat16* __restrict__ wqT,
    const __hip_bfloat16* __restrict__ wvT, const float* __restrict__ stats1,
    const float* __restrict__ stats2, __hip_bfloat16* __restrict__ qnout,
    __hip_bfloat16* __restrict__ vout, int N) {
  __shared__ float h0s[32][3];
  __shared__ __hip_bfloat16 h1s[32][136];
  __shared__ __hip_bfloat16 xs[32][136];

  int t = threadIdx.x;
  int n0 = blockIdx.x * 32;

  if (t < 32) {
    int n = n0 + t;
    float p0 = 0.f, p1 = 0.f, p2 = 0.f;
    if (n < N) {
      p0 = points[3 * n];
      p1 = points[3 * n + 1];
      p2 = points[3 * n + 2];
    }
#pragma unroll
    for (int j = 0; j < 3; ++j) {
      float m = stats1[j] / (float)N;
      float var = stats1[3 + j] / (float)N - m * m;
      float sc = rsqrtf(var + EPS_BN) * g1[j];
      float sh = b1[j] - m * sc;
      float y = p0 * w1[j] + p1 * w1[3 + j] + p2 * w1[6 + j];
      h0s[t][j] = fmaxf(y * sc + sh, 0.f);
    }
  }
  __syncthreads();

  {
    int c = t & 127, half = t >> 7;
    float m2 = stats2[c] / (float)N;
    float v2 = stats2[CIN + c] / (float)N - m2 * m2;
    float sc2 = rsqrtf(v2 + EPS_BN) * g2[c];
    float sh2 = b2[c] - m2 * sc2;
    float wc0 = w2[c], wc1 = w2[CIN + c], wc2 = w2[2 * CIN + c];
#pragma unroll
    for (int i = 0; i < 16; ++i) {
      int p = i * 2 + half;
      float y = h0s[p][0] * wc0 + h0s[p][1] * wc1 + h0s[p][2] * wc2;
      h1s[p][c] = __float2bfloat16(fmaxf(y * sc2 + sh2, 0.f));
    }
  }
  __syncthreads();

  int w = t >> 6, l = t & 63;
  int lr = l & 15, lg = l >> 4;
  int colbase = w * 32;

  {
    f32x4 acc[2][2];
#pragma unroll
    for (int nt = 0; nt < 2; ++nt) {
      float bc = b3[colbase + nt * 16 + lr];
#pragma unroll
      for (int mt = 0; mt < 2; ++mt) acc[mt][nt] = {bc, bc, bc, bc};
    }
#pragma unroll
    for (int kk = 0; kk < 4; ++kk) {
      short8 aA[2], bB[2];
#pragma unroll
      for (int mt = 0; mt < 2; ++mt)
        aA[mt] = *(const short8*)((const char*)h1s + (mt * 16 + lr) * 272 +
                                  (kk * 32 + lg * 8) * 2);
#pragma unroll
      for (int nt = 0; nt < 2; ++nt)
        bB[nt] = *(const short8*)((const char*)w3T +
                                  ((size_t)(colbase + nt * 16 + lr) * CIN +
                                   kk * 32 + lg * 8) *
                                      2);
#pragma unroll
      for (int mt = 0; mt < 2; ++mt)
#pragma unroll
        for (int nt = 0; nt < 2; ++nt)
          acc[mt][nt] = __builtin_amdgcn_mfma_f32_16x16x32_bf16(
              aA[mt], bB[nt], acc[mt][nt], 0, 0, 0);
    }
#pragma unroll
    for (int mt = 0; mt < 2; ++mt)
#pragma unroll
      for (int nt = 0; nt < 2; ++nt)
#pragma unroll
        for (int r = 0; r < 4; ++r) {
          int row = mt * 16 + lg * 4 + r;
          int col = colbase + nt * 16 + lr;
          int n = n0 + row;
          float f = (n < N) ? feats[(size_t)n * CIN + col] : 0.f;
          xs[row][col] = __float2bfloat16(acc[mt][nt][r] + f);
        }
  }
  __syncthreads();

  f32x4 aq[2][2], av[2][2];
#pragma unroll
  for (int nt = 0; nt < 2; ++nt) {
    float bqc = bq[colbase + nt * 16 + lr];
    float bvc = bv[colbase + nt * 16 + lr];
#pragma unroll
    for (int mt = 0; mt < 2; ++mt) {
      aq[mt][nt] = {bqc, bqc, bqc, bqc};
      av[mt][nt] = {bvc, bvc, bvc, bvc};
    }
  }
#pragma unroll
  for (int kk = 0; kk < 4; ++kk) {
    short8 aA[2], bQ[2], bV[2];
#pragma unroll
    for (int mt = 0; mt < 2; ++mt)
      aA[mt] = *(const short8*)((const char*)xs + (mt * 16 + lr) * 272 +
                                (kk * 32 + lg * 8) * 2);
#pragma unroll
    for (int nt = 0; nt < 2; ++nt) {
      size_t off =
          ((size_t)(colbase + nt * 16 + lr) * CIN + kk * 32 + lg * 8) * 2;
      bQ[nt] = *(const short8*)((const char*)wqT + off);
      bV[nt] = *(const short8*)((const char*)wvT + off);
    }
#pragma unroll
    for (int mt = 0; mt < 2; ++mt)
#pragma unroll
      for (int nt = 0; nt < 2; ++nt) {
        aq[mt][nt] = __builtin_amdgcn_mfma_f32_16x16x32_bf16(aA[mt], bQ[nt],
                                                             aq[mt][nt], 0, 0, 0);
        av[mt][nt] = __builtin_amdgcn_mfma_f32_16x16x32_bf16(aA[mt], bV[nt],
                                                             av[mt][nt], 0, 0, 0);
      }
  }
  __syncthreads();

#pragma unroll
  for (int mt = 0; mt < 2; ++mt)
#pragma unroll
    for (int nt = 0; nt < 2; ++nt)
#pragma unroll
      for (int r = 0; r < 4; ++r) {
        float q = aq[mt][nt][r];
        float s = q * q;
        s += __shfl_xor(s, 1);
        s += __shfl_xor(s, 2);
        s += __shfl_xor(s, 4);
        s += __shfl_xor(s, 8);
        float inv = 1.f / fmaxf(sqrtf(s), EPS_NORM);
        int row = mt * 16 + lg * 4 + r;
        int col = colbase + nt * 16 + lr;
        xs[row][col] = __float2bfloat16(q * inv);
        h1s[row][col] = __float2bfloat16(av[mt][nt][r]);
      }
  __syncthreads();

  {
    int row = t >> 3, part = t & 7;
    int n = n0 + row;
    if (n < N) {
      const char* srcq = (const char*)&xs[row][0] + part * 32;
      char* dstq = (char*)qnout + (size_t)n * 256 + part * 32;
      *(uint4*)dstq = *(const uint4*)srcq;
      *(uint4*)(dstq + 16) = *(const uint4*)(srcq + 16);
      const char* srcv = (const char*)&h1s[row][0] + part * 32;
      char* dstv = (char*)vout + (size_t)n * 256 + part * 32;
      *(uint4*)dstv = *(const uint4*)srcv;
      *(uint4*)(dstv + 16) = *(const uint4*)(srcv + 16);
    }
  }
}

// ---------------- gather + in-block dots + out projection ----------------------
__global__ __launch_bounds__(512) void k_gather_out(
    const unsigned* __restrict__ recs, const int* __restrict__ poffs,
    const __hip_bfloat16* __restrict__ qn, const __hip_bfloat16* __restrict__ v,
    const __hip_bfloat16* __restrict__ pnb,
    const __hip_bfloat16* __restrict__ woT, const float* __restrict__ bo,
    float* __restrict__ out, int N) {
  __shared__ __hip_bfloat16 accs[32][136];
  __shared__ unsigned short dotlds[32][256];
  int t = threadIdx.x;
  int w = t >> 6, l = t & 63;
  int h = l >> 3;
  int n0 = blockIdx.x * 32;
  const char* vbase = (const char*)v + 4 * l;

  {
    int row = t >> 4, part = t & 15;
    int n = n0 + row;
    uint4 val = {0u, 0u, 0u, 0u};
    if (n < N)
      val = *(const uint4*)((const char*)qn + (size_t)n * 256 + part * 16);
    *(uint4*)((char*)&accs[row][0] + part * 16) = val;
  }
  __syncthreads();

  {
    int lr = l & 15, lg = l >> 4;
    int rg = w & 1;
    const short8 zero8 = {0, 0, 0, 0, 0, 0, 0, 0};
#pragma unroll
    for (int hh = 0; hh < 2; ++hh) {
      int hx = (w >> 1) * 2 + hh;
      short8 aA = zero8, bB0 = zero8, bB1 = zero8;
      if (lg < 2) {
        aA = *(const short8*)((const char*)&accs[rg * 16 + lr][0] +
                              (hx * CHD + lg * 8) * 2);
        bB0 = *(const short8*)(pnb + lr * CIN + hx * CHD + lg * 8);
        bB1 = *(const short8*)(pnb + (16 + lr) * CIN + hx * CHD + lg * 8);
      }
      f32x4 c0 = {0.f, 0.f, 0.f, 0.f}, c1 = {0.f, 0.f, 0.f, 0.f};
      c0 = __builtin_amdgcn_mfma_f32_16x16x32_bf16(aA, bB0, c0, 0, 0, 0);
      c1 = __builtin_amdgcn_mfma_f32_16x16x32_bf16(aA, bB1, c1, 0, 0, 0);
#pragma unroll
      for (int r = 0; r < 4; ++r) {
        int row = rg * 16 + lg * 4 + r;
        __hip_bfloat16 b0 = __float2bfloat16(c0[r]);
        __hip_bfloat16 b1 = __float2bfloat16(c1[r]);
        dotlds[row][lr * 8 + hx] = *(unsigned short*)&b0;
        dotlds[row][(16 + lr) * 8 + hx] = *(unsigned short*)&b1;
      }
    }
  }
  __syncthreads();

#pragma unroll 1
  for (int j = 0; j < 4; ++j) {
    int nl = w * 4 + j;
    int n = n0 + nl;
    float ax = 0.f, ay = 0.f;
    if (n < N) {
      const unsigned short* dptr = &dotlds[nl][0];
      int beg = poffs[n], end = poffs[n + 1];
      for (int idx = beg; idx < end; idx += 8) {
        unsigned r0 = recs[idx + 0], r1 = recs[idx + 1], r2 = recs[idx + 2],
                 r3 = recs[idx + 3], r4 = recs[idx + 4], r5 = recs[idx + 5],
                 r6 = recs[idx + 6], r7 = recs[idx + 7];
        unsigned v0 = *(const unsigned*)(vbase + (size_t)(r0 & 0x1FFFF) * 256);
        unsigned v1 = *(const unsigned*)(vbase + (size_t)(r1 & 0x1FFFF) * 256);
        unsigned v2 = *(const unsigned*)(vbase + (size_t)(r2 & 0x1FFFF) * 256);
        unsigned v3 = *(const unsigned*)(vbase + (size_t)(r3 & 0x1FFFF) * 256);
        unsigned v4 = *(const unsigned*)(vbase + (size_t)(r4 & 0x1FFFF) * 256);
        unsigned v5 = *(const unsigned*)(vbase + (size_t)(r5 & 0x1FFFF) * 256);
        unsigned v6 = *(const unsigned*)(vbase + (size_t)(r6 & 0x1FFFF) * 256);
        unsigned v7 = *(const unsigned*)(vbase + (size_t)(r7 & 0x1FFFF) * 256);
        float a0 = bfus(dptr[(r0 >> 17) * 8 + h]);
        float a1 = bfus(dptr[(r1 >> 17) * 8 + h]);
        float a2 = bfus(dptr[(r2 >> 17) * 8 + h]);
        float a3 = bfus(dptr[(r3 >> 17) * 8 + h]);
        float a4 = bfus(dptr[(r4 >> 17) * 8 + h]);
        float a5 = bfus(dptr[(r5 >> 17) * 8 + h]);
        float a6 = bfus(dptr[(r6 >> 17) * 8 + h]);
        float a7 = bfus(dptr[(r7 >> 17) * 8 + h]);
        ax += a0 * bflo(v0);
        ay += a0 * bfhi(v0);
        ax += a1 * bflo(v1);
        ay += a1 * bfhi(v1);
        ax += a2 * bflo(v2);
        ay += a2 * bfhi(v2);
        ax += a3 * bflo(v3);
        ay += a3 * bfhi(v3);
        ax += a4 * bflo(v4);
        ay += a4 * bfhi(v4);
        ax += a5 * bflo(v5);
        ay += a5 * bfhi(v5);
        ax += a6 * bflo(v6);
        ay += a6 * bfhi(v6);
        ax += a7 * bflo(v7);
        ay += a7 * bfhi(v7);
      }
    }
    __hip_bfloat16 bx = __float2bfloat16(ax), by = __float2bfloat16(ay);
    unsigned pk = (unsigned)*(unsigned short*)&bx |
                  ((unsigned)*(unsigned short*)&by << 16);
    ((unsigned*)((char*)accs + nl * 272))[l] = pk;
  }
  __syncthreads();

  int lr = l & 15, lg = l >> 4;
  int colb = w * 16;
  float bc = bo[colb + lr];
  f32x4 acc0 = {bc, bc, bc, bc}, acc1 = {bc, bc, bc, bc};
#pragma unroll
  for (int kk = 0; kk < 4; ++kk) {
    short8 aA0 = *(const short8*)((const char*)accs + lr * 272 +
                                  (kk * 32 + lg * 8) * 2);
    short8 aA1 = *(const short8*)((const char*)accs + (16 + lr) * 272 +
                                  (kk * 32 + lg * 8) * 2);
    short8 bB = *(const short8*)(woT + (size_t)(colb + lr) * CIN + kk * 32 +
                                 lg * 8);
    acc0 = __builtin_amdgcn_mfma_f32_16x16x32_bf16(aA0, bB, acc0, 0, 0, 0);
    acc1 = __builtin_amdgcn_mfma_f32_16x16x32_bf16(aA1, bB, acc1, 0, 0, 0);
  }
#pragma unroll
  for (int r = 0; r < 4; ++r) {
    int nr0 = n0 + lg * 4 + r;
    int nr1 = nr0 + 16;
    if (nr0 < N) out[(size_t)nr0 * CIN + colb + lr] = acc0[r];
    if (nr1 < N) out[(size_t)nr1 * CIN + colb + lr] = acc1[r];
  }
}

// ---------------- launch -------------------------------------------------------
extern "C" void kernel_launch(void* const* d_in, const int* in_sizes, int n_in,
                              void* d_out, int out_size, void* d_ws,
                              size_t ws_size, hipStream_t stream) {
  const float* points = (const float*)d_in[0];
  const float* feats = (const float*)d_in[1];
  const int* k_idx = (const int*)d_in[2];
  const int* q_idx = (const int*)d_in[3];
  const int* kernel_idx = (const int*)d_in[4];
  const float* w1 = (const float*)d_in[5];
  const float* g1 = (const float*)d_in[6];
  const float* b1 = (const float*)d_in[7];
  const float* w2 = (const float*)d_in[8];
  const float* g2 = (const float*)d_in[9];
  const float* b2 = (const float*)d_in[10];
  const float* w3 = (const float*)d_in[11];
  const float* b3 = (const float*)d_in[12];
  const float* wq = (const float*)d_in[13];
  const float* bq = (const float*)d_in[14];
  const float* wv = (const float*)d_in[15];
  const float* bv = (const float*)d_in[16];
  const float* wo = (const float*)d_in[17];
  const float* bo = (const float*)d_in[18];
  const float* pos_enc = (const float*)d_in[19];

  int N = in_sizes[0] / 3;
  int M = in_sizes[2];
  int NB = (N + 1023) / 1024;     // <= 256
  int NBKT = (N + 255) >> 8;      // <= 512
  int Np = (N + 4) & ~3;

  float* ws = (float*)d_ws;
  float* stats1 = ws;                                 // 8
  float* stats2 = ws + 8;                             // 256 (ends 264)
  __hip_bfloat16* pnb = (__hip_bfloat16*)(ws + 264);  // 32*128 bf16 (ends 2312)
  int* cnt = (int*)(ws + 4096);                       // Np
  int* poffs = cnt + Np;                              // Np (N+1 used)
  int* bsum = poffs + Np;                             // 512
  int* bbase = bsum + 512;                            // 512
  int* bcur = bbase + 512;                            // 512
  unsigned* recs = (unsigned*)(bcur + 512);           // recn (padded)
  size_t recn = ((size_t)M + 8 * (size_t)N + 7) & ~(size_t)7;
  unsigned* stg = recs + recn;                        // recn staging
  __hip_bfloat16* qnb = (__hip_bfloat16*)(stg + recn);  // N*128
  __hip_bfloat16* vb = qnb + (size_t)N * CIN;           // N*128
  __hip_bfloat16* wqT = vb + (size_t)N * CIN;
  __hip_bfloat16* wvT = wqT + CIN * CIN;
  __hip_bfloat16* w3T = wvT + CIN * CIN;
  __hip_bfloat16* woT = w3T + CIN * CIN;
  float* outf = (float*)d_out;

  hipMemsetAsync(ws, 0, 4096 * sizeof(float), stream);
  hipMemsetAsync(cnt, 0, (size_t)Np * sizeof(int), stream);

  k_bn1_stats<<<256, 256, 0, stream>>>(points, w1, stats1, N);
  k_bn2_stats<<<512, 128, 0, stream>>>(points, w1, g1, b1, w2, stats1, stats2, N);
  k_prep<<<64, 256, 0, stream>>>(pos_enc, wq, wv, w3, wo, pnb, wqT, wvT, w3T, woT);
  k_hist<<<4096, 256, 0, stream>>>(q_idx, cnt, M);
  k_scan1<<<NB, 256, 0, stream>>>(cnt, poffs, bsum, N);
  k_scan2<<<1, 256, 0, stream>>>(bsum, bbase, NB, poffs + N);
  k_scan3<<<NB, 256, 0, stream>>>(cnt, poffs, bbase, recs, N);
  k_binit<<<2, 256, 0, stream>>>(poffs, bcur, N);
  k_bucket1<<<(M + CH - 1) / CH, 256, 0, stream>>>(q_idx, k_idx, kernel_idx,
                                                   bcur, stg, M);
  k_bucket2<<<NBKT, 256, 0, stream>>>(stg, poffs, bcur, recs, N);
  k_qv<<<(N + 31) / 32, 256, 0, stream>>>(points, feats, w1, g1, b1, w2, g2, b2,
                                          b3, bq, bv, w3T, wqT, wvT, stats1,
                                          stats2, qnb, vb, N);
  k_gather_out<<<(N + 31) / 32, 512, 0, stream>>>(recs, poffs, qnb, vb, pnb,
                                                  woT, bo, outf, N);
}